// Round 9
// baseline (2510.363 us; speedup 1.0000x reference)
//
#include <hip/hip_runtime.h>
#include <stdint.h>

#define T_LEN 2048
#define BATCH 16
#define HID   1024
#define BT    (BATCH * T_LEN)   // 32768
#define DTAIL 18                 // depths >= DTAIL go to the serial tail bucket
#define NBUCK (DTAIL + 1)

typedef short short8 __attribute__((ext_vector_type(8)));
typedef float f32x4  __attribute__((ext_vector_type(4)));
typedef unsigned int u32;
typedef u32 u32x4 __attribute__((ext_vector_type(4)));
typedef unsigned short u16;

__device__ __forceinline__ u16 f2bf(float f) {          // RNE f32->bf16
  u32 u = __builtin_bit_cast(u32, f);
  u = (u + 0x7fffu + ((u >> 16) & 1u)) >> 16;
  return (u16)u;
}
__device__ __forceinline__ float bf2f(u16 h) {
  u32 u = ((u32)h) << 16;
  return __builtin_bit_cast(float, u);
}

// ---------- small utility kernels ----------
__global__ void k_dbg(float* o, float v) { o[0] = v; }

__global__ void k_cvt(const float* __restrict__ s, u16* __restrict__ d, int n8) {
  int i = blockIdx.x * blockDim.x + threadIdx.x;
  if (i >= n8) return;
  const float4* sp = (const float4*)s;
  float4 a = sp[i * 2], b = sp[i * 2 + 1];
  union { u16 h[8]; uint4 v; } o;
  o.h[0] = f2bf(a.x); o.h[1] = f2bf(a.y); o.h[2] = f2bf(a.z); o.h[3] = f2bf(a.w);
  o.h[4] = f2bf(b.x); o.h[5] = f2bf(b.y); o.h[6] = f2bf(b.z); o.h[7] = f2bf(b.w);
  ((uint4*)d)[i] = o.v;
}

// dst[i][h] = src[h][i], f32 -> bf16, 1024x1024
__global__ void k_tr(const float* __restrict__ src, u16* __restrict__ dst) {
  __shared__ float tile[32][33];
  int bx = blockIdx.x * 32, by = blockIdx.y * 32;
  int tx = threadIdx.x, ty = threadIdx.y;   // 32 x 8
#pragma unroll
  for (int j = 0; j < 4; ++j)
    tile[ty + j * 8][tx] = src[(size_t)(by + ty + j * 8) * HID + bx + tx];
  __syncthreads();
#pragma unroll
  for (int j = 0; j < 4; ++j)
    dst[(size_t)(bx + ty + j * 8) * HID + by + tx] = f2bf(tile[tx][ty + j * 8]);
}

// out[r] = sum_h W[r,h]*v[h] (+ add[r])
__global__ void k_matvec(const float* __restrict__ W, const float* __restrict__ v,
                         const float* __restrict__ add, float* __restrict__ out) {
  int r = blockIdx.x;
  float s = 0.f;
  for (int h = threadIdx.x; h < HID; h += 256)
    s += W[(size_t)r * HID + h] * v[h];
  for (int o = 32; o; o >>= 1) s += __shfl_down(s, o);
  __shared__ float ws_[4];
  if ((threadIdx.x & 63) == 0) ws_[threadIdx.x >> 6] = s;
  __syncthreads();
  if (threadIdx.x == 0) {
    s = ws_[0] + ws_[1] + ws_[2] + ws_[3];
    out[r] = s + (add ? add[r] : 0.f);
  }
}

// depth per (b,t) via parallel prefix-max of last-reset position.
__global__ __launch_bounds__(256) void k_depths(const void* startp, int* __restrict__ p,
                                                int* __restrict__ cnt) {
  __shared__ int tmax[256];
  __shared__ int lc[NBUCK];
  __shared__ int isIntSh;
  const int b = blockIdx.x;
  const int tid = threadIdx.x;
  if (tid < NBUCK) lc[tid] = 0;
  if (tid == 0) {
    const unsigned char* q = (const unsigned char*)startp;
    int nz = 0;
    for (int i = 0; i < 256; ++i) if ((i & 3) && q[i]) nz++;
    isIntSh = (nz == 0);
  }
  __syncthreads();
  const int isInt = isIntSh;
  int st[8], lastk[8];
  const int t0 = tid * 8;
  int last = -1;
#pragma unroll
  for (int k = 0; k < 8; ++k) {
    const int t = t0 + k;
    int s;
    if (isInt) s = ((const int*)startp)[b * T_LEN + t] != 0;
    else       s = ((const unsigned char*)startp)[b * T_LEN + t] != 0;
    st[k] = s;
    if (s || t == 0) last = t;
    lastk[k] = last;
  }
  tmax[tid] = last;
  __syncthreads();
  for (int off = 1; off < 256; off <<= 1) {
    int v = tmax[tid];
    int u = (tid >= off) ? tmax[tid - off] : -1;
    __syncthreads();
    tmax[tid] = v > u ? v : u;
    __syncthreads();
  }
  const int pre = (tid > 0) ? tmax[tid - 1] : -1;
#pragma unroll
  for (int k = 0; k < 8; ++k) {
    const int t = t0 + k;
    const int R = lastk[k] > pre ? lastk[k] : pre;
    int d = t - R;
    if (d > DTAIL) d = DTAIL;
    atomicAdd(&lc[d], 1);
    p[b * T_LEN + t] = st[k] ? ~d : d;
  }
  __syncthreads();
  if (tid < NBUCK && lc[tid]) atomicAdd(&cnt[tid], lc[tid]);
}

__global__ void k_offsets(const int* cnt, int* offs, int* cursors) {
  if (threadIdx.x == 0 && blockIdx.x == 0) {
    int s = 0;
    for (int d = 0; d < NBUCK; ++d) { offs[d] = s; cursors[d] = s; s += cnt[d]; }
  }
}

// build per-depth gather lists (wave-aggregated atomics)
__global__ void k_build(const int* __restrict__ p, int* cursors,
                        int* __restrict__ s0, int* __restrict__ s1, int* __restrict__ dl) {
  const int i = blockIdx.x * 256 + threadIdx.x;
  const int pv = p[i];
  const int d = pv < 0 ? ~pv : pv;
  const int isStart = pv < 0;
  const int lane = threadIdx.x & 63;
  int slot = -1;
  while (__ballot(slot < 0)) {
    unsigned long long m = __ballot(slot < 0);
    int leader = __ffsll((unsigned long long)m) - 1;
    int dle = __shfl(d, leader);
    unsigned long long grp = __ballot(slot < 0 && d == dle);
    if (slot < 0 && d == dle) {
      int base = 0;
      if (lane == leader) base = atomicAdd(&cursors[dle], (int)__popcll(grp));
      base = __shfl(base, leader);
      slot = base + (int)__popcll(grp & ((1ull << lane) - 1ull));
    }
  }
  const int b = i >> 11;
  int s;
  if (d == 0) s = isStart ? (BT + 32) : (BT + b);
  else        s = i - 1;
  s0[slot] = s;
  if (d == 0) s = isStart ? (BT + 32) : (BT + 16 + b);
  s1[slot] = s;
  dl[slot] = i;
}

// serial tail: items with depth >= DTAIL, ascending t order (exact).
__global__ __launch_bounds__(1024) void k_tail(
    const int* __restrict__ cnt, const int* __restrict__ offs, const int* __restrict__ dstl,
    const u16* __restrict__ Uw, const float* __restrict__ bu,
    const u16* __restrict__ xp, u16* hs, float* __restrict__ hfin) {
  const int n = cnt[DTAIL];
  if (n <= 0) return;
  const int lo = offs[DTAIL];
  __shared__ int idx[4096];
  const int tid = threadIdx.x;
  const int m = n > 4096 ? 4096 : n;
  if (tid == 0) {
    for (int i = 0; i < m; ++i) {
      int v = dstl[lo + i];
      int j = i;
      while (j > 0 && idx[j - 1] > v) { idx[j] = idx[j - 1]; --j; }
      idx[j] = v;
    }
  }
  __syncthreads();
  const int col = tid;
  for (int e = 0; e < m; ++e) {
    const int i = idx[e];
    const u16* hp = hs + (size_t)(i - 1) * HID;
    const u16* ur = Uw + (size_t)col * HID;
    float acc = 0.f;
    for (int r = 0; r < HID; ++r) acc += bf2f(ur[r]) * bf2f(hp[r]);
    const float v = acc + bu[col] + bf2f(xp[(size_t)i * HID + col]);
    const float hval = tanhf(v);
    hs[(size_t)i * HID + col] = f2bf(hval);
    if ((i & (T_LEN - 1)) == T_LEN - 1) hfin[(i >> 11) * HID + col] = hval;
    __threadfence_block();
    __syncthreads();
  }
}

// ---------- 128^2 GEMM (small M / deep scan rounds / weight combos) ----------
template <int EPI, bool GATHER>
__global__ __launch_bounds__(256) void k_gemm(
    const u16* A, const u16* __restrict__ B, void* __restrict__ C,
    const float* __restrict__ bias, int M,
    const int* __restrict__ cnt, const int* __restrict__ offs, int d,
    const int* __restrict__ srcl, const int* __restrict__ dstl,
    const u16* __restrict__ xp, const float* __restrict__ bu,
    float* __restrict__ hfin, u16* hs) {
  __shared__ u16 As[128 * 32];
  __shared__ u16 Bs[128 * 32];
  const int tid = threadIdx.x;
  const int lane = tid & 63;
  const int wv = tid >> 6;
  int Mt = M, lo = 0;
  if (GATHER) { Mt = cnt[d]; lo = offs[d]; if (Mt <= 0) return; }
  const int n0 = blockIdx.x * 128;
  const int wm = (wv >> 1) * 64;
  const int wn = (wv & 1) * 64;
  const int kcol = (lane & 3) * 8;

  for (int mb = blockIdx.y; mb * 128 < Mt; mb += gridDim.y) {
    const int m0 = mb * 128;
    const u16* aptr[2];
    const u16* bptr[2];
#pragma unroll
    for (int i = 0; i < 2; ++i) {
      const int lr = (i * 4 + wv) * 16 + (lane >> 2);
      int gr = m0 + lr;
      if (gr > Mt - 1) gr = Mt - 1;
      if (GATHER) gr = srcl[lo + gr];
      aptr[i] = A + (size_t)gr * HID + kcol;
      bptr[i] = B + (size_t)(n0 + lr) * HID + kcol;
    }
    f32x4 acc[4][4] = {};
    for (int k0 = 0; k0 < HID; k0 += 32) {
      __syncthreads();
#pragma unroll
      for (int i = 0; i < 2; ++i) {
        __builtin_amdgcn_global_load_lds(
            (const __attribute__((address_space(1))) void*)(aptr[i] + k0),
            (__attribute__((address_space(3))) void*)(As + (i * 4 + wv) * 512), 16, 0, 0);
        __builtin_amdgcn_global_load_lds(
            (const __attribute__((address_space(1))) void*)(bptr[i] + k0),
            (__attribute__((address_space(3))) void*)(Bs + (i * 4 + wv) * 512), 16, 0, 0);
      }
      __syncthreads();
      short8 af[4], bf_[4];
#pragma unroll
      for (int f = 0; f < 4; ++f) {
        af[f]  = *(const short8*)(As + (wm + f * 16 + (lane & 15)) * 32 + (lane >> 4) * 8);
        bf_[f] = *(const short8*)(Bs + (wn + f * 16 + (lane & 15)) * 32 + (lane >> 4) * 8);
      }
#pragma unroll
      for (int mi = 0; mi < 4; ++mi)
#pragma unroll
        for (int ni = 0; ni < 4; ++ni)
          acc[mi][ni] = __builtin_amdgcn_mfma_f32_16x16x32_bf16(af[mi], bf_[ni], acc[mi][ni], 0, 0, 0);
    }
#pragma unroll
    for (int mi = 0; mi < 4; ++mi) {
      const int r0 = m0 + wm + mi * 16 + ((lane >> 4) << 2);
#pragma unroll
      for (int ni = 0; ni < 4; ++ni) {
        const int col = n0 + wn + ni * 16 + (lane & 15);
        float bv;
        if (EPI == 3) bv = bu[col];
        else          bv = bias ? bias[col] : 0.0f;
#pragma unroll
        for (int j = 0; j < 4; ++j) {
          const int row = r0 + j;
          if (row >= Mt) continue;
          float v = acc[mi][ni][j] + bv;
          if (EPI == 0) {
            ((u16*)C)[(size_t)row * HID + col] = f2bf(v);
          } else if (EPI == 1) {
            v = v > 0.0f ? v : 0.01f * v;
            ((u16*)C)[(size_t)row * HID + col] = f2bf(v);
          } else if (EPI == 2) {
            ((float*)C)[(size_t)row * HID + col] = v;
          } else {
            const int dsti = dstl[lo + row];
            v += bf2f(xp[(size_t)dsti * HID + col]);
            const float hval = tanhf(v);
            hs[(size_t)dsti * HID + col] = f2bf(hval);
            if ((dsti & (T_LEN - 1)) == T_LEN - 1)
              hfin[(dsti >> 11) * HID + col] = hval;
          }
        }
      }
    }
  }
}

// inline-asm ds_read_b128: opaque to the compiler's waitcnt pass, so outstanding
// global_load_lds ops are NOT drained before it.
#define DSR(dst, base, imm) \
  asm volatile("ds_read_b128 %0, %1 offset:" #imm : "=v"(dst) : "v"(base))

__device__ __forceinline__ unsigned ldsaddr(const u16* p) {
  return (unsigned)(unsigned long long)(__attribute__((address_space(3))) const void*)p;
}

// ---------- 256^2 pipelined GEMM: triple-buffered LDS, counted vmcnt, asm ds_read ----------
// 8 waves (2M x 4N), BK=32, 3 x 32KiB bufs, stage t+2 while computing t.
// Per step: vmcnt(4) [tile t+1 stays in flight] + s_barrier; 12 asm ds_read; 4 gload_lds;
// lgkmcnt(0)+sched_barrier(0); 32 MFMA in one setprio cluster. Never drains vmcnt to 0
// in steady state. BUFFER OFFSETS boB/bo2 ARE IN BYTES (round-8 bug: bo2 started at
// 32768 = buffer 1; tile t+2 must start in buffer 2 = byte 65536).
template <int EPI, bool GATHER>
__global__ __launch_bounds__(512, 2) void k_pgemm(
    const u16* __restrict__ A, const u16* __restrict__ B, void* __restrict__ C,
    const float* __restrict__ bias, int M,
    const int* __restrict__ cnt, const int* __restrict__ offs, int d,
    const int* __restrict__ srcl, const int* __restrict__ dstl,
    const u16* __restrict__ xp, const float* __restrict__ bu,
    float* __restrict__ hfin, u16* hs) {
  __shared__ u16 lds3[3 * 16384];   // 96 KiB
  const int tid = threadIdx.x;
  const int l = tid & 63;
  const int w = tid >> 6;
  const int wr = w & 1;
  const int wc = w >> 1;
  int Mt = M, lo = 0;
  if (GATHER) { Mt = cnt[d]; lo = offs[d]; if (Mt <= 0) return; }

  // XCD-aware bijective remap (grid total % 8 == 0)
  const int nid = blockIdx.y * gridDim.x + blockIdx.x;
  const int cpx = (gridDim.x * gridDim.y) >> 3;
  const int swz = (nid & 7) * cpx + (nid >> 3);
  const int n0 = (swz & 3) * 256;
  const int by0 = swz >> 2;

  const int srow = w * 32 + (l >> 2);
  const int scol = ((l & 3) ^ ((l >> 3) & 3)) * 8;  // pre-swizzled global k-chunk
  const int ldsA = w * 1024;
  const int fr = l & 15;
  const int chunkP = (((l >> 4) ^ ((fr >> 1) & 3)) * 8);
  const int rdA0 = (wr * 128 + fr) * 32 + chunkP;
  const int rdB0 = 8192 + (wc * 64 + fr) * 32 + chunkP;
  const unsigned ldsBase = ldsaddr(lds3);
  const unsigned aAr = ldsBase + rdA0 * 2;   // + buf byte-offset per step
  const unsigned aBr = ldsBase + rdB0 * 2;

  const u16* Bp0 = B + (size_t)(n0 + srow) * HID + scol;
  const u16* Bp1 = Bp0 + (size_t)16 * HID;

  for (int mb = by0; mb * 256 < Mt; mb += gridDim.y) {
    const int m0 = mb * 256;
    const u16* Ap0;
    const u16* Ap1;
    {
      int r0 = m0 + srow, r1 = m0 + 16 + srow;
      if (r0 > Mt - 1) r0 = Mt - 1;
      if (r1 > Mt - 1) r1 = Mt - 1;
      if (GATHER) { r0 = srcl[lo + r0]; r1 = srcl[lo + r1]; }
      Ap0 = A + (size_t)r0 * HID + scol;
      Ap1 = A + (size_t)r1 * HID + scol;
    }

    auto STAGE = [&](int t, int bo) {   // bo: u16 index of buffer base
      const int kb = t * 32;
      __builtin_amdgcn_global_load_lds(
          (const __attribute__((address_space(1))) void*)(Ap0 + kb),
          (__attribute__((address_space(3))) void*)(lds3 + bo + ldsA), 16, 0, 0);
      __builtin_amdgcn_global_load_lds(
          (const __attribute__((address_space(1))) void*)(Ap1 + kb),
          (__attribute__((address_space(3))) void*)(lds3 + bo + ldsA + 512), 16, 0, 0);
      __builtin_amdgcn_global_load_lds(
          (const __attribute__((address_space(1))) void*)(Bp0 + kb),
          (__attribute__((address_space(3))) void*)(lds3 + bo + 8192 + ldsA), 16, 0, 0);
      __builtin_amdgcn_global_load_lds(
          (const __attribute__((address_space(1))) void*)(Bp1 + kb),
          (__attribute__((address_space(3))) void*)(lds3 + bo + 8192 + ldsA + 512), 16, 0, 0);
    };

    __builtin_amdgcn_s_barrier();     // LDS reuse safe across m-iterations
    STAGE(0, 0);
    STAGE(1, 16384);

    f32x4 acc[8][4] = {};
    unsigned boB = 0, bo2 = 65536;    // BYTES: (t%3)*32768, ((t+2)%3)*32768  [fixed]
    for (int t = 0; t < 32; ++t) {
      if (t < 31) { asm volatile("s_waitcnt vmcnt(4)" ::: "memory"); }
      else        { asm volatile("s_waitcnt vmcnt(0)" ::: "memory"); }
      __builtin_amdgcn_s_barrier();
      const unsigned aA = aAr + boB;
      const unsigned aB = aBr + boB;
      u32x4 br_[4], ar_[8];
      DSR(br_[0], aB, 0);    DSR(br_[1], aB, 1024);
      DSR(br_[2], aB, 2048); DSR(br_[3], aB, 3072);
      DSR(ar_[0], aA, 0);    DSR(ar_[1], aA, 1024);
      DSR(ar_[2], aA, 2048); DSR(ar_[3], aA, 3072);
      DSR(ar_[4], aA, 4096); DSR(ar_[5], aA, 5120);
      DSR(ar_[6], aA, 6144); DSR(ar_[7], aA, 7168);
      if (t < 30) STAGE(t + 2, bo2 >> 1);          // bo2 bytes -> u16 index
      asm volatile("s_waitcnt lgkmcnt(0)" ::: "memory");
      __builtin_amdgcn_sched_barrier(0);
      __builtin_amdgcn_s_setprio(1);
#pragma unroll
      for (int mi = 0; mi < 8; ++mi) {
        const short8 am = __builtin_bit_cast(short8, ar_[mi]);
#pragma unroll
        for (int ni = 0; ni < 4; ++ni)
          acc[mi][ni] = __builtin_amdgcn_mfma_f32_16x16x32_bf16(
              am, __builtin_bit_cast(short8, br_[ni]), acc[mi][ni], 0, 0, 0);
      }
      __builtin_amdgcn_s_setprio(0);
      boB += 32768; if (boB == 98304) boB = 0;
      bo2 += 32768; if (bo2 == 98304) bo2 = 0;
    }

    // epilogue: wave tile at (m0 + wr*128, n0 + wc*64)
#pragma unroll
    for (int mi = 0; mi < 8; ++mi) {
      const int r0 = m0 + wr * 128 + mi * 16 + ((l >> 4) << 2);
#pragma unroll
      for (int ni = 0; ni < 4; ++ni) {
        const int col = n0 + wc * 64 + ni * 16 + fr;
        float bv;
        if (EPI == 3) bv = bu[col];
        else          bv = bias ? bias[col] : 0.0f;
#pragma unroll
        for (int j = 0; j < 4; ++j) {
          const int row = r0 + j;
          if (row >= Mt) continue;
          float v = acc[mi][ni][j] + bv;
          if (EPI == 0) {
            ((u16*)C)[(size_t)row * HID + col] = f2bf(v);
          } else if (EPI == 1) {
            v = v > 0.0f ? v : 0.01f * v;
            ((u16*)C)[(size_t)row * HID + col] = f2bf(v);
          } else if (EPI == 2) {
            ((float*)C)[(size_t)row * HID + col] = v;
          } else {
            const int dsti = dstl[lo + row];
            v += bf2f(xp[(size_t)dsti * HID + col]);
            const float hval = tanhf(v);
            hs[(size_t)dsti * HID + col] = f2bf(hval);
            if ((dsti & (T_LEN - 1)) == T_LEN - 1)
              hfin[(dsti >> 11) * HID + col] = hval;
          }
        }
      }
    }
  }
}

// ---------- host ----------
extern "C" void kernel_launch(void* const* d_in, const int* in_sizes, int n_in,
                              void* d_out, int out_size, void* d_ws, size_t ws_size,
                              hipStream_t stream) {
  (void)in_sizes; (void)n_in; (void)out_size;
  const float* emb   = (const float*)d_in[0];
  const void*  start = d_in[1];
  const float* h0    = (const float*)d_in[2];
  const float* Win   = (const float*)d_in[3];
  const float* b_in  = (const float*)d_in[4];
  const float* Wout  = (const float*)d_in[5];
  const float* b_out = (const float*)d_in[6];
  const float* Uh    = (const float*)d_in[7];
  const float* bUh   = (const float*)d_in[8];
  const float* Wh    = (const float*)d_in[9];
  const float* Wy    = (const float*)d_in[10];
  const float* bWy   = (const float*)d_in[11];
  const float* Wff   = (const float*)d_in[12];
  const float* bff   = (const float*)d_in[13];
  float* dout = (float*)d_out;

  char* w = (char*)d_ws;
  auto alloc = [&](size_t b) { char* r = w; w += (b + 255) & ~(size_t)255; return r; };
  u16* E     = (u16*)alloc((size_t)BT * HID * 2);
  u16* X1    = (u16*)alloc((size_t)BT * HID * 2);
  u16* HS    = (u16*)alloc((size_t)(BT + 33) * HID * 2);
  u16* W0b   = (u16*)alloc((size_t)HID * HID * 2);
  u16* Wc0b  = (u16*)alloc((size_t)HID * HID * 2);
  u16* Wc1b  = (u16*)alloc((size_t)HID * HID * 2);
  u16* Wh1b  = (u16*)alloc((size_t)HID * HID * 2);
  u16* Woutb = (u16*)alloc((size_t)HID * HID * 2);
  u16* Uhb   = (u16*)alloc((size_t)2 * HID * HID * 2);
  u16* Wh0b  = (u16*)alloc((size_t)HID * HID * 2);
  u16* Wff0b = (u16*)alloc((size_t)HID * HID * 2);
  u16* Wff1b = (u16*)alloc((size_t)HID * HID * 2);
  u16* WinT  = (u16*)alloc((size_t)HID * HID * 2);
  u16* Wy0T  = (u16*)alloc((size_t)HID * HID * 2);
  u16* Wy1T  = (u16*)alloc((size_t)HID * HID * 2);
  float* bias0 = (float*)alloc(HID * 4);
  float* bc0   = (float*)alloc(HID * 4);
  float* bc1   = (float*)alloc(HID * 4);
  int* pArr = (int*)alloc(BT * 4);
  int* src0 = (int*)alloc(BT * 4);
  int* src1 = (int*)alloc(BT * 4);
  int* dstl = (int*)alloc(BT * 4);
  int* cnts = (int*)alloc(64 * 4);
  int* offs = (int*)alloc(64 * 4);
  int* curs = (int*)alloc(64 * 4);

  if ((size_t)(w - (char*)d_ws) > ws_size) {
    k_dbg<<<1, 1, 0, stream>>>(dout, (float)ws_size);
    return;
  }

  hipMemsetAsync(cnts, 0, NBUCK * 4, stream);
  hipMemsetAsync(HS + (size_t)(BT + 32) * HID, 0, HID * 2, stream);

  // converts (f32 -> bf16)
  k_cvt<<<(BT * HID / 8 + 255) / 256, 256, 0, stream>>>(emb, E, BT * HID / 8);
  k_cvt<<<1024, 256, 0, stream>>>(Uh, Uhb, 2 * HID * HID / 8);
  k_cvt<<<512, 256, 0, stream>>>(Wh,             Wh0b,  HID * HID / 8);
  k_cvt<<<512, 256, 0, stream>>>(Wh + HID * HID, Wh1b,  HID * HID / 8);
  k_cvt<<<512, 256, 0, stream>>>(Wff,             Wff0b, HID * HID / 8);
  k_cvt<<<512, 256, 0, stream>>>(Wff + HID * HID, Wff1b, HID * HID / 8);
  k_cvt<<<512, 256, 0, stream>>>(Wout, Woutb, HID * HID / 8);
  k_cvt<<<16, 256, 0, stream>>>(h0, HS + (size_t)BT * HID, 2 * BATCH * HID / 8);

  dim3 tb(32, 8), tg(32, 32);
  k_tr<<<tg, tb, 0, stream>>>(Win, WinT);
  k_tr<<<tg, tb, 0, stream>>>(Wy,             Wy0T);
  k_tr<<<tg, tb, 0, stream>>>(Wy + HID * HID, Wy1T);

  // folded biases
  k_matvec<<<HID, 256, 0, stream>>>(Wh, b_in, nullptr, bias0);
  k_matvec<<<HID, 256, 0, stream>>>(Wff, bWy, bff, bc0);
  k_matvec<<<HID, 256, 0, stream>>>(Wff + HID * HID, bWy + HID, bff + HID, bc1);

  // depth lists
  k_depths<<<BATCH, 256, 0, stream>>>(start, pArr, cnts);
  k_offsets<<<1, 64, 0, stream>>>(cnts, offs, curs);
  k_build<<<BT / 256, 256, 0, stream>>>(pArr, curs, src0, src1, dstl);

  // combined weights: W0 = Wh0@Win, Wc_l = Wff_l@Wy_l  (128^2 kernel, M=1024)
  k_gemm<0, false><<<dim3(8, 8), 256, 0, stream>>>(Wh0b, WinT, W0b, nullptr, HID,
      nullptr, nullptr, 0, nullptr, nullptr, nullptr, nullptr, nullptr, nullptr);
  k_gemm<0, false><<<dim3(8, 8), 256, 0, stream>>>(Wff0b, Wy0T, Wc0b, nullptr, HID,
      nullptr, nullptr, 0, nullptr, nullptr, nullptr, nullptr, nullptr, nullptr);
  k_gemm<0, false><<<dim3(8, 8), 256, 0, stream>>>(Wff1b, Wy1T, Wc1b, nullptr, HID,
      nullptr, nullptr, 0, nullptr, nullptr, nullptr, nullptr, nullptr, nullptr);

  // xp0 = emb @ W0^T + bias0
  k_pgemm<0, false><<<dim3(4, 128), 512, 0, stream>>>(E, W0b, X1, bias0, BT,
      nullptr, nullptr, 0, nullptr, nullptr, nullptr, nullptr, nullptr, nullptr);

  // scan rounds: pipelined 256^2 for d<3, 128^2 for deeper (grid-stride covers overflow)
  static const int gy[DTAIL] = {132, 66, 34, 18, 10, 6, 4, 2, 2, 2, 1, 1, 1, 1, 1, 1, 1, 1};
  static const int gy256[3] = {66, 34, 16};

  // layer 0 scan + exact tail
  for (int d = 0; d < 3; ++d)
    k_pgemm<3, true><<<dim3(4, gy256[d]), 512, 0, stream>>>(HS, Uhb, nullptr, nullptr, 0,
        cnts, offs, d, src0, dstl, X1, bUh, dout, HS);
  for (int d = 3; d < DTAIL; ++d)
    k_gemm<3, true><<<dim3(8, gy[d]), 256, 0, stream>>>(HS, Uhb, nullptr, nullptr, 0,
        cnts, offs, d, src0, dstl, X1, bUh, dout, HS);
  k_tail<<<1, 1024, 0, stream>>>(cnts, offs, dstl, Uhb, bUh, X1, HS, dout);

  // layer_in1 = leaky_relu(hs0 @ Wc0^T + bc0)
  k_pgemm<1, false><<<dim3(4, 128), 512, 0, stream>>>(HS, Wc0b, E, bc0, BT,
      nullptr, nullptr, 0, nullptr, nullptr, nullptr, nullptr, nullptr, nullptr);
  // xp1 = layer_in1 @ Wh1^T
  k_pgemm<0, false><<<dim3(4, 128), 512, 0, stream>>>(E, Wh1b, X1, nullptr, BT,
      nullptr, nullptr, 0, nullptr, nullptr, nullptr, nullptr, nullptr, nullptr);

  // layer 1 scan + tail
  for (int d = 0; d < 3; ++d)
    k_pgemm<3, true><<<dim3(4, gy256[d]), 512, 0, stream>>>(HS, Uhb + HID * HID, nullptr, nullptr, 0,
        cnts, offs, d, src1, dstl, X1, bUh + HID, dout + BATCH * HID, HS);
  for (int d = 3; d < DTAIL; ++d)
    k_gemm<3, true><<<dim3(8, gy[d]), 256, 0, stream>>>(HS, Uhb + HID * HID, nullptr, nullptr, 0,
        cnts, offs, d, src1, dstl, X1, bUh + HID, dout + BATCH * HID, HS);
  k_tail<<<1, 1024, 0, stream>>>(cnts, offs, dstl, Uhb + HID * HID, bUh + HID, X1, HS,
                                 dout + BATCH * HID);

  // layer_in2 = leaky_relu(hs1 @ Wc1^T + bc1)
  k_pgemm<1, false><<<dim3(4, 128), 512, 0, stream>>>(HS, Wc1b, E, bc1, BT,
      nullptr, nullptr, 0, nullptr, nullptr, nullptr, nullptr, nullptr, nullptr);
  // out = layer_in2 @ Wout^T + b_out
  k_pgemm<2, false><<<dim3(4, 128), 512, 0, stream>>>(E, Woutb, dout + 2 * BATCH * HID, b_out, BT,
      nullptr, nullptr, 0, nullptr, nullptr, nullptr, nullptr, nullptr, nullptr);
}

// Round 10
// 2508.879 us; speedup vs baseline: 1.0006x; 1.0006x over previous
//
#include <hip/hip_runtime.h>
#include <stdint.h>

#define T_LEN 2048
#define BATCH 16
#define HID   1024
#define BT    (BATCH * T_LEN)   // 32768
#define DTAIL 18                 // depths >= DTAIL go to the serial tail bucket
#define NBUCK (DTAIL + 1)

typedef short short8 __attribute__((ext_vector_type(8)));
typedef float f32x4  __attribute__((ext_vector_type(4)));
typedef unsigned int u32;
typedef u32 u32x4 __attribute__((ext_vector_type(4)));
typedef unsigned short u16;

__device__ __forceinline__ u16 f2bf(float f) {          // RNE f32->bf16
  u32 u = __builtin_bit_cast(u32, f);
  u = (u + 0x7fffu + ((u >> 16) & 1u)) >> 16;
  return (u16)u;
}
__device__ __forceinline__ float bf2f(u16 h) {
  u32 u = ((u32)h) << 16;
  return __builtin_bit_cast(float, u);
}

// ---------- small utility kernels ----------
__global__ void k_dbg(float* o, float v) { o[0] = v; }

__global__ void k_cvt(const float* __restrict__ s, u16* __restrict__ d, int n8) {
  int i = blockIdx.x * blockDim.x + threadIdx.x;
  if (i >= n8) return;
  const float4* sp = (const float4*)s;
  float4 a = sp[i * 2], b = sp[i * 2 + 1];
  union { u16 h[8]; uint4 v; } o;
  o.h[0] = f2bf(a.x); o.h[1] = f2bf(a.y); o.h[2] = f2bf(a.z); o.h[3] = f2bf(a.w);
  o.h[4] = f2bf(b.x); o.h[5] = f2bf(b.y); o.h[6] = f2bf(b.z); o.h[7] = f2bf(b.w);
  ((uint4*)d)[i] = o.v;
}

// dst[i][h] = src[h][i], f32 -> bf16, 1024x1024
__global__ void k_tr(const float* __restrict__ src, u16* __restrict__ dst) {
  __shared__ float tile[32][33];
  int bx = blockIdx.x * 32, by = blockIdx.y * 32;
  int tx = threadIdx.x, ty = threadIdx.y;   // 32 x 8
#pragma unroll
  for (int j = 0; j < 4; ++j)
    tile[ty + j * 8][tx] = src[(size_t)(by + ty + j * 8) * HID + bx + tx];
  __syncthreads();
#pragma unroll
  for (int j = 0; j < 4; ++j)
    dst[(size_t)(bx + ty + j * 8) * HID + by + tx] = f2bf(tile[tx][ty + j * 8]);
}

// out[r] = sum_h W[r,h]*v[h] (+ add[r])
__global__ void k_matvec(const float* __restrict__ W, const float* __restrict__ v,
                         const float* __restrict__ add, float* __restrict__ out) {
  int r = blockIdx.x;
  float s = 0.f;
  for (int h = threadIdx.x; h < HID; h += 256)
    s += W[(size_t)r * HID + h] * v[h];
  for (int o = 32; o; o >>= 1) s += __shfl_down(s, o);
  __shared__ float ws_[4];
  if ((threadIdx.x & 63) == 0) ws_[threadIdx.x >> 6] = s;
  __syncthreads();
  if (threadIdx.x == 0) {
    s = ws_[0] + ws_[1] + ws_[2] + ws_[3];
    out[r] = s + (add ? add[r] : 0.f);
  }
}

// depth per (b,t) via parallel prefix-max of last-reset position.
__global__ __launch_bounds__(256) void k_depths(const void* startp, int* __restrict__ p,
                                                int* __restrict__ cnt) {
  __shared__ int tmax[256];
  __shared__ int lc[NBUCK];
  __shared__ int isIntSh;
  const int b = blockIdx.x;
  const int tid = threadIdx.x;
  if (tid < NBUCK) lc[tid] = 0;
  if (tid == 0) {
    const unsigned char* q = (const unsigned char*)startp;
    int nz = 0;
    for (int i = 0; i < 256; ++i) if ((i & 3) && q[i]) nz++;
    isIntSh = (nz == 0);
  }
  __syncthreads();
  const int isInt = isIntSh;
  int st[8], lastk[8];
  const int t0 = tid * 8;
  int last = -1;
#pragma unroll
  for (int k = 0; k < 8; ++k) {
    const int t = t0 + k;
    int s;
    if (isInt) s = ((const int*)startp)[b * T_LEN + t] != 0;
    else       s = ((const unsigned char*)startp)[b * T_LEN + t] != 0;
    st[k] = s;
    if (s || t == 0) last = t;
    lastk[k] = last;
  }
  tmax[tid] = last;
  __syncthreads();
  for (int off = 1; off < 256; off <<= 1) {
    int v = tmax[tid];
    int u = (tid >= off) ? tmax[tid - off] : -1;
    __syncthreads();
    tmax[tid] = v > u ? v : u;
    __syncthreads();
  }
  const int pre = (tid > 0) ? tmax[tid - 1] : -1;
#pragma unroll
  for (int k = 0; k < 8; ++k) {
    const int t = t0 + k;
    const int R = lastk[k] > pre ? lastk[k] : pre;
    int d = t - R;
    if (d > DTAIL) d = DTAIL;
    atomicAdd(&lc[d], 1);
    p[b * T_LEN + t] = st[k] ? ~d : d;
  }
  __syncthreads();
  if (tid < NBUCK && lc[tid]) atomicAdd(&cnt[tid], lc[tid]);
}

__global__ void k_offsets(const int* cnt, int* offs, int* cursors) {
  if (threadIdx.x == 0 && blockIdx.x == 0) {
    int s = 0;
    for (int d = 0; d < NBUCK; ++d) { offs[d] = s; cursors[d] = s; s += cnt[d]; }
  }
}

// build per-depth gather lists (wave-aggregated atomics)
__global__ void k_build(const int* __restrict__ p, int* cursors,
                        int* __restrict__ s0, int* __restrict__ s1, int* __restrict__ dl) {
  const int i = blockIdx.x * 256 + threadIdx.x;
  const int pv = p[i];
  const int d = pv < 0 ? ~pv : pv;
  const int isStart = pv < 0;
  const int lane = threadIdx.x & 63;
  int slot = -1;
  while (__ballot(slot < 0)) {
    unsigned long long m = __ballot(slot < 0);
    int leader = __ffsll((unsigned long long)m) - 1;
    int dle = __shfl(d, leader);
    unsigned long long grp = __ballot(slot < 0 && d == dle);
    if (slot < 0 && d == dle) {
      int base = 0;
      if (lane == leader) base = atomicAdd(&cursors[dle], (int)__popcll(grp));
      base = __shfl(base, leader);
      slot = base + (int)__popcll(grp & ((1ull << lane) - 1ull));
    }
  }
  const int b = i >> 11;
  int s;
  if (d == 0) s = isStart ? (BT + 32) : (BT + b);
  else        s = i - 1;
  s0[slot] = s;
  if (d == 0) s = isStart ? (BT + 32) : (BT + 16 + b);
  s1[slot] = s;
  dl[slot] = i;
}

// serial tail: items with depth >= DTAIL, ascending t order (exact).
__global__ __launch_bounds__(1024) void k_tail(
    const int* __restrict__ cnt, const int* __restrict__ offs, const int* __restrict__ dstl,
    const u16* __restrict__ Uw, const float* __restrict__ bu,
    const u16* __restrict__ xp, u16* hs, float* __restrict__ hfin) {
  const int n = cnt[DTAIL];
  if (n <= 0) return;
  const int lo = offs[DTAIL];
  __shared__ int idx[4096];
  const int tid = threadIdx.x;
  const int m = n > 4096 ? 4096 : n;
  if (tid == 0) {
    for (int i = 0; i < m; ++i) {
      int v = dstl[lo + i];
      int j = i;
      while (j > 0 && idx[j - 1] > v) { idx[j] = idx[j - 1]; --j; }
      idx[j] = v;
    }
  }
  __syncthreads();
  const int col = tid;
  for (int e = 0; e < m; ++e) {
    const int i = idx[e];
    const u16* hp = hs + (size_t)(i - 1) * HID;
    const u16* ur = Uw + (size_t)col * HID;
    float acc = 0.f;
    for (int r = 0; r < HID; ++r) acc += bf2f(ur[r]) * bf2f(hp[r]);
    const float v = acc + bu[col] + bf2f(xp[(size_t)i * HID + col]);
    const float hval = tanhf(v);
    hs[(size_t)i * HID + col] = f2bf(hval);
    if ((i & (T_LEN - 1)) == T_LEN - 1) hfin[(i >> 11) * HID + col] = hval;
    __threadfence_block();
    __syncthreads();
  }
}

// ---------- 128^2 GEMM (small M / deep scan rounds / weight combos) ----------
template <int EPI, bool GATHER>
__global__ __launch_bounds__(256) void k_gemm(
    const u16* A, const u16* __restrict__ B, void* __restrict__ C,
    const float* __restrict__ bias, int M,
    const int* __restrict__ cnt, const int* __restrict__ offs, int d,
    const int* __restrict__ srcl, const int* __restrict__ dstl,
    const u16* __restrict__ xp, const float* __restrict__ bu,
    float* __restrict__ hfin, u16* hs) {
  __shared__ u16 As[128 * 32];
  __shared__ u16 Bs[128 * 32];
  const int tid = threadIdx.x;
  const int lane = tid & 63;
  const int wv = tid >> 6;
  int Mt = M, lo = 0;
  if (GATHER) { Mt = cnt[d]; lo = offs[d]; if (Mt <= 0) return; }
  const int n0 = blockIdx.x * 128;
  const int wm = (wv >> 1) * 64;
  const int wn = (wv & 1) * 64;
  const int kcol = (lane & 3) * 8;

  for (int mb = blockIdx.y; mb * 128 < Mt; mb += gridDim.y) {
    const int m0 = mb * 128;
    const u16* aptr[2];
    const u16* bptr[2];
#pragma unroll
    for (int i = 0; i < 2; ++i) {
      const int lr = (i * 4 + wv) * 16 + (lane >> 2);
      int gr = m0 + lr;
      if (gr > Mt - 1) gr = Mt - 1;
      if (GATHER) gr = srcl[lo + gr];
      aptr[i] = A + (size_t)gr * HID + kcol;
      bptr[i] = B + (size_t)(n0 + lr) * HID + kcol;
    }
    f32x4 acc[4][4] = {};
    for (int k0 = 0; k0 < HID; k0 += 32) {
      __syncthreads();
#pragma unroll
      for (int i = 0; i < 2; ++i) {
        __builtin_amdgcn_global_load_lds(
            (const __attribute__((address_space(1))) void*)(aptr[i] + k0),
            (__attribute__((address_space(3))) void*)(As + (i * 4 + wv) * 512), 16, 0, 0);
        __builtin_amdgcn_global_load_lds(
            (const __attribute__((address_space(1))) void*)(bptr[i] + k0),
            (__attribute__((address_space(3))) void*)(Bs + (i * 4 + wv) * 512), 16, 0, 0);
      }
      __syncthreads();
      short8 af[4], bf_[4];
#pragma unroll
      for (int f = 0; f < 4; ++f) {
        af[f]  = *(const short8*)(As + (wm + f * 16 + (lane & 15)) * 32 + (lane >> 4) * 8);
        bf_[f] = *(const short8*)(Bs + (wn + f * 16 + (lane & 15)) * 32 + (lane >> 4) * 8);
      }
#pragma unroll
      for (int mi = 0; mi < 4; ++mi)
#pragma unroll
        for (int ni = 0; ni < 4; ++ni)
          acc[mi][ni] = __builtin_amdgcn_mfma_f32_16x16x32_bf16(af[mi], bf_[ni], acc[mi][ni], 0, 0, 0);
    }
#pragma unroll
    for (int mi = 0; mi < 4; ++mi) {
      const int r0 = m0 + wm + mi * 16 + ((lane >> 4) << 2);
#pragma unroll
      for (int ni = 0; ni < 4; ++ni) {
        const int col = n0 + wn + ni * 16 + (lane & 15);
        float bv;
        if (EPI == 3) bv = bu[col];
        else          bv = bias ? bias[col] : 0.0f;
#pragma unroll
        for (int j = 0; j < 4; ++j) {
          const int row = r0 + j;
          if (row >= Mt) continue;
          float v = acc[mi][ni][j] + bv;
          if (EPI == 0) {
            ((u16*)C)[(size_t)row * HID + col] = f2bf(v);
          } else if (EPI == 1) {
            v = v > 0.0f ? v : 0.01f * v;
            ((u16*)C)[(size_t)row * HID + col] = f2bf(v);
          } else if (EPI == 2) {
            ((float*)C)[(size_t)row * HID + col] = v;
          } else {
            const int dsti = dstl[lo + row];
            v += bf2f(xp[(size_t)dsti * HID + col]);
            const float hval = tanhf(v);
            hs[(size_t)dsti * HID + col] = f2bf(hval);
            if ((dsti & (T_LEN - 1)) == T_LEN - 1)
              hfin[(dsti >> 11) * HID + col] = hval;
          }
        }
      }
    }
  }
}

// inline-asm ds_read_b128: opaque to the compiler's waitcnt pass, so outstanding
// global_load_lds ops are NOT drained before it.
#define DSR(dst, base, imm) \
  asm volatile("ds_read_b128 %0, %1 offset:" #imm : "=v"(dst) : "v"(base))

__device__ __forceinline__ unsigned ldsaddr(const u16* p) {
  return (unsigned)(unsigned long long)(__attribute__((address_space(3))) const void*)p;
}

// ---------- 256^2 pipelined GEMM: triple-buffered LDS, counted vmcnt, asm ds_read ----------
// 8 waves (2M x 4N), BK=32, 3 x 32KiB bufs, stage t+2 while computing t.
// Per step: vmcnt(4) [tile t+1 stays in flight] + s_barrier; 12 asm ds_read; 4 gload_lds;
// lgkmcnt(0)+sched_barrier(0); 32 MFMA in one setprio cluster. Never drains vmcnt to 0
// in steady state. BUFFER OFFSETS boB/bo2 ARE IN BYTES (round-8 bug: bo2 started at
// 32768 = buffer 1; tile t+2 must start in buffer 2 = byte 65536).
template <int EPI, bool GATHER>
__global__ __launch_bounds__(512, 2) void k_pgemm(
    const u16* __restrict__ A, const u16* __restrict__ B, void* __restrict__ C,
    const float* __restrict__ bias, int M,
    const int* __restrict__ cnt, const int* __restrict__ offs, int d,
    const int* __restrict__ srcl, const int* __restrict__ dstl,
    const u16* __restrict__ xp, const float* __restrict__ bu,
    float* __restrict__ hfin, u16* hs) {
  __shared__ u16 lds3[3 * 16384];   // 96 KiB
  const int tid = threadIdx.x;
  const int l = tid & 63;
  const int w = tid >> 6;
  const int wr = w & 1;
  const int wc = w >> 1;
  int Mt = M, lo = 0;
  if (GATHER) { Mt = cnt[d]; lo = offs[d]; if (Mt <= 0) return; }

  // XCD-aware bijective remap (grid total % 8 == 0)
  const int nid = blockIdx.y * gridDim.x + blockIdx.x;
  const int cpx = (gridDim.x * gridDim.y) >> 3;
  const int swz = (nid & 7) * cpx + (nid >> 3);
  const int n0 = (swz & 3) * 256;
  const int by0 = swz >> 2;

  const int srow = w * 32 + (l >> 2);
  const int scol = ((l & 3) ^ ((l >> 3) & 3)) * 8;  // pre-swizzled global k-chunk
  const int ldsA = w * 1024;
  const int fr = l & 15;
  const int chunkP = (((l >> 4) ^ ((fr >> 1) & 3)) * 8);
  const int rdA0 = (wr * 128 + fr) * 32 + chunkP;
  const int rdB0 = 8192 + (wc * 64 + fr) * 32 + chunkP;
  const unsigned ldsBase = ldsaddr(lds3);
  const unsigned aAr = ldsBase + rdA0 * 2;   // + buf byte-offset per step
  const unsigned aBr = ldsBase + rdB0 * 2;

  const u16* Bp0 = B + (size_t)(n0 + srow) * HID + scol;
  const u16* Bp1 = Bp0 + (size_t)16 * HID;

  for (int mb = by0; mb * 256 < Mt; mb += gridDim.y) {
    const int m0 = mb * 256;
    const u16* Ap0;
    const u16* Ap1;
    {
      int r0 = m0 + srow, r1 = m0 + 16 + srow;
      if (r0 > Mt - 1) r0 = Mt - 1;
      if (r1 > Mt - 1) r1 = Mt - 1;
      if (GATHER) { r0 = srcl[lo + r0]; r1 = srcl[lo + r1]; }
      Ap0 = A + (size_t)r0 * HID + scol;
      Ap1 = A + (size_t)r1 * HID + scol;
    }

    auto STAGE = [&](int t, int bo) {   // bo: u16 index of buffer base
      const int kb = t * 32;
      __builtin_amdgcn_global_load_lds(
          (const __attribute__((address_space(1))) void*)(Ap0 + kb),
          (__attribute__((address_space(3))) void*)(lds3 + bo + ldsA), 16, 0, 0);
      __builtin_amdgcn_global_load_lds(
          (const __attribute__((address_space(1))) void*)(Ap1 + kb),
          (__attribute__((address_space(3))) void*)(lds3 + bo + ldsA + 512), 16, 0, 0);
      __builtin_amdgcn_global_load_lds(
          (const __attribute__((address_space(1))) void*)(Bp0 + kb),
          (__attribute__((address_space(3))) void*)(lds3 + bo + 8192 + ldsA), 16, 0, 0);
      __builtin_amdgcn_global_load_lds(
          (const __attribute__((address_space(1))) void*)(Bp1 + kb),
          (__attribute__((address_space(3))) void*)(lds3 + bo + 8192 + ldsA + 512), 16, 0, 0);
    };

    __builtin_amdgcn_s_barrier();     // LDS reuse safe across m-iterations
    STAGE(0, 0);
    STAGE(1, 16384);

    f32x4 acc[8][4] = {};
    unsigned boB = 0, bo2 = 65536;    // BYTES: (t%3)*32768, ((t+2)%3)*32768  [fixed]
    for (int t = 0; t < 32; ++t) {
      if (t < 31) { asm volatile("s_waitcnt vmcnt(4)" ::: "memory"); }
      else        { asm volatile("s_waitcnt vmcnt(0)" ::: "memory"); }
      __builtin_amdgcn_s_barrier();
      const unsigned aA = aAr + boB;
      const unsigned aB = aBr + boB;
      u32x4 br_[4], ar_[8];
      DSR(br_[0], aB, 0);    DSR(br_[1], aB, 1024);
      DSR(br_[2], aB, 2048); DSR(br_[3], aB, 3072);
      DSR(ar_[0], aA, 0);    DSR(ar_[1], aA, 1024);
      DSR(ar_[2], aA, 2048); DSR(ar_[3], aA, 3072);
      DSR(ar_[4], aA, 4096); DSR(ar_[5], aA, 5120);
      DSR(ar_[6], aA, 6144); DSR(ar_[7], aA, 7168);
      if (t < 30) STAGE(t + 2, bo2 >> 1);          // bo2 bytes -> u16 index
      asm volatile("s_waitcnt lgkmcnt(0)" ::: "memory");
      __builtin_amdgcn_sched_barrier(0);
      __builtin_amdgcn_s_setprio(1);
#pragma unroll
      for (int mi = 0; mi < 8; ++mi) {
        const short8 am = __builtin_bit_cast(short8, ar_[mi]);
#pragma unroll
        for (int ni = 0; ni < 4; ++ni)
          acc[mi][ni] = __builtin_amdgcn_mfma_f32_16x16x32_bf16(
              am, __builtin_bit_cast(short8, br_[ni]), acc[mi][ni], 0, 0, 0);
      }
      __builtin_amdgcn_s_setprio(0);
      boB += 32768; if (boB == 98304) boB = 0;
      bo2 += 32768; if (bo2 == 98304) bo2 = 0;
    }

    // epilogue: wave tile at (m0 + wr*128, n0 + wc*64)
#pragma unroll
    for (int mi = 0; mi < 8; ++mi) {
      const int r0 = m0 + wr * 128 + mi * 16 + ((l >> 4) << 2);
#pragma unroll
      for (int ni = 0; ni < 4; ++ni) {
        const int col = n0 + wc * 64 + ni * 16 + fr;
        float bv;
        if (EPI == 3) bv = bu[col];
        else          bv = bias ? bias[col] : 0.0f;
#pragma unroll
        for (int j = 0; j < 4; ++j) {
          const int row = r0 + j;
          if (row >= Mt) continue;
          float v = acc[mi][ni][j] + bv;
          if (EPI == 0) {
            ((u16*)C)[(size_t)row * HID + col] = f2bf(v);
          } else if (EPI == 1) {
            v = v > 0.0f ? v : 0.01f * v;
            ((u16*)C)[(size_t)row * HID + col] = f2bf(v);
          } else if (EPI == 2) {
            ((float*)C)[(size_t)row * HID + col] = v;
          } else {
            const int dsti = dstl[lo + row];
            v += bf2f(xp[(size_t)dsti * HID + col]);
            const float hval = tanhf(v);
            hs[(size_t)dsti * HID + col] = f2bf(hval);
            if ((dsti & (T_LEN - 1)) == T_LEN - 1)
              hfin[(dsti >> 11) * HID + col] = hval;
          }
        }
      }
    }
  }
}

// ---------- host ----------
extern "C" void kernel_launch(void* const* d_in, const int* in_sizes, int n_in,
                              void* d_out, int out_size, void* d_ws, size_t ws_size,
                              hipStream_t stream) {
  (void)in_sizes; (void)n_in; (void)out_size;
  const float* emb   = (const float*)d_in[0];
  const void*  start = d_in[1];
  const float* h0    = (const float*)d_in[2];
  const float* Win   = (const float*)d_in[3];
  const float* b_in  = (const float*)d_in[4];
  const float* Wout  = (const float*)d_in[5];
  const float* b_out = (const float*)d_in[6];
  const float* Uh    = (const float*)d_in[7];
  const float* bUh   = (const float*)d_in[8];
  const float* Wh    = (const float*)d_in[9];
  const float* Wy    = (const float*)d_in[10];
  const float* bWy   = (const float*)d_in[11];
  const float* Wff   = (const float*)d_in[12];
  const float* bff   = (const float*)d_in[13];
  float* dout = (float*)d_out;

  char* w = (char*)d_ws;
  auto alloc = [&](size_t b) { char* r = w; w += (b + 255) & ~(size_t)255; return r; };
  u16* E     = (u16*)alloc((size_t)BT * HID * 2);
  u16* X1    = (u16*)alloc((size_t)BT * HID * 2);
  u16* HS    = (u16*)alloc((size_t)(BT + 33) * HID * 2);
  u16* W0b   = (u16*)alloc((size_t)HID * HID * 2);
  u16* Wc0b  = (u16*)alloc((size_t)HID * HID * 2);
  u16* Wc1b  = (u16*)alloc((size_t)HID * HID * 2);
  u16* Wh1b  = (u16*)alloc((size_t)HID * HID * 2);
  u16* Woutb = (u16*)alloc((size_t)HID * HID * 2);
  u16* Uhb   = (u16*)alloc((size_t)2 * HID * HID * 2);
  u16* Wh0b  = (u16*)alloc((size_t)HID * HID * 2);
  u16* Wff0b = (u16*)alloc((size_t)HID * HID * 2);
  u16* Wff1b = (u16*)alloc((size_t)HID * HID * 2);
  u16* WinT  = (u16*)alloc((size_t)HID * HID * 2);
  u16* Wy0T  = (u16*)alloc((size_t)HID * HID * 2);
  u16* Wy1T  = (u16*)alloc((size_t)HID * HID * 2);
  float* bias0 = (float*)alloc(HID * 4);
  float* bc0   = (float*)alloc(HID * 4);
  float* bc1   = (float*)alloc(HID * 4);
  int* pArr = (int*)alloc(BT * 4);
  int* src0 = (int*)alloc(BT * 4);
  int* src1 = (int*)alloc(BT * 4);
  int* dstl = (int*)alloc(BT * 4);
  int* cnts = (int*)alloc(64 * 4);
  int* offs = (int*)alloc(64 * 4);
  int* curs = (int*)alloc(64 * 4);

  if ((size_t)(w - (char*)d_ws) > ws_size) {
    k_dbg<<<1, 1, 0, stream>>>(dout, (float)ws_size);
    return;
  }

  hipMemsetAsync(cnts, 0, NBUCK * 4, stream);
  hipMemsetAsync(HS + (size_t)(BT + 32) * HID, 0, HID * 2, stream);

  // converts (f32 -> bf16)
  k_cvt<<<(BT * HID / 8 + 255) / 256, 256, 0, stream>>>(emb, E, BT * HID / 8);
  k_cvt<<<1024, 256, 0, stream>>>(Uh, Uhb, 2 * HID * HID / 8);
  k_cvt<<<512, 256, 0, stream>>>(Wh,             Wh0b,  HID * HID / 8);
  k_cvt<<<512, 256, 0, stream>>>(Wh + HID * HID, Wh1b,  HID * HID / 8);
  k_cvt<<<512, 256, 0, stream>>>(Wff,             Wff0b, HID * HID / 8);
  k_cvt<<<512, 256, 0, stream>>>(Wff + HID * HID, Wff1b, HID * HID / 8);
  k_cvt<<<512, 256, 0, stream>>>(Wout, Woutb, HID * HID / 8);
  k_cvt<<<16, 256, 0, stream>>>(h0, HS + (size_t)BT * HID, 2 * BATCH * HID / 8);

  dim3 tb(32, 8), tg(32, 32);
  k_tr<<<tg, tb, 0, stream>>>(Win, WinT);
  k_tr<<<tg, tb, 0, stream>>>(Wy,             Wy0T);
  k_tr<<<tg, tb, 0, stream>>>(Wy + HID * HID, Wy1T);

  // folded biases
  k_matvec<<<HID, 256, 0, stream>>>(Wh, b_in, nullptr, bias0);
  k_matvec<<<HID, 256, 0, stream>>>(Wff, bWy, bff, bc0);
  k_matvec<<<HID, 256, 0, stream>>>(Wff + HID * HID, bWy + HID, bff + HID, bc1);

  // depth lists
  k_depths<<<BATCH, 256, 0, stream>>>(start, pArr, cnts);
  k_offsets<<<1, 64, 0, stream>>>(cnts, offs, curs);
  k_build<<<BT / 256, 256, 0, stream>>>(pArr, curs, src0, src1, dstl);

  // combined weights: W0 = Wh0@Win, Wc_l = Wff_l@Wy_l  (128^2 kernel, M=1024)
  k_gemm<0, false><<<dim3(8, 8), 256, 0, stream>>>(Wh0b, WinT, W0b, nullptr, HID,
      nullptr, nullptr, 0, nullptr, nullptr, nullptr, nullptr, nullptr, nullptr);
  k_gemm<0, false><<<dim3(8, 8), 256, 0, stream>>>(Wff0b, Wy0T, Wc0b, nullptr, HID,
      nullptr, nullptr, 0, nullptr, nullptr, nullptr, nullptr, nullptr, nullptr);
  k_gemm<0, false><<<dim3(8, 8), 256, 0, stream>>>(Wff1b, Wy1T, Wc1b, nullptr, HID,
      nullptr, nullptr, 0, nullptr, nullptr, nullptr, nullptr, nullptr, nullptr);

  // xp0 = emb @ W0^T + bias0
  k_pgemm<0, false><<<dim3(4, 128), 512, 0, stream>>>(E, W0b, X1, bias0, BT,
      nullptr, nullptr, 0, nullptr, nullptr, nullptr, nullptr, nullptr, nullptr);

  // scan rounds: pipelined 256^2 for d<3, 128^2 for deeper (grid-stride covers overflow)
  static const int gy[DTAIL] = {132, 66, 34, 18, 10, 6, 4, 2, 2, 2, 1, 1, 1, 1, 1, 1, 1, 1};
  static const int gy256[3] = {66, 34, 16};

  // layer 0 scan + exact tail
  for (int d = 0; d < 3; ++d)
    k_pgemm<3, true><<<dim3(4, gy256[d]), 512, 0, stream>>>(HS, Uhb, nullptr, nullptr, 0,
        cnts, offs, d, src0, dstl, X1, bUh, dout, HS);
  for (int d = 3; d < DTAIL; ++d)
    k_gemm<3, true><<<dim3(8, gy[d]), 256, 0, stream>>>(HS, Uhb, nullptr, nullptr, 0,
        cnts, offs, d, src0, dstl, X1, bUh, dout, HS);
  k_tail<<<1, 1024, 0, stream>>>(cnts, offs, dstl, Uhb, bUh, X1, HS, dout);

  // layer_in1 = leaky_relu(hs0 @ Wc0^T + bc0)
  k_pgemm<1, false><<<dim3(4, 128), 512, 0, stream>>>(HS, Wc0b, E, bc0, BT,
      nullptr, nullptr, 0, nullptr, nullptr, nullptr, nullptr, nullptr, nullptr);
  // xp1 = layer_in1 @ Wh1^T
  k_pgemm<0, false><<<dim3(4, 128), 512, 0, stream>>>(E, Wh1b, X1, nullptr, BT,
      nullptr, nullptr, 0, nullptr, nullptr, nullptr, nullptr, nullptr, nullptr);

  // layer 1 scan + tail
  for (int d = 0; d < 3; ++d)
    k_pgemm<3, true><<<dim3(4, gy256[d]), 512, 0, stream>>>(HS, Uhb + HID * HID, nullptr, nullptr, 0,
        cnts, offs, d, src1, dstl, X1, bUh + HID, dout + BATCH * HID, HS);
  for (int d = 3; d < DTAIL; ++d)
    k_gemm<3, true><<<dim3(8, gy[d]), 256, 0, stream>>>(HS, Uhb + HID * HID, nullptr, nullptr, 0,
        cnts, offs, d, src1, dstl, X1, bUh + HID, dout + BATCH * HID, HS);
  k_tail<<<1, 1024, 0, stream>>>(cnts, offs, dstl, Uhb + HID * HID, bUh + HID, X1, HS,
                                 dout + BATCH * HID);

  // layer_in2 = leaky_relu(hs1 @ Wc1^T + bc1)
  k_pgemm<1, false><<<dim3(4, 128), 512, 0, stream>>>(HS, Wc1b, E, bc1, BT,
      nullptr, nullptr, 0, nullptr, nullptr, nullptr, nullptr, nullptr, nullptr);
  // out = layer_in2 @ Wout^T + b_out
  k_pgemm<2, false><<<dim3(4, 128), 512, 0, stream>>>(E, Woutb, dout + 2 * BATCH * HID, b_out, BT,
      nullptr, nullptr, 0, nullptr, nullptr, nullptr, nullptr, nullptr, nullptr);
}

// Round 11
// 2355.685 us; speedup vs baseline: 1.0657x; 1.0650x over previous
//
#include <hip/hip_runtime.h>
#include <stdint.h>

#define T_LEN 2048
#define BATCH 16
#define HID   1024
#define BT    (BATCH * T_LEN)   // 32768
#define DTAIL 18                 // depths >= DTAIL go to the serial tail bucket
#define NBUCK (DTAIL + 1)

typedef short short8 __attribute__((ext_vector_type(8)));
typedef float f32x4  __attribute__((ext_vector_type(4)));
typedef unsigned int u32;
typedef unsigned short u16;

__device__ __forceinline__ u16 f2bf(float f) {          // RNE f32->bf16
  u32 u = __builtin_bit_cast(u32, f);
  u = (u + 0x7fffu + ((u >> 16) & 1u)) >> 16;
  return (u16)u;
}
__device__ __forceinline__ float bf2f(u16 h) {
  u32 u = ((u32)h) << 16;
  return __builtin_bit_cast(float, u);
}

// ---------- small utility kernels ----------
__global__ void k_dbg(float* o, float v) { o[0] = v; }

__global__ void k_cvt(const float* __restrict__ s, u16* __restrict__ d, int n8) {
  int i = blockIdx.x * blockDim.x + threadIdx.x;
  if (i >= n8) return;
  const float4* sp = (const float4*)s;
  float4 a = sp[i * 2], b = sp[i * 2 + 1];
  union { u16 h[8]; uint4 v; } o;
  o.h[0] = f2bf(a.x); o.h[1] = f2bf(a.y); o.h[2] = f2bf(a.z); o.h[3] = f2bf(a.w);
  o.h[4] = f2bf(b.x); o.h[5] = f2bf(b.y); o.h[6] = f2bf(b.z); o.h[7] = f2bf(b.w);
  ((uint4*)d)[i] = o.v;
}

// dst[i][h] = src[h][i], f32 -> bf16, 1024x1024
__global__ void k_tr(const float* __restrict__ src, u16* __restrict__ dst) {
  __shared__ float tile[32][33];
  int bx = blockIdx.x * 32, by = blockIdx.y * 32;
  int tx = threadIdx.x, ty = threadIdx.y;   // 32 x 8
#pragma unroll
  for (int j = 0; j < 4; ++j)
    tile[ty + j * 8][tx] = src[(size_t)(by + ty + j * 8) * HID + bx + tx];
  __syncthreads();
#pragma unroll
  for (int j = 0; j < 4; ++j)
    dst[(size_t)(bx + ty + j * 8) * HID + by + tx] = f2bf(tile[tx][ty + j * 8]);
}

// out[r] = sum_h W[r,h]*v[h] (+ add[r])
__global__ void k_matvec(const float* __restrict__ W, const float* __restrict__ v,
                         const float* __restrict__ add, float* __restrict__ out) {
  int r = blockIdx.x;
  float s = 0.f;
  for (int h = threadIdx.x; h < HID; h += 256)
    s += W[(size_t)r * HID + h] * v[h];
  for (int o = 32; o; o >>= 1) s += __shfl_down(s, o);
  __shared__ float ws_[4];
  if ((threadIdx.x & 63) == 0) ws_[threadIdx.x >> 6] = s;
  __syncthreads();
  if (threadIdx.x == 0) {
    s = ws_[0] + ws_[1] + ws_[2] + ws_[3];
    out[r] = s + (add ? add[r] : 0.f);
  }
}

// depth per (b,t) via parallel prefix-max of last-reset position.
__global__ __launch_bounds__(256) void k_depths(const void* startp, int* __restrict__ p,
                                                int* __restrict__ cnt) {
  __shared__ int tmax[256];
  __shared__ int lc[NBUCK];
  __shared__ int isIntSh;
  const int b = blockIdx.x;
  const int tid = threadIdx.x;
  if (tid < NBUCK) lc[tid] = 0;
  if (tid == 0) {
    const unsigned char* q = (const unsigned char*)startp;
    int nz = 0;
    for (int i = 0; i < 256; ++i) if ((i & 3) && q[i]) nz++;
    isIntSh = (nz == 0);
  }
  __syncthreads();
  const int isInt = isIntSh;
  int st[8], lastk[8];
  const int t0 = tid * 8;
  int last = -1;
#pragma unroll
  for (int k = 0; k < 8; ++k) {
    const int t = t0 + k;
    int s;
    if (isInt) s = ((const int*)startp)[b * T_LEN + t] != 0;
    else       s = ((const unsigned char*)startp)[b * T_LEN + t] != 0;
    st[k] = s;
    if (s || t == 0) last = t;
    lastk[k] = last;
  }
  tmax[tid] = last;
  __syncthreads();
  for (int off = 1; off < 256; off <<= 1) {
    int v = tmax[tid];
    int u = (tid >= off) ? tmax[tid - off] : -1;
    __syncthreads();
    tmax[tid] = v > u ? v : u;
    __syncthreads();
  }
  const int pre = (tid > 0) ? tmax[tid - 1] : -1;
#pragma unroll
  for (int k = 0; k < 8; ++k) {
    const int t = t0 + k;
    const int R = lastk[k] > pre ? lastk[k] : pre;
    int d = t - R;
    if (d > DTAIL) d = DTAIL;
    atomicAdd(&lc[d], 1);
    p[b * T_LEN + t] = st[k] ? ~d : d;
  }
  __syncthreads();
  if (tid < NBUCK && lc[tid]) atomicAdd(&cnt[tid], lc[tid]);
}

__global__ void k_offsets(const int* cnt, int* offs, int* cursors) {
  if (threadIdx.x == 0 && blockIdx.x == 0) {
    int s = 0;
    for (int d = 0; d < NBUCK; ++d) { offs[d] = s; cursors[d] = s; s += cnt[d]; }
  }
}

// build per-depth gather lists (wave-aggregated atomics)
__global__ void k_build(const int* __restrict__ p, int* cursors,
                        int* __restrict__ s0, int* __restrict__ s1, int* __restrict__ dl) {
  const int i = blockIdx.x * 256 + threadIdx.x;
  const int pv = p[i];
  const int d = pv < 0 ? ~pv : pv;
  const int isStart = pv < 0;
  const int lane = threadIdx.x & 63;
  int slot = -1;
  while (__ballot(slot < 0)) {
    unsigned long long m = __ballot(slot < 0);
    int leader = __ffsll((unsigned long long)m) - 1;
    int dle = __shfl(d, leader);
    unsigned long long grp = __ballot(slot < 0 && d == dle);
    if (slot < 0 && d == dle) {
      int base = 0;
      if (lane == leader) base = atomicAdd(&cursors[dle], (int)__popcll(grp));
      base = __shfl(base, leader);
      slot = base + (int)__popcll(grp & ((1ull << lane) - 1ull));
    }
  }
  const int b = i >> 11;
  int s;
  if (d == 0) s = isStart ? (BT + 32) : (BT + b);
  else        s = i - 1;
  s0[slot] = s;
  if (d == 0) s = isStart ? (BT + 32) : (BT + 16 + b);
  s1[slot] = s;
  dl[slot] = i;
}

// serial tail: items with depth >= DTAIL, ascending t order (exact).
__global__ __launch_bounds__(1024) void k_tail(
    const int* __restrict__ cnt, const int* __restrict__ offs, const int* __restrict__ dstl,
    const u16* __restrict__ Uw, const float* __restrict__ bu,
    const u16* __restrict__ xp, u16* hs, float* __restrict__ hfin) {
  const int n = cnt[DTAIL];
  if (n <= 0) return;
  const int lo = offs[DTAIL];
  __shared__ int idx[4096];
  const int tid = threadIdx.x;
  const int m = n > 4096 ? 4096 : n;
  if (tid == 0) {
    for (int i = 0; i < m; ++i) {
      int v = dstl[lo + i];
      int j = i;
      while (j > 0 && idx[j - 1] > v) { idx[j] = idx[j - 1]; --j; }
      idx[j] = v;
    }
  }
  __syncthreads();
  const int col = tid;
  for (int e = 0; e < m; ++e) {
    const int i = idx[e];
    const u16* hp = hs + (size_t)(i - 1) * HID;
    const u16* ur = Uw + (size_t)col * HID;
    float acc = 0.f;
    for (int r = 0; r < HID; ++r) acc += bf2f(ur[r]) * bf2f(hp[r]);
    const float v = acc + bu[col] + bf2f(xp[(size_t)i * HID + col]);
    const float hval = tanhf(v);
    hs[(size_t)i * HID + col] = f2bf(hval);
    if ((i & (T_LEN - 1)) == T_LEN - 1) hfin[(i >> 11) * HID + col] = hval;
    __threadfence_block();
    __syncthreads();
  }
}

// ---------- 128^2 GEMM, BK=32 (the proven workhorse: big GEMMs, scan d0/d1) ----------
template <int EPI, bool GATHER>
__global__ __launch_bounds__(256) void k_gemm(
    const u16* A, const u16* __restrict__ B, void* __restrict__ C,
    const float* __restrict__ bias, int M,
    const int* __restrict__ cnt, const int* __restrict__ offs, int d,
    const int* __restrict__ srcl, const int* __restrict__ dstl,
    const u16* __restrict__ xp, const float* __restrict__ bu,
    float* __restrict__ hfin, u16* hs) {
  __shared__ u16 As[128 * 32];
  __shared__ u16 Bs[128 * 32];
  const int tid = threadIdx.x;
  const int lane = tid & 63;
  const int wv = tid >> 6;
  int Mt = M, lo = 0;
  if (GATHER) { Mt = cnt[d]; lo = offs[d]; if (Mt <= 0) return; }
  const int n0 = blockIdx.x * 128;
  const int wm = (wv >> 1) * 64;
  const int wn = (wv & 1) * 64;
  const int kcol = (lane & 3) * 8;

  for (int mb = blockIdx.y; mb * 128 < Mt; mb += gridDim.y) {
    const int m0 = mb * 128;
    const u16* aptr[2];
    const u16* bptr[2];
#pragma unroll
    for (int i = 0; i < 2; ++i) {
      const int lr = (i * 4 + wv) * 16 + (lane >> 2);
      int gr = m0 + lr;
      if (gr > Mt - 1) gr = Mt - 1;
      if (GATHER) gr = srcl[lo + gr];
      aptr[i] = A + (size_t)gr * HID + kcol;
      bptr[i] = B + (size_t)(n0 + lr) * HID + kcol;
    }
    f32x4 acc[4][4] = {};
    for (int k0 = 0; k0 < HID; k0 += 32) {
      __syncthreads();
#pragma unroll
      for (int i = 0; i < 2; ++i) {
        __builtin_amdgcn_global_load_lds(
            (const __attribute__((address_space(1))) void*)(aptr[i] + k0),
            (__attribute__((address_space(3))) void*)(As + (i * 4 + wv) * 512), 16, 0, 0);
        __builtin_amdgcn_global_load_lds(
            (const __attribute__((address_space(1))) void*)(bptr[i] + k0),
            (__attribute__((address_space(3))) void*)(Bs + (i * 4 + wv) * 512), 16, 0, 0);
      }
      __syncthreads();
      short8 af[4], bf_[4];
#pragma unroll
      for (int f = 0; f < 4; ++f) {
        af[f]  = *(const short8*)(As + (wm + f * 16 + (lane & 15)) * 32 + (lane >> 4) * 8);
        bf_[f] = *(const short8*)(Bs + (wn + f * 16 + (lane & 15)) * 32 + (lane >> 4) * 8);
      }
#pragma unroll
      for (int mi = 0; mi < 4; ++mi)
#pragma unroll
        for (int ni = 0; ni < 4; ++ni)
          acc[mi][ni] = __builtin_amdgcn_mfma_f32_16x16x32_bf16(af[mi], bf_[ni], acc[mi][ni], 0, 0, 0);
    }
#pragma unroll
    for (int mi = 0; mi < 4; ++mi) {
      const int r0 = m0 + wm + mi * 16 + ((lane >> 4) << 2);
#pragma unroll
      for (int ni = 0; ni < 4; ++ni) {
        const int col = n0 + wn + ni * 16 + (lane & 15);
        float bv;
        if (EPI == 3) bv = bu[col];
        else          bv = bias ? bias[col] : 0.0f;
#pragma unroll
        for (int j = 0; j < 4; ++j) {
          const int row = r0 + j;
          if (row >= Mt) continue;
          float v = acc[mi][ni][j] + bv;
          if (EPI == 0) {
            ((u16*)C)[(size_t)row * HID + col] = f2bf(v);
          } else if (EPI == 1) {
            v = v > 0.0f ? v : 0.01f * v;
            ((u16*)C)[(size_t)row * HID + col] = f2bf(v);
          } else if (EPI == 2) {
            ((float*)C)[(size_t)row * HID + col] = v;
          } else {
            const int dsti = dstl[lo + row];
            v += bf2f(xp[(size_t)dsti * HID + col]);
            const float hval = tanhf(v);
            hs[(size_t)dsti * HID + col] = f2bf(hval);
            if ((dsti & (T_LEN - 1)) == T_LEN - 1)
              hfin[(dsti >> 11) * HID + col] = hval;
          }
        }
      }
    }
  }
}

// ---------- 128^2 GEMM, BK=128 (k_deep: latency-floor killer for small-M rounds) ----------
// 8 K-steps instead of 32: 4x fewer exposed stage drains. Single-buffered 64 KiB LDS.
// LDS layout: [128 rows][16 slots of 8 u16]; logical chunk g lives at slot g^(row&15)
// (store side: pre-swizzled per-lane global column; read side: slot=(s*4+p)^fr) ->
// ds_read_b128 is 2-way-or-better on banks. Same MFMA fragment math as k_gemm.
template <int EPI, bool GATHER>
__global__ __launch_bounds__(256) void k_deep(
    const u16* __restrict__ A, const u16* __restrict__ B, void* __restrict__ C,
    const float* __restrict__ bias, int M,
    const int* __restrict__ cnt, const int* __restrict__ offs, int d,
    const int* __restrict__ srcl, const int* __restrict__ dstl,
    const u16* __restrict__ xp, const float* __restrict__ bu,
    float* __restrict__ hfin, u16* hs) {
  __shared__ u16 As[128 * 128];   // 32 KiB
  __shared__ u16 Bs[128 * 128];   // 32 KiB
  const int tid = threadIdx.x;
  const int l = tid & 63;
  const int wv = tid >> 6;
  int Mt = M, lo = 0;
  if (GATHER) { Mt = cnt[d]; lo = offs[d]; if (Mt <= 0) return; }
  const int n0 = blockIdx.x * 128;
  const int wm = (wv >> 1) * 64;
  const int wn = (wv & 1) * 64;
  const int fr = l & 15;
  const int p  = l >> 4;          // 0..3

  for (int mb = blockIdx.y; mb * 128 < Mt; mb += gridDim.y) {
    const int m0 = mb * 128;
    // staging instr i (i=0..7): rows rowbase = wv*32+i*4 (+p), slot l&15,
    // carrying logical chunk g = (l&15) ^ ((i*4)&12) ^ p  -> global u16 col g*8
    const u16* aptr[8];
    const u16* bptr[8];
#pragma unroll
    for (int i = 0; i < 8; ++i) {
      const int g = ((l & 15) ^ ((i * 4) & 12) ^ p) * 8;
      int gr = m0 + wv * 32 + i * 4 + p;
      if (gr > Mt - 1) gr = Mt - 1;                    // tail clamp (masked at store)
      if (GATHER) gr = srcl[lo + gr];
      aptr[i] = A + (size_t)gr * HID + g;
      bptr[i] = B + (size_t)(n0 + wv * 32 + i * 4 + p) * HID + g;
    }
    f32x4 acc[4][4] = {};
    for (int t = 0; t < 8; ++t) {
      const int k0 = t * 128;
      __syncthreads();
#pragma unroll
      for (int i = 0; i < 8; ++i) {
        __builtin_amdgcn_global_load_lds(
            (const __attribute__((address_space(1))) void*)(aptr[i] + k0),
            (__attribute__((address_space(3))) void*)(As + (wv * 32 + i * 4) * 128), 16, 0, 0);
        __builtin_amdgcn_global_load_lds(
            (const __attribute__((address_space(1))) void*)(bptr[i] + k0),
            (__attribute__((address_space(3))) void*)(Bs + (wv * 32 + i * 4) * 128), 16, 0, 0);
      }
      __syncthreads();
#pragma unroll
      for (int s = 0; s < 4; ++s) {
        const int slot = ((s * 4 + p) ^ fr) * 8;
        short8 af[4], bf_[4];
#pragma unroll
        for (int f = 0; f < 4; ++f) {
          af[f]  = *(const short8*)(As + (wm + f * 16 + fr) * 128 + slot);
          bf_[f] = *(const short8*)(Bs + (wn + f * 16 + fr) * 128 + slot);
        }
#pragma unroll
        for (int mi = 0; mi < 4; ++mi)
#pragma unroll
          for (int ni = 0; ni < 4; ++ni)
            acc[mi][ni] = __builtin_amdgcn_mfma_f32_16x16x32_bf16(af[mi], bf_[ni], acc[mi][ni], 0, 0, 0);
      }
    }
#pragma unroll
    for (int mi = 0; mi < 4; ++mi) {
      const int r0 = m0 + wm + mi * 16 + ((l >> 4) << 2);
#pragma unroll
      for (int ni = 0; ni < 4; ++ni) {
        const int col = n0 + wn + ni * 16 + fr;
        float bv;
        if (EPI == 3) bv = bu[col];
        else          bv = bias ? bias[col] : 0.0f;
#pragma unroll
        for (int j = 0; j < 4; ++j) {
          const int row = r0 + j;
          if (row >= Mt) continue;
          float v = acc[mi][ni][j] + bv;
          if (EPI == 0) {
            ((u16*)C)[(size_t)row * HID + col] = f2bf(v);
          } else if (EPI == 1) {
            v = v > 0.0f ? v : 0.01f * v;
            ((u16*)C)[(size_t)row * HID + col] = f2bf(v);
          } else if (EPI == 2) {
            ((float*)C)[(size_t)row * HID + col] = v;
          } else {
            const int dsti = dstl[lo + row];
            v += bf2f(xp[(size_t)dsti * HID + col]);
            const float hval = tanhf(v);
            hs[(size_t)dsti * HID + col] = f2bf(hval);
            if ((dsti & (T_LEN - 1)) == T_LEN - 1)
              hfin[(dsti >> 11) * HID + col] = hval;
          }
        }
      }
    }
  }
}

// ---------- host ----------
extern "C" void kernel_launch(void* const* d_in, const int* in_sizes, int n_in,
                              void* d_out, int out_size, void* d_ws, size_t ws_size,
                              hipStream_t stream) {
  (void)in_sizes; (void)n_in; (void)out_size;
  const float* emb   = (const float*)d_in[0];
  const void*  start = d_in[1];
  const float* h0    = (const float*)d_in[2];
  const float* Win   = (const float*)d_in[3];
  const float* b_in  = (const float*)d_in[4];
  const float* Wout  = (const float*)d_in[5];
  const float* b_out = (const float*)d_in[6];
  const float* Uh    = (const float*)d_in[7];
  const float* bUh   = (const float*)d_in[8];
  const float* Wh    = (const float*)d_in[9];
  const float* Wy    = (const float*)d_in[10];
  const float* bWy   = (const float*)d_in[11];
  const float* Wff   = (const float*)d_in[12];
  const float* bff   = (const float*)d_in[13];
  float* dout = (float*)d_out;

  char* w = (char*)d_ws;
  auto alloc = [&](size_t b) { char* r = w; w += (b + 255) & ~(size_t)255; return r; };
  u16* E     = (u16*)alloc((size_t)BT * HID * 2);
  u16* X1    = (u16*)alloc((size_t)BT * HID * 2);
  u16* HS    = (u16*)alloc((size_t)(BT + 33) * HID * 2);
  u16* W0b   = (u16*)alloc((size_t)HID * HID * 2);
  u16* Wc0b  = (u16*)alloc((size_t)HID * HID * 2);
  u16* Wc1b  = (u16*)alloc((size_t)HID * HID * 2);
  u16* Wh1b  = (u16*)alloc((size_t)HID * HID * 2);
  u16* Woutb = (u16*)alloc((size_t)HID * HID * 2);
  u16* Uhb   = (u16*)alloc((size_t)2 * HID * HID * 2);
  u16* Wh0b  = (u16*)alloc((size_t)HID * HID * 2);
  u16* Wff0b = (u16*)alloc((size_t)HID * HID * 2);
  u16* Wff1b = (u16*)alloc((size_t)HID * HID * 2);
  u16* WinT  = (u16*)alloc((size_t)HID * HID * 2);
  u16* Wy0T  = (u16*)alloc((size_t)HID * HID * 2);
  u16* Wy1T  = (u16*)alloc((size_t)HID * HID * 2);
  float* bias0 = (float*)alloc(HID * 4);
  float* bc0   = (float*)alloc(HID * 4);
  float* bc1   = (float*)alloc(HID * 4);
  int* pArr = (int*)alloc(BT * 4);
  int* src0 = (int*)alloc(BT * 4);
  int* src1 = (int*)alloc(BT * 4);
  int* dstl = (int*)alloc(BT * 4);
  int* cnts = (int*)alloc(64 * 4);
  int* offs = (int*)alloc(64 * 4);
  int* curs = (int*)alloc(64 * 4);

  if ((size_t)(w - (char*)d_ws) > ws_size) {
    k_dbg<<<1, 1, 0, stream>>>(dout, (float)ws_size);
    return;
  }

  hipMemsetAsync(cnts, 0, NBUCK * 4, stream);
  hipMemsetAsync(HS + (size_t)(BT + 32) * HID, 0, HID * 2, stream);

  // converts (f32 -> bf16)
  k_cvt<<<(BT * HID / 8 + 255) / 256, 256, 0, stream>>>(emb, E, BT * HID / 8);
  k_cvt<<<1024, 256, 0, stream>>>(Uh, Uhb, 2 * HID * HID / 8);
  k_cvt<<<512, 256, 0, stream>>>(Wh,             Wh0b,  HID * HID / 8);
  k_cvt<<<512, 256, 0, stream>>>(Wh + HID * HID, Wh1b,  HID * HID / 8);
  k_cvt<<<512, 256, 0, stream>>>(Wff,             Wff0b, HID * HID / 8);
  k_cvt<<<512, 256, 0, stream>>>(Wff + HID * HID, Wff1b, HID * HID / 8);
  k_cvt<<<512, 256, 0, stream>>>(Wout, Woutb, HID * HID / 8);
  k_cvt<<<16, 256, 0, stream>>>(h0, HS + (size_t)BT * HID, 2 * BATCH * HID / 8);

  dim3 tb(32, 8), tg(32, 32);
  k_tr<<<tg, tb, 0, stream>>>(Win, WinT);
  k_tr<<<tg, tb, 0, stream>>>(Wy,             Wy0T);
  k_tr<<<tg, tb, 0, stream>>>(Wy + HID * HID, Wy1T);

  // folded biases
  k_matvec<<<HID, 256, 0, stream>>>(Wh, b_in, nullptr, bias0);
  k_matvec<<<HID, 256, 0, stream>>>(Wff, bWy, bff, bc0);
  k_matvec<<<HID, 256, 0, stream>>>(Wff + HID * HID, bWy + HID, bff + HID, bc1);

  // depth lists
  k_depths<<<BATCH, 256, 0, stream>>>(start, pArr, cnts);
  k_offsets<<<1, 64, 0, stream>>>(cnts, offs, curs);
  k_build<<<BT / 256, 256, 0, stream>>>(pArr, curs, src0, src1, dstl);

  // combined weights: W0 = Wh0@Win, Wc_l = Wff_l@Wy_l  (k_deep: 8-step K loop)
  k_deep<0, false><<<dim3(8, 8), 256, 0, stream>>>(Wh0b, WinT, W0b, nullptr, HID,
      nullptr, nullptr, 0, nullptr, nullptr, nullptr, nullptr, nullptr, nullptr);
  k_deep<0, false><<<dim3(8, 8), 256, 0, stream>>>(Wff0b, Wy0T, Wc0b, nullptr, HID,
      nullptr, nullptr, 0, nullptr, nullptr, nullptr, nullptr, nullptr, nullptr);
  k_deep<0, false><<<dim3(8, 8), 256, 0, stream>>>(Wff1b, Wy1T, Wc1b, nullptr, HID,
      nullptr, nullptr, 0, nullptr, nullptr, nullptr, nullptr, nullptr, nullptr);

  // xp0 = emb @ W0^T + bias0
  k_gemm<0, false><<<dim3(8, 256), 256, 0, stream>>>(E, W0b, X1, bias0, BT,
      nullptr, nullptr, 0, nullptr, nullptr, nullptr, nullptr, nullptr, nullptr);

  // scan rounds: k_gemm for d0/d1 (ample TLP), k_deep for d>=2 (latency-floored)
  static const int gy[2] = {132, 66};
  static const int gyd[DTAIL - 2] = {42, 22, 12, 6, 4, 2, 2, 2, 1, 1, 1, 1, 1, 1, 1, 1};

  // layer 0 scan + exact tail
  for (int d = 0; d < 2; ++d)
    k_gemm<3, true><<<dim3(8, gy[d]), 256, 0, stream>>>(HS, Uhb, nullptr, nullptr, 0,
        cnts, offs, d, src0, dstl, X1, bUh, dout, HS);
  for (int d = 2; d < DTAIL; ++d)
    k_deep<3, true><<<dim3(8, gyd[d - 2]), 256, 0, stream>>>(HS, Uhb, nullptr, nullptr, 0,
        cnts, offs, d, src0, dstl, X1, bUh, dout, HS);
  k_tail<<<1, 1024, 0, stream>>>(cnts, offs, dstl, Uhb, bUh, X1, HS, dout);

  // layer_in1 = leaky_relu(hs0 @ Wc0^T + bc0)
  k_gemm<1, false><<<dim3(8, 256), 256, 0, stream>>>(HS, Wc0b, E, bc0, BT,
      nullptr, nullptr, 0, nullptr, nullptr, nullptr, nullptr, nullptr, nullptr);
  // xp1 = layer_in1 @ Wh1^T
  k_gemm<0, false><<<dim3(8, 256), 256, 0, stream>>>(E, Wh1b, X1, nullptr, BT,
      nullptr, nullptr, 0, nullptr, nullptr, nullptr, nullptr, nullptr, nullptr);

  // layer 1 scan + tail
  for (int d = 0; d < 2; ++d)
    k_gemm<3, true><<<dim3(8, gy[d]), 256, 0, stream>>>(HS, Uhb + HID * HID, nullptr, nullptr, 0,
        cnts, offs, d, src1, dstl, X1, bUh + HID, dout + BATCH * HID, HS);
  for (int d = 2; d < DTAIL; ++d)
    k_deep<3, true><<<dim3(8, gyd[d - 2]), 256, 0, stream>>>(HS, Uhb + HID * HID, nullptr, nullptr, 0,
        cnts, offs, d, src1, dstl, X1, bUh + HID, dout + BATCH * HID, HS);
  k_tail<<<1, 1024, 0, stream>>>(cnts, offs, dstl, Uhb + HID * HID, bUh + HID, X1, HS,
                                 dout + BATCH * HID);

  // layer_in2 = leaky_relu(hs1 @ Wc1^T + bc1)
  k_gemm<1, false><<<dim3(8, 256), 256, 0, stream>>>(HS, Wc1b, E, bc1, BT,
      nullptr, nullptr, 0, nullptr, nullptr, nullptr, nullptr, nullptr, nullptr);
  // out = layer_in2 @ Wout^T + b_out
  k_gemm<2, false><<<dim3(8, 256), 256, 0, stream>>>(E, Woutb, dout + 2 * BATCH * HID, b_out, BT,
      nullptr, nullptr, 0, nullptr, nullptr, nullptr, nullptr, nullptr, nullptr);
}

// Round 12
// 2042.107 us; speedup vs baseline: 1.2293x; 1.1536x over previous
//
#include <hip/hip_runtime.h>
#include <stdint.h>

#define T_LEN 2048
#define BATCH 16
#define HID   1024
#define BT    (BATCH * T_LEN)   // 32768
#define DTAIL 18                 // depths >= DTAIL go to the serial tail bucket
#define NBUCK (DTAIL + 1)

typedef short short8 __attribute__((ext_vector_type(8)));
typedef float f32x4  __attribute__((ext_vector_type(4)));
typedef unsigned int u32;
typedef unsigned short u16;

__device__ __forceinline__ u16 f2bf(float f) {          // RNE f32->bf16
  u32 u = __builtin_bit_cast(u32, f);
  u = (u + 0x7fffu + ((u >> 16) & 1u)) >> 16;
  return (u16)u;
}
__device__ __forceinline__ float bf2f(u16 h) {
  u32 u = ((u32)h) << 16;
  return __builtin_bit_cast(float, u);
}

// ---------- small utility kernels ----------
__global__ void k_dbg(float* o, float v) { o[0] = v; }

__global__ void k_cvt(const float* __restrict__ s, u16* __restrict__ d, int n8) {
  int i = blockIdx.x * blockDim.x + threadIdx.x;
  if (i >= n8) return;
  const float4* sp = (const float4*)s;
  float4 a = sp[i * 2], b = sp[i * 2 + 1];
  union { u16 h[8]; uint4 v; } o;
  o.h[0] = f2bf(a.x); o.h[1] = f2bf(a.y); o.h[2] = f2bf(a.z); o.h[3] = f2bf(a.w);
  o.h[4] = f2bf(b.x); o.h[5] = f2bf(b.y); o.h[6] = f2bf(b.z); o.h[7] = f2bf(b.w);
  ((uint4*)d)[i] = o.v;
}

// dst[i][h] = src[h][i], f32 -> bf16, 1024x1024
__global__ void k_tr(const float* __restrict__ src, u16* __restrict__ dst) {
  __shared__ float tile[32][33];
  int bx = blockIdx.x * 32, by = blockIdx.y * 32;
  int tx = threadIdx.x, ty = threadIdx.y;   // 32 x 8
#pragma unroll
  for (int j = 0; j < 4; ++j)
    tile[ty + j * 8][tx] = src[(size_t)(by + ty + j * 8) * HID + bx + tx];
  __syncthreads();
#pragma unroll
  for (int j = 0; j < 4; ++j)
    dst[(size_t)(bx + ty + j * 8) * HID + by + tx] = f2bf(tile[tx][ty + j * 8]);
}

// out[r] = sum_h W[r,h]*v[h] (+ add[r])
__global__ void k_matvec(const float* __restrict__ W, const float* __restrict__ v,
                         const float* __restrict__ add, float* __restrict__ out) {
  int r = blockIdx.x;
  float s = 0.f;
  for (int h = threadIdx.x; h < HID; h += 256)
    s += W[(size_t)r * HID + h] * v[h];
  for (int o = 32; o; o >>= 1) s += __shfl_down(s, o);
  __shared__ float ws_[4];
  if ((threadIdx.x & 63) == 0) ws_[threadIdx.x >> 6] = s;
  __syncthreads();
  if (threadIdx.x == 0) {
    s = ws_[0] + ws_[1] + ws_[2] + ws_[3];
    out[r] = s + (add ? add[r] : 0.f);
  }
}

// depth per (b,t) via parallel prefix-max of last-reset position.
__global__ __launch_bounds__(256) void k_depths(const void* startp, int* __restrict__ p,
                                                int* __restrict__ cnt) {
  __shared__ int tmax[256];
  __shared__ int lc[NBUCK];
  __shared__ int isIntSh;
  const int b = blockIdx.x;
  const int tid = threadIdx.x;
  if (tid < NBUCK) lc[tid] = 0;
  if (tid == 0) {
    const unsigned char* q = (const unsigned char*)startp;
    int nz = 0;
    for (int i = 0; i < 256; ++i) if ((i & 3) && q[i]) nz++;
    isIntSh = (nz == 0);
  }
  __syncthreads();
  const int isInt = isIntSh;
  int st[8], lastk[8];
  const int t0 = tid * 8;
  int last = -1;
#pragma unroll
  for (int k = 0; k < 8; ++k) {
    const int t = t0 + k;
    int s;
    if (isInt) s = ((const int*)startp)[b * T_LEN + t] != 0;
    else       s = ((const unsigned char*)startp)[b * T_LEN + t] != 0;
    st[k] = s;
    if (s || t == 0) last = t;
    lastk[k] = last;
  }
  tmax[tid] = last;
  __syncthreads();
  for (int off = 1; off < 256; off <<= 1) {
    int v = tmax[tid];
    int u = (tid >= off) ? tmax[tid - off] : -1;
    __syncthreads();
    tmax[tid] = v > u ? v : u;
    __syncthreads();
  }
  const int pre = (tid > 0) ? tmax[tid - 1] : -1;
#pragma unroll
  for (int k = 0; k < 8; ++k) {
    const int t = t0 + k;
    const int R = lastk[k] > pre ? lastk[k] : pre;
    int d = t - R;
    if (d > DTAIL) d = DTAIL;
    atomicAdd(&lc[d], 1);
    p[b * T_LEN + t] = st[k] ? ~d : d;
  }
  __syncthreads();
  if (tid < NBUCK && lc[tid]) atomicAdd(&cnt[tid], lc[tid]);
}

__global__ void k_offsets(const int* cnt, int* offs, int* cursors) {
  if (threadIdx.x == 0 && blockIdx.x == 0) {
    int s = 0;
    for (int d = 0; d < NBUCK; ++d) { offs[d] = s; cursors[d] = s; s += cnt[d]; }
  }
}

// build per-depth gather lists (wave-aggregated atomics)
__global__ void k_build(const int* __restrict__ p, int* cursors,
                        int* __restrict__ s0, int* __restrict__ s1, int* __restrict__ dl) {
  const int i = blockIdx.x * 256 + threadIdx.x;
  const int pv = p[i];
  const int d = pv < 0 ? ~pv : pv;
  const int isStart = pv < 0;
  const int lane = threadIdx.x & 63;
  int slot = -1;
  while (__ballot(slot < 0)) {
    unsigned long long m = __ballot(slot < 0);
    int leader = __ffsll((unsigned long long)m) - 1;
    int dle = __shfl(d, leader);
    unsigned long long grp = __ballot(slot < 0 && d == dle);
    if (slot < 0 && d == dle) {
      int base = 0;
      if (lane == leader) base = atomicAdd(&cursors[dle], (int)__popcll(grp));
      base = __shfl(base, leader);
      slot = base + (int)__popcll(grp & ((1ull << lane) - 1ull));
    }
  }
  const int b = i >> 11;
  int s;
  if (d == 0) s = isStart ? (BT + 32) : (BT + b);
  else        s = i - 1;
  s0[slot] = s;
  if (d == 0) s = isStart ? (BT + 32) : (BT + 16 + b);
  s1[slot] = s;
  dl[slot] = i;
}

// serial tail: items with depth >= DTAIL, ascending t order (exact).
__global__ __launch_bounds__(1024) void k_tail(
    const int* __restrict__ cnt, const int* __restrict__ offs, const int* __restrict__ dstl,
    const u16* __restrict__ Uw, const float* __restrict__ bu,
    const u16* __restrict__ xp, u16* hs, float* __restrict__ hfin) {
  const int n = cnt[DTAIL];
  if (n <= 0) return;
  const int lo = offs[DTAIL];
  __shared__ int idx[4096];
  const int tid = threadIdx.x;
  const int m = n > 4096 ? 4096 : n;
  if (tid == 0) {
    for (int i = 0; i < m; ++i) {
      int v = dstl[lo + i];
      int j = i;
      while (j > 0 && idx[j - 1] > v) { idx[j] = idx[j - 1]; --j; }
      idx[j] = v;
    }
  }
  __syncthreads();
  const int col = tid;
  for (int e = 0; e < m; ++e) {
    const int i = idx[e];
    const u16* hp = hs + (size_t)(i - 1) * HID;
    const u16* ur = Uw + (size_t)col * HID;
    float acc = 0.f;
    for (int r = 0; r < HID; ++r) acc += bf2f(ur[r]) * bf2f(hp[r]);
    const float v = acc + bu[col] + bf2f(xp[(size_t)i * HID + col]);
    const float hval = tanhf(v);
    hs[(size_t)i * HID + col] = f2bf(hval);
    if ((i & (T_LEN - 1)) == T_LEN - 1) hfin[(i >> 11) * HID + col] = hval;
    __threadfence_block();
    __syncthreads();
  }
}

// ---------- 128^2 GEMM, BK=128 (k_deep): 8 K-steps, 4x fewer exposed stage drains ----------
// Single-buffered 64 KiB LDS, 2 blocks/CU. LDS layout: [128 rows][16 slots of 8 u16];
// logical chunk g lives at slot g^(row&15) (store side: pre-swizzled per-lane global
// column; read side: slot=(s*4+p)^fr) -> ds_read_b128 is 2-way on banks (free).
template <int EPI, bool GATHER>
__global__ __launch_bounds__(256) void k_deep(
    const u16* __restrict__ A, const u16* __restrict__ B, void* __restrict__ C,
    const float* __restrict__ bias, int M,
    const int* __restrict__ cnt, const int* __restrict__ offs, int d,
    const int* __restrict__ srcl, const int* __restrict__ dstl,
    const u16* __restrict__ xp, const float* __restrict__ bu,
    float* __restrict__ hfin, u16* hs) {
  __shared__ u16 As[128 * 128];   // 32 KiB
  __shared__ u16 Bs[128 * 128];   // 32 KiB
  const int tid = threadIdx.x;
  const int l = tid & 63;
  const int wv = tid >> 6;
  int Mt = M, lo = 0;
  if (GATHER) { Mt = cnt[d]; lo = offs[d]; if (Mt <= 0) return; }
  const int n0 = blockIdx.x * 128;
  const int wm = (wv >> 1) * 64;
  const int wn = (wv & 1) * 64;
  const int fr = l & 15;
  const int p  = l >> 4;          // 0..3

  for (int mb = blockIdx.y; mb * 128 < Mt; mb += gridDim.y) {
    const int m0 = mb * 128;
    // staging instr i (i=0..7): rows rowbase = wv*32+i*4 (+p), slot l&15,
    // carrying logical chunk g = (l&15) ^ ((i*4)&12) ^ p  -> global u16 col g*8
    const u16* aptr[8];
    const u16* bptr[8];
#pragma unroll
    for (int i = 0; i < 8; ++i) {
      const int g = ((l & 15) ^ ((i * 4) & 12) ^ p) * 8;
      int gr = m0 + wv * 32 + i * 4 + p;
      if (gr > Mt - 1) gr = Mt - 1;                    // tail clamp (masked at store)
      if (GATHER) gr = srcl[lo + gr];
      aptr[i] = A + (size_t)gr * HID + g;
      bptr[i] = B + (size_t)(n0 + wv * 32 + i * 4 + p) * HID + g;
    }
    f32x4 acc[4][4] = {};
    for (int t = 0; t < 8; ++t) {
      const int k0 = t * 128;
      __syncthreads();
#pragma unroll
      for (int i = 0; i < 8; ++i) {
        __builtin_amdgcn_global_load_lds(
            (const __attribute__((address_space(1))) void*)(aptr[i] + k0),
            (__attribute__((address_space(3))) void*)(As + (wv * 32 + i * 4) * 128), 16, 0, 0);
        __builtin_amdgcn_global_load_lds(
            (const __attribute__((address_space(1))) void*)(bptr[i] + k0),
            (__attribute__((address_space(3))) void*)(Bs + (wv * 32 + i * 4) * 128), 16, 0, 0);
      }
      __syncthreads();
#pragma unroll
      for (int s = 0; s < 4; ++s) {
        const int slot = ((s * 4 + p) ^ fr) * 8;
        short8 af[4], bf_[4];
#pragma unroll
        for (int f = 0; f < 4; ++f) {
          af[f]  = *(const short8*)(As + (wm + f * 16 + fr) * 128 + slot);
          bf_[f] = *(const short8*)(Bs + (wn + f * 16 + fr) * 128 + slot);
        }
#pragma unroll
        for (int mi = 0; mi < 4; ++mi)
#pragma unroll
          for (int ni = 0; ni < 4; ++ni)
            acc[mi][ni] = __builtin_amdgcn_mfma_f32_16x16x32_bf16(af[mi], bf_[ni], acc[mi][ni], 0, 0, 0);
      }
    }
#pragma unroll
    for (int mi = 0; mi < 4; ++mi) {
      const int r0 = m0 + wm + mi * 16 + ((l >> 4) << 2);
#pragma unroll
      for (int ni = 0; ni < 4; ++ni) {
        const int col = n0 + wn + ni * 16 + fr;
        float bv;
        if (EPI == 3) bv = bu[col];
        else          bv = bias ? bias[col] : 0.0f;
#pragma unroll
        for (int j = 0; j < 4; ++j) {
          const int row = r0 + j;
          if (row >= Mt) continue;
          float v = acc[mi][ni][j] + bv;
          if (EPI == 0) {
            ((u16*)C)[(size_t)row * HID + col] = f2bf(v);
          } else if (EPI == 1) {
            v = v > 0.0f ? v : 0.01f * v;
            ((u16*)C)[(size_t)row * HID + col] = f2bf(v);
          } else if (EPI == 2) {
            ((float*)C)[(size_t)row * HID + col] = v;
          } else {
            const int dsti = dstl[lo + row];
            v += bf2f(xp[(size_t)dsti * HID + col]);
            const float hval = tanhf(v);
            hs[(size_t)dsti * HID + col] = f2bf(hval);
            if ((dsti & (T_LEN - 1)) == T_LEN - 1)
              hfin[(dsti >> 11) * HID + col] = hval;
          }
        }
      }
    }
  }
}

// ---------- host ----------
extern "C" void kernel_launch(void* const* d_in, const int* in_sizes, int n_in,
                              void* d_out, int out_size, void* d_ws, size_t ws_size,
                              hipStream_t stream) {
  (void)in_sizes; (void)n_in; (void)out_size;
  const float* emb   = (const float*)d_in[0];
  const void*  start = d_in[1];
  const float* h0    = (const float*)d_in[2];
  const float* Win   = (const float*)d_in[3];
  const float* b_in  = (const float*)d_in[4];
  const float* Wout  = (const float*)d_in[5];
  const float* b_out = (const float*)d_in[6];
  const float* Uh    = (const float*)d_in[7];
  const float* bUh   = (const float*)d_in[8];
  const float* Wh    = (const float*)d_in[9];
  const float* Wy    = (const float*)d_in[10];
  const float* bWy   = (const float*)d_in[11];
  const float* Wff   = (const float*)d_in[12];
  const float* bff   = (const float*)d_in[13];
  float* dout = (float*)d_out;

  char* w = (char*)d_ws;
  auto alloc = [&](size_t b) { char* r = w; w += (b + 255) & ~(size_t)255; return r; };
  u16* E     = (u16*)alloc((size_t)BT * HID * 2);
  u16* X1    = (u16*)alloc((size_t)BT * HID * 2);
  u16* HS    = (u16*)alloc((size_t)(BT + 33) * HID * 2);
  u16* W0b   = (u16*)alloc((size_t)HID * HID * 2);
  u16* Wc0b  = (u16*)alloc((size_t)HID * HID * 2);
  u16* Wc1b  = (u16*)alloc((size_t)HID * HID * 2);
  u16* Wh1b  = (u16*)alloc((size_t)HID * HID * 2);
  u16* Woutb = (u16*)alloc((size_t)HID * HID * 2);
  u16* Uhb   = (u16*)alloc((size_t)2 * HID * HID * 2);
  u16* Wh0b  = (u16*)alloc((size_t)HID * HID * 2);
  u16* Wff0b = (u16*)alloc((size_t)HID * HID * 2);
  u16* Wff1b = (u16*)alloc((size_t)HID * HID * 2);
  u16* WinT  = (u16*)alloc((size_t)HID * HID * 2);
  u16* Wy0T  = (u16*)alloc((size_t)HID * HID * 2);
  u16* Wy1T  = (u16*)alloc((size_t)HID * HID * 2);
  float* bias0 = (float*)alloc(HID * 4);
  float* bc0   = (float*)alloc(HID * 4);
  float* bc1   = (float*)alloc(HID * 4);
  int* pArr = (int*)alloc(BT * 4);
  int* src0 = (int*)alloc(BT * 4);
  int* src1 = (int*)alloc(BT * 4);
  int* dstl = (int*)alloc(BT * 4);
  int* cnts = (int*)alloc(64 * 4);
  int* offs = (int*)alloc(64 * 4);
  int* curs = (int*)alloc(64 * 4);

  if ((size_t)(w - (char*)d_ws) > ws_size) {
    k_dbg<<<1, 1, 0, stream>>>(dout, (float)ws_size);
    return;
  }

  hipMemsetAsync(cnts, 0, NBUCK * 4, stream);
  hipMemsetAsync(HS + (size_t)(BT + 32) * HID, 0, HID * 2, stream);

  // converts (f32 -> bf16)
  k_cvt<<<(BT * HID / 8 + 255) / 256, 256, 0, stream>>>(emb, E, BT * HID / 8);
  k_cvt<<<1024, 256, 0, stream>>>(Uh, Uhb, 2 * HID * HID / 8);
  k_cvt<<<512, 256, 0, stream>>>(Wh,             Wh0b,  HID * HID / 8);
  k_cvt<<<512, 256, 0, stream>>>(Wh + HID * HID, Wh1b,  HID * HID / 8);
  k_cvt<<<512, 256, 0, stream>>>(Wff,             Wff0b, HID * HID / 8);
  k_cvt<<<512, 256, 0, stream>>>(Wff + HID * HID, Wff1b, HID * HID / 8);
  k_cvt<<<512, 256, 0, stream>>>(Wout, Woutb, HID * HID / 8);
  k_cvt<<<16, 256, 0, stream>>>(h0, HS + (size_t)BT * HID, 2 * BATCH * HID / 8);

  dim3 tb(32, 8), tg(32, 32);
  k_tr<<<tg, tb, 0, stream>>>(Win, WinT);
  k_tr<<<tg, tb, 0, stream>>>(Wy,             Wy0T);
  k_tr<<<tg, tb, 0, stream>>>(Wy + HID * HID, Wy1T);

  // folded biases
  k_matvec<<<HID, 256, 0, stream>>>(Wh, b_in, nullptr, bias0);
  k_matvec<<<HID, 256, 0, stream>>>(Wff, bWy, bff, bc0);
  k_matvec<<<HID, 256, 0, stream>>>(Wff + HID * HID, bWy + HID, bff + HID, bc1);

  // depth lists
  k_depths<<<BATCH, 256, 0, stream>>>(start, pArr, cnts);
  k_offsets<<<1, 64, 0, stream>>>(cnts, offs, curs);
  k_build<<<BT / 256, 256, 0, stream>>>(pArr, curs, src0, src1, dstl);

  // combined weights: W0 = Wh0@Win, Wc_l = Wff_l@Wy_l
  k_deep<0, false><<<dim3(8, 8), 256, 0, stream>>>(Wh0b, WinT, W0b, nullptr, HID,
      nullptr, nullptr, 0, nullptr, nullptr, nullptr, nullptr, nullptr, nullptr);
  k_deep<0, false><<<dim3(8, 8), 256, 0, stream>>>(Wff0b, Wy0T, Wc0b, nullptr, HID,
      nullptr, nullptr, 0, nullptr, nullptr, nullptr, nullptr, nullptr, nullptr);
  k_deep<0, false><<<dim3(8, 8), 256, 0, stream>>>(Wff1b, Wy1T, Wc1b, nullptr, HID,
      nullptr, nullptr, 0, nullptr, nullptr, nullptr, nullptr, nullptr, nullptr);

  // xp0 = emb @ W0^T + bias0   (k_deep, BK=128)
  k_deep<0, false><<<dim3(8, 256), 256, 0, stream>>>(E, W0b, X1, bias0, BT,
      nullptr, nullptr, 0, nullptr, nullptr, nullptr, nullptr, nullptr, nullptr);

  // scan rounds: all k_deep (grid-stride covers any overflow)
  static const int gyd[DTAIL] = {132, 66, 42, 22, 12, 6, 4, 2, 2, 2, 1, 1, 1, 1, 1, 1, 1, 1};

  // layer 0 scan + exact tail
  for (int d = 0; d < DTAIL; ++d)
    k_deep<3, true><<<dim3(8, gyd[d]), 256, 0, stream>>>(HS, Uhb, nullptr, nullptr, 0,
        cnts, offs, d, src0, dstl, X1, bUh, dout, HS);
  k_tail<<<1, 1024, 0, stream>>>(cnts, offs, dstl, Uhb, bUh, X1, HS, dout);

  // layer_in1 = leaky_relu(hs0 @ Wc0^T + bc0)
  k_deep<1, false><<<dim3(8, 256), 256, 0, stream>>>(HS, Wc0b, E, bc0, BT,
      nullptr, nullptr, 0, nullptr, nullptr, nullptr, nullptr, nullptr, nullptr);
  // xp1 = layer_in1 @ Wh1^T
  k_deep<0, false><<<dim3(8, 256), 256, 0, stream>>>(E, Wh1b, X1, nullptr, BT,
      nullptr, nullptr, 0, nullptr, nullptr, nullptr, nullptr, nullptr, nullptr);

  // layer 1 scan + tail
  for (int d = 0; d < DTAIL; ++d)
    k_deep<3, true><<<dim3(8, gyd[d]), 256, 0, stream>>>(HS, Uhb + HID * HID, nullptr, nullptr, 0,
        cnts, offs, d, src1, dstl, X1, bUh + HID, dout + BATCH * HID, HS);
  k_tail<<<1, 1024, 0, stream>>>(cnts, offs, dstl, Uhb + HID * HID, bUh + HID, X1, HS,
                                 dout + BATCH * HID);

  // layer_in2 = leaky_relu(hs1 @ Wc1^T + bc1)
  k_deep<1, false><<<dim3(8, 256), 256, 0, stream>>>(HS, Wc1b, E, bc1, BT,
      nullptr, nullptr, 0, nullptr, nullptr, nullptr, nullptr, nullptr, nullptr);
  // out = layer_in2 @ Wout^T + b_out
  k_deep<2, false><<<dim3(8, 256), 256, 0, stream>>>(E, Woutb, dout + 2 * BATCH * HID, b_out, BT,
      nullptr, nullptr, 0, nullptr, nullptr, nullptr, nullptr, nullptr, nullptr);
}

// Round 13
// 1944.038 us; speedup vs baseline: 1.2913x; 1.0504x over previous
//
#include <hip/hip_runtime.h>
#include <stdint.h>

#define T_LEN 2048
#define BATCH 16
#define HID   1024
#define BT    (BATCH * T_LEN)   // 32768
#define DTAIL 18                 // depths >= DTAIL go to the serial tail bucket
#define NBUCK (DTAIL + 1)

typedef short short8 __attribute__((ext_vector_type(8)));
typedef float f32x4  __attribute__((ext_vector_type(4)));
typedef unsigned int u32;
typedef unsigned short u16;

__device__ __forceinline__ u16 f2bf(float f) {          // RNE f32->bf16
  u32 u = __builtin_bit_cast(u32, f);
  u = (u + 0x7fffu + ((u >> 16) & 1u)) >> 16;
  return (u16)u;
}
__device__ __forceinline__ float bf2f(u16 h) {
  u32 u = ((u32)h) << 16;
  return __builtin_bit_cast(float, u);
}

// ---------- small utility kernels ----------
__global__ void k_dbg(float* o, float v) { o[0] = v; }

__global__ void k_cvt(const float* __restrict__ s, u16* __restrict__ d, int n8) {
  int i = blockIdx.x * blockDim.x + threadIdx.x;
  if (i >= n8) return;
  const float4* sp = (const float4*)s;
  float4 a = sp[i * 2], b = sp[i * 2 + 1];
  union { u16 h[8]; uint4 v; } o;
  o.h[0] = f2bf(a.x); o.h[1] = f2bf(a.y); o.h[2] = f2bf(a.z); o.h[3] = f2bf(a.w);
  o.h[4] = f2bf(b.x); o.h[5] = f2bf(b.y); o.h[6] = f2bf(b.z); o.h[7] = f2bf(b.w);
  ((uint4*)d)[i] = o.v;
}

// dst[i][h] = src[h][i], f32 -> bf16, 1024x1024
__global__ void k_tr(const float* __restrict__ src, u16* __restrict__ dst) {
  __shared__ float tile[32][33];
  int bx = blockIdx.x * 32, by = blockIdx.y * 32;
  int tx = threadIdx.x, ty = threadIdx.y;   // 32 x 8
#pragma unroll
  for (int j = 0; j < 4; ++j)
    tile[ty + j * 8][tx] = src[(size_t)(by + ty + j * 8) * HID + bx + tx];
  __syncthreads();
#pragma unroll
  for (int j = 0; j < 4; ++j)
    dst[(size_t)(bx + ty + j * 8) * HID + by + tx] = f2bf(tile[tx][ty + j * 8]);
}

// out[r] = sum_h W[r,h]*v[h] (+ add[r])
__global__ void k_matvec(const float* __restrict__ W, const float* __restrict__ v,
                         const float* __restrict__ add, float* __restrict__ out) {
  int r = blockIdx.x;
  float s = 0.f;
  for (int h = threadIdx.x; h < HID; h += 256)
    s += W[(size_t)r * HID + h] * v[h];
  for (int o = 32; o; o >>= 1) s += __shfl_down(s, o);
  __shared__ float ws_[4];
  if ((threadIdx.x & 63) == 0) ws_[threadIdx.x >> 6] = s;
  __syncthreads();
  if (threadIdx.x == 0) {
    s = ws_[0] + ws_[1] + ws_[2] + ws_[3];
    out[r] = s + (add ? add[r] : 0.f);
  }
}

// depth per (b,t) via parallel prefix-max of last-reset position.
__global__ __launch_bounds__(256) void k_depths(const void* startp, int* __restrict__ p,
                                                int* __restrict__ cnt) {
  __shared__ int tmax[256];
  __shared__ int lc[NBUCK];
  __shared__ int isIntSh;
  const int b = blockIdx.x;
  const int tid = threadIdx.x;
  if (tid < NBUCK) lc[tid] = 0;
  if (tid == 0) {
    const unsigned char* q = (const unsigned char*)startp;
    int nz = 0;
    for (int i = 0; i < 256; ++i) if ((i & 3) && q[i]) nz++;
    isIntSh = (nz == 0);
  }
  __syncthreads();
  const int isInt = isIntSh;
  int st[8], lastk[8];
  const int t0 = tid * 8;
  int last = -1;
#pragma unroll
  for (int k = 0; k < 8; ++k) {
    const int t = t0 + k;
    int s;
    if (isInt) s = ((const int*)startp)[b * T_LEN + t] != 0;
    else       s = ((const unsigned char*)startp)[b * T_LEN + t] != 0;
    st[k] = s;
    if (s || t == 0) last = t;
    lastk[k] = last;
  }
  tmax[tid] = last;
  __syncthreads();
  for (int off = 1; off < 256; off <<= 1) {
    int v = tmax[tid];
    int u = (tid >= off) ? tmax[tid - off] : -1;
    __syncthreads();
    tmax[tid] = v > u ? v : u;
    __syncthreads();
  }
  const int pre = (tid > 0) ? tmax[tid - 1] : -1;
#pragma unroll
  for (int k = 0; k < 8; ++k) {
    const int t = t0 + k;
    const int R = lastk[k] > pre ? lastk[k] : pre;
    int d = t - R;
    if (d > DTAIL) d = DTAIL;
    atomicAdd(&lc[d], 1);
    p[b * T_LEN + t] = st[k] ? ~d : d;
  }
  __syncthreads();
  if (tid < NBUCK && lc[tid]) atomicAdd(&cnt[tid], lc[tid]);
}

__global__ void k_offsets(const int* cnt, int* offs, int* cursors) {
  if (threadIdx.x == 0 && blockIdx.x == 0) {
    int s = 0;
    for (int d = 0; d < NBUCK; ++d) { offs[d] = s; cursors[d] = s; s += cnt[d]; }
  }
}

// build per-depth gather lists (wave-aggregated atomics)
__global__ void k_build(const int* __restrict__ p, int* cursors,
                        int* __restrict__ s0, int* __restrict__ s1, int* __restrict__ dl) {
  const int i = blockIdx.x * 256 + threadIdx.x;
  const int pv = p[i];
  const int d = pv < 0 ? ~pv : pv;
  const int isStart = pv < 0;
  const int lane = threadIdx.x & 63;
  int slot = -1;
  while (__ballot(slot < 0)) {
    unsigned long long m = __ballot(slot < 0);
    int leader = __ffsll((unsigned long long)m) - 1;
    int dle = __shfl(d, leader);
    unsigned long long grp = __ballot(slot < 0 && d == dle);
    if (slot < 0 && d == dle) {
      int base = 0;
      if (lane == leader) base = atomicAdd(&cursors[dle], (int)__popcll(grp));
      base = __shfl(base, leader);
      slot = base + (int)__popcll(grp & ((1ull << lane) - 1ull));
    }
  }
  const int b = i >> 11;
  int s;
  if (d == 0) s = isStart ? (BT + 32) : (BT + b);
  else        s = i - 1;
  s0[slot] = s;
  if (d == 0) s = isStart ? (BT + 32) : (BT + 16 + b);
  s1[slot] = s;
  dl[slot] = i;
}

// serial tail: items with depth >= DTAIL, ascending t order (exact).
__global__ __launch_bounds__(1024) void k_tail(
    const int* __restrict__ cnt, const int* __restrict__ offs, const int* __restrict__ dstl,
    const u16* __restrict__ Uw, const float* __restrict__ bu,
    const u16* __restrict__ xp, u16* hs, float* __restrict__ hfin) {
  const int n = cnt[DTAIL];
  if (n <= 0) return;
  const int lo = offs[DTAIL];
  __shared__ int idx[4096];
  const int tid = threadIdx.x;
  const int m = n > 4096 ? 4096 : n;
  if (tid == 0) {
    for (int i = 0; i < m; ++i) {
      int v = dstl[lo + i];
      int j = i;
      while (j > 0 && idx[j - 1] > v) { idx[j] = idx[j - 1]; --j; }
      idx[j] = v;
    }
  }
  __syncthreads();
  const int col = tid;
  for (int e = 0; e < m; ++e) {
    const int i = idx[e];
    const u16* hp = hs + (size_t)(i - 1) * HID;
    const u16* ur = Uw + (size_t)col * HID;
    float acc = 0.f;
    for (int r = 0; r < HID; ++r) acc += bf2f(ur[r]) * bf2f(hp[r]);
    const float v = acc + bu[col] + bf2f(xp[(size_t)i * HID + col]);
    const float hval = tanhf(v);
    hs[(size_t)i * HID + col] = f2bf(hval);
    if ((i & (T_LEN - 1)) == T_LEN - 1) hfin[(i >> 11) * HID + col] = hval;
    __threadfence_block();
    __syncthreads();
  }
}

// ---------- 128^2 GEMM, BK=128 (k_deep): 8 K-steps + XCD panel co-location ----------
// Block-index swizzle: dispatch id D (x-fastest), XCD = D%8. Map so all 8 n-blocks of
// an M-panel land on the SAME XCD in consecutive slots: c=D&7, q=D>>3 ->
// n0=(q&7)*128, m0=((q>>3)<<3)+c. XCD c touches only panels m%8==c: per-GEMM A
// traffic through L3 drops 512 MB -> 64 MB (old mapping: XCD=x -> every XCD
// streamed ALL of A). gridDim.y (= #m-panels) must be a multiple of 8.
// LDS: [128 rows][16 slots of 8 u16], chunk g at slot g^(row&15) (pre-swizzled
// source; read slot=(s*4+p)^fr) -> conflict-free, verified BANK_CONFLICT=0.
template <int EPI, bool GATHER>
__global__ __launch_bounds__(256) void k_deep(
    const u16* __restrict__ A, const u16* __restrict__ B, void* __restrict__ C,
    const float* __restrict__ bias, int M,
    const int* __restrict__ cnt, const int* __restrict__ offs, int d,
    const int* __restrict__ srcl, const int* __restrict__ dstl,
    const u16* __restrict__ xp, const float* __restrict__ bu,
    float* __restrict__ hfin, u16* hs) {
  __shared__ u16 As[128 * 128];   // 32 KiB
  __shared__ u16 Bs[128 * 128];   // 32 KiB
  const int tid = threadIdx.x;
  const int l = tid & 63;
  const int wv = tid >> 6;
  int Mt = M, lo = 0;
  if (GATHER) { Mt = cnt[d]; lo = offs[d]; if (Mt <= 0) return; }

  // XCD panel co-location swizzle
  const int D = blockIdx.y * gridDim.x + blockIdx.x;   // dispatch order, x fastest
  const int xcd = D & 7;
  const int q = D >> 3;
  const int n0 = (q & 7) * 128;
  const int by0 = ((q >> 3) << 3) + xcd;

  const int wm = (wv >> 1) * 64;
  const int wn = (wv & 1) * 64;
  const int fr = l & 15;
  const int p  = l >> 4;          // 0..3

  for (int mb = by0; mb * 128 < Mt; mb += gridDim.y) {
    const int m0 = mb * 128;
    // staging instr i (i=0..7): rows rowbase = wv*32+i*4 (+p), slot l&15,
    // carrying logical chunk g = (l&15) ^ ((i*4)&12) ^ p  -> global u16 col g*8
    const u16* aptr[8];
    const u16* bptr[8];
#pragma unroll
    for (int i = 0; i < 8; ++i) {
      const int g = ((l & 15) ^ ((i * 4) & 12) ^ p) * 8;
      int gr = m0 + wv * 32 + i * 4 + p;
      if (gr > Mt - 1) gr = Mt - 1;                    // tail clamp (masked at store)
      if (GATHER) gr = srcl[lo + gr];
      aptr[i] = A + (size_t)gr * HID + g;
      bptr[i] = B + (size_t)(n0 + wv * 32 + i * 4 + p) * HID + g;
    }
    f32x4 acc[4][4] = {};
    for (int t = 0; t < 8; ++t) {
      const int k0 = t * 128;
      __syncthreads();
#pragma unroll
      for (int i = 0; i < 8; ++i) {
        __builtin_amdgcn_global_load_lds(
            (const __attribute__((address_space(1))) void*)(aptr[i] + k0),
            (__attribute__((address_space(3))) void*)(As + (wv * 32 + i * 4) * 128), 16, 0, 0);
        __builtin_amdgcn_global_load_lds(
            (const __attribute__((address_space(1))) void*)(bptr[i] + k0),
            (__attribute__((address_space(3))) void*)(Bs + (wv * 32 + i * 4) * 128), 16, 0, 0);
      }
      __syncthreads();
#pragma unroll
      for (int s = 0; s < 4; ++s) {
        const int slot = ((s * 4 + p) ^ fr) * 8;
        short8 af[4], bf_[4];
#pragma unroll
        for (int f = 0; f < 4; ++f) {
          af[f]  = *(const short8*)(As + (wm + f * 16 + fr) * 128 + slot);
          bf_[f] = *(const short8*)(Bs + (wn + f * 16 + fr) * 128 + slot);
        }
#pragma unroll
        for (int mi = 0; mi < 4; ++mi)
#pragma unroll
          for (int ni = 0; ni < 4; ++ni)
            acc[mi][ni] = __builtin_amdgcn_mfma_f32_16x16x32_bf16(af[mi], bf_[ni], acc[mi][ni], 0, 0, 0);
      }
    }
#pragma unroll
    for (int mi = 0; mi < 4; ++mi) {
      const int r0 = m0 + wm + mi * 16 + ((l >> 4) << 2);
#pragma unroll
      for (int ni = 0; ni < 4; ++ni) {
        const int col = n0 + wn + ni * 16 + fr;
        float bv;
        if (EPI == 3) bv = bu[col];
        else          bv = bias ? bias[col] : 0.0f;
#pragma unroll
        for (int j = 0; j < 4; ++j) {
          const int row = r0 + j;
          if (row >= Mt) continue;
          float v = acc[mi][ni][j] + bv;
          if (EPI == 0) {
            ((u16*)C)[(size_t)row * HID + col] = f2bf(v);
          } else if (EPI == 1) {
            v = v > 0.0f ? v : 0.01f * v;
            ((u16*)C)[(size_t)row * HID + col] = f2bf(v);
          } else if (EPI == 2) {
            ((float*)C)[(size_t)row * HID + col] = v;
          } else {
            const int dsti = dstl[lo + row];
            v += bf2f(xp[(size_t)dsti * HID + col]);
            const float hval = tanhf(v);
            hs[(size_t)dsti * HID + col] = f2bf(hval);
            if ((dsti & (T_LEN - 1)) == T_LEN - 1)
              hfin[(dsti >> 11) * HID + col] = hval;
          }
        }
      }
    }
  }
}

// ---------- host ----------
extern "C" void kernel_launch(void* const* d_in, const int* in_sizes, int n_in,
                              void* d_out, int out_size, void* d_ws, size_t ws_size,
                              hipStream_t stream) {
  (void)in_sizes; (void)n_in; (void)out_size;
  const float* emb   = (const float*)d_in[0];
  const void*  start = d_in[1];
  const float* h0    = (const float*)d_in[2];
  const float* Win   = (const float*)d_in[3];
  const float* b_in  = (const float*)d_in[4];
  const float* Wout  = (const float*)d_in[5];
  const float* b_out = (const float*)d_in[6];
  const float* Uh    = (const float*)d_in[7];
  const float* bUh   = (const float*)d_in[8];
  const float* Wh    = (const float*)d_in[9];
  const float* Wy    = (const float*)d_in[10];
  const float* bWy   = (const float*)d_in[11];
  const float* Wff   = (const float*)d_in[12];
  const float* bff   = (const float*)d_in[13];
  float* dout = (float*)d_out;

  char* w = (char*)d_ws;
  auto alloc = [&](size_t b) { char* r = w; w += (b + 255) & ~(size_t)255; return r; };
  u16* E     = (u16*)alloc((size_t)BT * HID * 2);
  u16* X1    = (u16*)alloc((size_t)BT * HID * 2);
  u16* HS    = (u16*)alloc((size_t)(BT + 33) * HID * 2);
  u16* W0b   = (u16*)alloc((size_t)HID * HID * 2);
  u16* Wc0b  = (u16*)alloc((size_t)HID * HID * 2);
  u16* Wc1b  = (u16*)alloc((size_t)HID * HID * 2);
  u16* Wh1b  = (u16*)alloc((size_t)HID * HID * 2);
  u16* Woutb = (u16*)alloc((size_t)HID * HID * 2);
  u16* Uhb   = (u16*)alloc((size_t)2 * HID * HID * 2);
  u16* Wh0b  = (u16*)alloc((size_t)HID * HID * 2);
  u16* Wff0b = (u16*)alloc((size_t)HID * HID * 2);
  u16* Wff1b = (u16*)alloc((size_t)HID * HID * 2);
  u16* WinT  = (u16*)alloc((size_t)HID * HID * 2);
  u16* Wy0T  = (u16*)alloc((size_t)HID * HID * 2);
  u16* Wy1T  = (u16*)alloc((size_t)HID * HID * 2);
  float* bias0 = (float*)alloc(HID * 4);
  float* bc0   = (float*)alloc(HID * 4);
  float* bc1   = (float*)alloc(HID * 4);
  int* pArr = (int*)alloc(BT * 4);
  int* src0 = (int*)alloc(BT * 4);
  int* src1 = (int*)alloc(BT * 4);
  int* dstl = (int*)alloc(BT * 4);
  int* cnts = (int*)alloc(64 * 4);
  int* offs = (int*)alloc(64 * 4);
  int* curs = (int*)alloc(64 * 4);

  if ((size_t)(w - (char*)d_ws) > ws_size) {
    k_dbg<<<1, 1, 0, stream>>>(dout, (float)ws_size);
    return;
  }

  hipMemsetAsync(cnts, 0, NBUCK * 4, stream);
  hipMemsetAsync(HS + (size_t)(BT + 32) * HID, 0, HID * 2, stream);

  // converts (f32 -> bf16)
  k_cvt<<<(BT * HID / 8 + 255) / 256, 256, 0, stream>>>(emb, E, BT * HID / 8);
  k_cvt<<<1024, 256, 0, stream>>>(Uh, Uhb, 2 * HID * HID / 8);
  k_cvt<<<512, 256, 0, stream>>>(Wh,             Wh0b,  HID * HID / 8);
  k_cvt<<<512, 256, 0, stream>>>(Wh + HID * HID, Wh1b,  HID * HID / 8);
  k_cvt<<<512, 256, 0, stream>>>(Wff,             Wff0b, HID * HID / 8);
  k_cvt<<<512, 256, 0, stream>>>(Wff + HID * HID, Wff1b, HID * HID / 8);
  k_cvt<<<512, 256, 0, stream>>>(Wout, Woutb, HID * HID / 8);
  k_cvt<<<16, 256, 0, stream>>>(h0, HS + (size_t)BT * HID, 2 * BATCH * HID / 8);

  dim3 tb(32, 8), tg(32, 32);
  k_tr<<<tg, tb, 0, stream>>>(Win, WinT);
  k_tr<<<tg, tb, 0, stream>>>(Wy,             Wy0T);
  k_tr<<<tg, tb, 0, stream>>>(Wy + HID * HID, Wy1T);

  // folded biases
  k_matvec<<<HID, 256, 0, stream>>>(Wh, b_in, nullptr, bias0);
  k_matvec<<<HID, 256, 0, stream>>>(Wff, bWy, bff, bc0);
  k_matvec<<<HID, 256, 0, stream>>>(Wff + HID * HID, bWy + HID, bff + HID, bc1);

  // depth lists
  k_depths<<<BATCH, 256, 0, stream>>>(start, pArr, cnts);
  k_offsets<<<1, 64, 0, stream>>>(cnts, offs, curs);
  k_build<<<BT / 256, 256, 0, stream>>>(pArr, curs, src0, src1, dstl);

  // combined weights: W0 = Wh0@Win, Wc_l = Wff_l@Wy_l
  k_deep<0, false><<<dim3(8, 8), 256, 0, stream>>>(Wh0b, WinT, W0b, nullptr, HID,
      nullptr, nullptr, 0, nullptr, nullptr, nullptr, nullptr, nullptr, nullptr);
  k_deep<0, false><<<dim3(8, 8), 256, 0, stream>>>(Wff0b, Wy0T, Wc0b, nullptr, HID,
      nullptr, nullptr, 0, nullptr, nullptr, nullptr, nullptr, nullptr, nullptr);
  k_deep<0, false><<<dim3(8, 8), 256, 0, stream>>>(Wff1b, Wy1T, Wc1b, nullptr, HID,
      nullptr, nullptr, 0, nullptr, nullptr, nullptr, nullptr, nullptr, nullptr);

  // xp0 = emb @ W0^T + bias0
  k_deep<0, false><<<dim3(8, 256), 256, 0, stream>>>(E, W0b, X1, bias0, BT,
      nullptr, nullptr, 0, nullptr, nullptr, nullptr, nullptr, nullptr, nullptr);

  // scan rounds (y-dims multiples of 8 for the XCD swizzle; grid-stride covers overflow)
  static const int gyd[DTAIL] = {128, 64, 32, 16, 8, 8, 8, 8, 8, 8, 8, 8, 8, 8, 8, 8, 8, 8};

  // layer 0 scan + exact tail
  for (int d = 0; d < DTAIL; ++d)
    k_deep<3, true><<<dim3(8, gyd[d]), 256, 0, stream>>>(HS, Uhb, nullptr, nullptr, 0,
        cnts, offs, d, src0, dstl, X1, bUh, dout, HS);
  k_tail<<<1, 1024, 0, stream>>>(cnts, offs, dstl, Uhb, bUh, X1, HS, dout);

  // layer_in1 = leaky_relu(hs0 @ Wc0^T + bc0)
  k_deep<1, false><<<dim3(8, 256), 256, 0, stream>>>(HS, Wc0b, E, bc0, BT,
      nullptr, nullptr, 0, nullptr, nullptr, nullptr, nullptr, nullptr, nullptr);
  // xp1 = layer_in1 @ Wh1^T
  k_deep<0, false><<<dim3(8, 256), 256, 0, stream>>>(E, Wh1b, X1, nullptr, BT,
      nullptr, nullptr, 0, nullptr, nullptr, nullptr, nullptr, nullptr, nullptr);

  // layer 1 scan + tail
  for (int d = 0; d < DTAIL; ++d)
    k_deep<3, true><<<dim3(8, gyd[d]), 256, 0, stream>>>(HS, Uhb + HID * HID, nullptr, nullptr, 0,
        cnts, offs, d, src1, dstl, X1, bUh + HID, dout + BATCH * HID, HS);
  k_tail<<<1, 1024, 0, stream>>>(cnts, offs, dstl, Uhb + HID * HID, bUh + HID, X1, HS,
                                 dout + BATCH * HID);

  // layer_in2 = leaky_relu(hs1 @ Wc1^T + bc1)
  k_deep<1, false><<<dim3(8, 256), 256, 0, stream>>>(HS, Wc1b, E, bc1, BT,
      nullptr, nullptr, 0, nullptr, nullptr, nullptr, nullptr, nullptr, nullptr);
  // out = layer_in2 @ Wout^T + b_out
  k_deep<2, false><<<dim3(8, 256), 256, 0, stream>>>(E, Woutb, dout + 2 * BATCH * HID, b_out, BT,
      nullptr, nullptr, 0, nullptr, nullptr, nullptr, nullptr, nullptr, nullptr);
}

// Round 14
// 1676.818 us; speedup vs baseline: 1.4971x; 1.1594x over previous
//
#include <hip/hip_runtime.h>
#include <stdint.h>

#define T_LEN 2048
#define BATCH 16
#define HID   1024
#define BT    (BATCH * T_LEN)   // 32768
#define DTAIL 18                 // depths >= DTAIL go to the serial tail bucket
#define NBUCK (DTAIL + 1)

typedef short short8 __attribute__((ext_vector_type(8)));
typedef float f32x4  __attribute__((ext_vector_type(4)));
typedef unsigned int u32;
typedef unsigned short u16;

__device__ __forceinline__ u16 f2bf(float f) {          // RNE f32->bf16
  u32 u = __builtin_bit_cast(u32, f);
  u = (u + 0x7fffu + ((u >> 16) & 1u)) >> 16;
  return (u16)u;
}
__device__ __forceinline__ float bf2f(u16 h) {
  u32 u = ((u32)h) << 16;
  return __builtin_bit_cast(float, u);
}

// ---------- small utility kernels ----------
__global__ void k_dbg(float* o, float v) { o[0] = v; }

__global__ void k_cvt(const float* __restrict__ s, u16* __restrict__ d, int n8) {
  int i = blockIdx.x * blockDim.x + threadIdx.x;
  if (i >= n8) return;
  const float4* sp = (const float4*)s;
  float4 a = sp[i * 2], b = sp[i * 2 + 1];
  union { u16 h[8]; uint4 v; } o;
  o.h[0] = f2bf(a.x); o.h[1] = f2bf(a.y); o.h[2] = f2bf(a.z); o.h[3] = f2bf(a.w);
  o.h[4] = f2bf(b.x); o.h[5] = f2bf(b.y); o.h[6] = f2bf(b.z); o.h[7] = f2bf(b.w);
  ((uint4*)d)[i] = o.v;
}

// dst[i][h] = src[h][i], f32 -> bf16, 1024x1024
__global__ void k_tr(const float* __restrict__ src, u16* __restrict__ dst) {
  __shared__ float tile[32][33];
  int bx = blockIdx.x * 32, by = blockIdx.y * 32;
  int tx = threadIdx.x, ty = threadIdx.y;   // 32 x 8
#pragma unroll
  for (int j = 0; j < 4; ++j)
    tile[ty + j * 8][tx] = src[(size_t)(by + ty + j * 8) * HID + bx + tx];
  __syncthreads();
#pragma unroll
  for (int j = 0; j < 4; ++j)
    dst[(size_t)(bx + ty + j * 8) * HID + by + tx] = f2bf(tile[tx][ty + j * 8]);
}

// out[r] = sum_h W[r,h]*v[h] (+ add[r])
__global__ void k_matvec(const float* __restrict__ W, const float* __restrict__ v,
                         const float* __restrict__ add, float* __restrict__ out) {
  int r = blockIdx.x;
  float s = 0.f;
  for (int h = threadIdx.x; h < HID; h += 256)
    s += W[(size_t)r * HID + h] * v[h];
  for (int o = 32; o; o >>= 1) s += __shfl_down(s, o);
  __shared__ float ws_[4];
  if ((threadIdx.x & 63) == 0) ws_[threadIdx.x >> 6] = s;
  __syncthreads();
  if (threadIdx.x == 0) {
    s = ws_[0] + ws_[1] + ws_[2] + ws_[3];
    out[r] = s + (add ? add[r] : 0.f);
  }
}

// depth per (b,t) via parallel prefix-max of last-reset position.
__global__ __launch_bounds__(256) void k_depths(const void* startp, int* __restrict__ p,
                                                int* __restrict__ cnt) {
  __shared__ int tmax[256];
  __shared__ int lc[NBUCK];
  __shared__ int isIntSh;
  const int b = blockIdx.x;
  const int tid = threadIdx.x;
  if (tid < NBUCK) lc[tid] = 0;
  if (tid == 0) {
    const unsigned char* q = (const unsigned char*)startp;
    int nz = 0;
    for (int i = 0; i < 256; ++i) if ((i & 3) && q[i]) nz++;
    isIntSh = (nz == 0);
  }
  __syncthreads();
  const int isInt = isIntSh;
  int st[8], lastk[8];
  const int t0 = tid * 8;
  int last = -1;
#pragma unroll
  for (int k = 0; k < 8; ++k) {
    const int t = t0 + k;
    int s;
    if (isInt) s = ((const int*)startp)[b * T_LEN + t] != 0;
    else       s = ((const unsigned char*)startp)[b * T_LEN + t] != 0;
    st[k] = s;
    if (s || t == 0) last = t;
    lastk[k] = last;
  }
  tmax[tid] = last;
  __syncthreads();
  for (int off = 1; off < 256; off <<= 1) {
    int v = tmax[tid];
    int u = (tid >= off) ? tmax[tid - off] : -1;
    __syncthreads();
    tmax[tid] = v > u ? v : u;
    __syncthreads();
  }
  const int pre = (tid > 0) ? tmax[tid - 1] : -1;
#pragma unroll
  for (int k = 0; k < 8; ++k) {
    const int t = t0 + k;
    const int R = lastk[k] > pre ? lastk[k] : pre;
    int d = t - R;
    if (d > DTAIL) d = DTAIL;
    atomicAdd(&lc[d], 1);
    p[b * T_LEN + t] = st[k] ? ~d : d;
  }
  __syncthreads();
  if (tid < NBUCK && lc[tid]) atomicAdd(&cnt[tid], lc[tid]);
}

__global__ void k_offsets(const int* cnt, int* offs, int* cursors) {
  if (threadIdx.x == 0 && blockIdx.x == 0) {
    int s = 0;
    for (int d = 0; d < NBUCK; ++d) { offs[d] = s; cursors[d] = s; s += cnt[d]; }
  }
}

// build per-depth gather lists (wave-aggregated atomics)
__global__ void k_build(const int* __restrict__ p, int* cursors,
                        int* __restrict__ s0, int* __restrict__ s1, int* __restrict__ dl) {
  const int i = blockIdx.x * 256 + threadIdx.x;
  const int pv = p[i];
  const int d = pv < 0 ? ~pv : pv;
  const int isStart = pv < 0;
  const int lane = threadIdx.x & 63;
  int slot = -1;
  while (__ballot(slot < 0)) {
    unsigned long long m = __ballot(slot < 0);
    int leader = __ffsll((unsigned long long)m) - 1;
    int dle = __shfl(d, leader);
    unsigned long long grp = __ballot(slot < 0 && d == dle);
    if (slot < 0 && d == dle) {
      int base = 0;
      if (lane == leader) base = atomicAdd(&cursors[dle], (int)__popcll(grp));
      base = __shfl(base, leader);
      slot = base + (int)__popcll(grp & ((1ull << lane) - 1ull));
    }
  }
  const int b = i >> 11;
  int s;
  if (d == 0) s = isStart ? (BT + 32) : (BT + b);
  else        s = i - 1;
  s0[slot] = s;
  if (d == 0) s = isStart ? (BT + 32) : (BT + 16 + b);
  s1[slot] = s;
  dl[slot] = i;
}

// serial tail: items with depth >= DTAIL, ascending t order (exact).
__global__ __launch_bounds__(1024) void k_tail(
    const int* __restrict__ cnt, const int* __restrict__ offs, const int* __restrict__ dstl,
    const u16* __restrict__ Uw, const float* __restrict__ bu,
    const u16* __restrict__ xp, u16* hs, float* __restrict__ hfin) {
  const int n = cnt[DTAIL];
  if (n <= 0) return;
  const int lo = offs[DTAIL];
  __shared__ int idx[4096];
  const int tid = threadIdx.x;
  const int m = n > 4096 ? 4096 : n;
  if (tid == 0) {
    for (int i = 0; i < m; ++i) {
      int v = dstl[lo + i];
      int j = i;
      while (j > 0 && idx[j - 1] > v) { idx[j] = idx[j - 1]; --j; }
      idx[j] = v;
    }
  }
  __syncthreads();
  const int col = tid;
  for (int e = 0; e < m; ++e) {
    const int i = idx[e];
    const u16* hp = hs + (size_t)(i - 1) * HID;
    const u16* ur = Uw + (size_t)col * HID;
    float acc = 0.f;
    for (int r = 0; r < HID; ++r) acc += bf2f(ur[r]) * bf2f(hp[r]);
    const float v = acc + bu[col] + bf2f(xp[(size_t)i * HID + col]);
    const float hval = tanhf(v);
    hs[(size_t)i * HID + col] = f2bf(hval);
    if ((i & (T_LEN - 1)) == T_LEN - 1) hfin[(i >> 11) * HID + col] = hval;
    __threadfence_block();
    __syncthreads();
  }
}

// ---------- 128^2 GEMM, BK=128, 8 waves (k_deep8): low-VGPR for occupancy ----------
// Each wave computes 64x32 (acc[4][2] = 32 VGPR vs 64 in the 4-wave version).
// __launch_bounds__(512,4) forces <=128 regs/wave -> 4 waves/SIMD = 2 blocks x 8 waves
// resident (2x the TLP of round 12/13) to hide the per-step vmcnt(0) drain.
// LDS: [128 rows][16 slots of 8 u16]; logical chunk g at physical slot g^(row&15).
// Store side: gload_lds lane l of instr i covers row w*16+i*4+(l>>4), phys slot l&15,
// so source column = ((l&15) ^ ((i*4+(l>>4))&15))*8 (involution verified vs round-12
// refchecked layout). Read side: slot = ((s*4+(l>>4)) ^ (l&15))*8 -> conflict-free.
template <int EPI, bool GATHER>
__global__ __launch_bounds__(512, 4) void k_deep8(
    const u16* __restrict__ A, const u16* __restrict__ B, void* __restrict__ C,
    const float* __restrict__ bias, int M,
    const int* __restrict__ cnt, const int* __restrict__ offs, int d,
    const int* __restrict__ srcl, const int* __restrict__ dstl,
    const u16* __restrict__ xp, const float* __restrict__ bu,
    float* __restrict__ hfin, u16* hs) {
  __shared__ u16 As[128 * 128];   // 32 KiB
  __shared__ u16 Bs[128 * 128];   // 32 KiB
  const int tid = threadIdx.x;
  const int l = tid & 63;
  const int w = tid >> 6;          // wave 0..7
  int Mt = M, lo = 0;
  if (GATHER) { Mt = cnt[d]; lo = offs[d]; if (Mt <= 0) return; }
  const int n0 = blockIdx.x * 128;
  const int wr = w & 1;            // M half (64 rows)
  const int wc = w >> 1;           // N quarter (32 cols)
  const int fr = l & 15;
  const int p  = l >> 4;           // 0..3

  for (int mb = blockIdx.y; mb * 128 < Mt; mb += gridDim.y) {
    const int m0 = mb * 128;
    // staging instr i (i=0..3): rows w*16 + i*4 + p, phys slot l&15,
    // carrying logical chunk g = (l&15) ^ ((i*4 + p)&15) -> global u16 col g*8
    const u16* aptr[4];
    const u16* bptr[4];
#pragma unroll
    for (int i = 0; i < 4; ++i) {
      const int g = ((l & 15) ^ ((i * 4 + p) & 15)) * 8;
      int gr = m0 + w * 16 + i * 4 + p;
      if (gr > Mt - 1) gr = Mt - 1;                    // tail clamp (masked at store)
      if (GATHER) gr = srcl[lo + gr];
      aptr[i] = A + (size_t)gr * HID + g;
      bptr[i] = B + (size_t)(n0 + w * 16 + i * 4 + p) * HID + g;
    }
    f32x4 acc[4][2] = {};
    for (int t = 0; t < 8; ++t) {
      const int k0 = t * 128;
      __syncthreads();
#pragma unroll
      for (int i = 0; i < 4; ++i) {
        __builtin_amdgcn_global_load_lds(
            (const __attribute__((address_space(1))) void*)(aptr[i] + k0),
            (__attribute__((address_space(3))) void*)(As + (w * 16 + i * 4) * 128), 16, 0, 0);
        __builtin_amdgcn_global_load_lds(
            (const __attribute__((address_space(1))) void*)(bptr[i] + k0),
            (__attribute__((address_space(3))) void*)(Bs + (w * 16 + i * 4) * 128), 16, 0, 0);
      }
      __syncthreads();
#pragma unroll
      for (int s = 0; s < 4; ++s) {
        const int slot = ((s * 4 + p) ^ fr) * 8;
        short8 af[4], bf_[2];
#pragma unroll
        for (int f = 0; f < 4; ++f)
          af[f] = *(const short8*)(As + (wr * 64 + f * 16 + fr) * 128 + slot);
#pragma unroll
        for (int f = 0; f < 2; ++f)
          bf_[f] = *(const short8*)(Bs + (wc * 32 + f * 16 + fr) * 128 + slot);
#pragma unroll
        for (int mi = 0; mi < 4; ++mi)
#pragma unroll
          for (int ni = 0; ni < 2; ++ni)
            acc[mi][ni] = __builtin_amdgcn_mfma_f32_16x16x32_bf16(af[mi], bf_[ni], acc[mi][ni], 0, 0, 0);
      }
    }
#pragma unroll
    for (int mi = 0; mi < 4; ++mi) {
      const int r0 = m0 + wr * 64 + mi * 16 + p * 4;
#pragma unroll
      for (int ni = 0; ni < 2; ++ni) {
        const int col = n0 + wc * 32 + ni * 16 + fr;
        float bv;
        if (EPI == 3) bv = bu[col];
        else          bv = bias ? bias[col] : 0.0f;
#pragma unroll
        for (int j = 0; j < 4; ++j) {
          const int row = r0 + j;
          if (row >= Mt) continue;
          float v = acc[mi][ni][j] + bv;
          if (EPI == 0) {
            ((u16*)C)[(size_t)row * HID + col] = f2bf(v);
          } else if (EPI == 1) {
            v = v > 0.0f ? v : 0.01f * v;
            ((u16*)C)[(size_t)row * HID + col] = f2bf(v);
          } else if (EPI == 2) {
            ((float*)C)[(size_t)row * HID + col] = v;
          } else {
            const int dsti = dstl[lo + row];
            v += bf2f(xp[(size_t)dsti * HID + col]);
            const float hval = tanhf(v);
            hs[(size_t)dsti * HID + col] = f2bf(hval);
            if ((dsti & (T_LEN - 1)) == T_LEN - 1)
              hfin[(dsti >> 11) * HID + col] = hval;
          }
        }
      }
    }
  }
}

// ---------- host ----------
extern "C" void kernel_launch(void* const* d_in, const int* in_sizes, int n_in,
                              void* d_out, int out_size, void* d_ws, size_t ws_size,
                              hipStream_t stream) {
  (void)in_sizes; (void)n_in; (void)out_size;
  const float* emb   = (const float*)d_in[0];
  const void*  start = d_in[1];
  const float* h0    = (const float*)d_in[2];
  const float* Win   = (const float*)d_in[3];
  const float* b_in  = (const float*)d_in[4];
  const float* Wout  = (const float*)d_in[5];
  const float* b_out = (const float*)d_in[6];
  const float* Uh    = (const float*)d_in[7];
  const float* bUh   = (const float*)d_in[8];
  const float* Wh    = (const float*)d_in[9];
  const float* Wy    = (const float*)d_in[10];
  const float* bWy   = (const float*)d_in[11];
  const float* Wff   = (const float*)d_in[12];
  const float* bff   = (const float*)d_in[13];
  float* dout = (float*)d_out;

  char* w = (char*)d_ws;
  auto alloc = [&](size_t b) { char* r = w; w += (b + 255) & ~(size_t)255; return r; };
  u16* E     = (u16*)alloc((size_t)BT * HID * 2);
  u16* X1    = (u16*)alloc((size_t)BT * HID * 2);
  u16* HS    = (u16*)alloc((size_t)(BT + 33) * HID * 2);
  u16* W0b   = (u16*)alloc((size_t)HID * HID * 2);
  u16* Wc0b  = (u16*)alloc((size_t)HID * HID * 2);
  u16* Wc1b  = (u16*)alloc((size_t)HID * HID * 2);
  u16* Wh1b  = (u16*)alloc((size_t)HID * HID * 2);
  u16* Woutb = (u16*)alloc((size_t)HID * HID * 2);
  u16* Uhb   = (u16*)alloc((size_t)2 * HID * HID * 2);
  u16* Wh0b  = (u16*)alloc((size_t)HID * HID * 2);
  u16* Wff0b = (u16*)alloc((size_t)HID * HID * 2);
  u16* Wff1b = (u16*)alloc((size_t)HID * HID * 2);
  u16* WinT  = (u16*)alloc((size_t)HID * HID * 2);
  u16* Wy0T  = (u16*)alloc((size_t)HID * HID * 2);
  u16* Wy1T  = (u16*)alloc((size_t)HID * HID * 2);
  float* bias0 = (float*)alloc(HID * 4);
  float* bc0   = (float*)alloc(HID * 4);
  float* bc1   = (float*)alloc(HID * 4);
  int* pArr = (int*)alloc(BT * 4);
  int* src0 = (int*)alloc(BT * 4);
  int* src1 = (int*)alloc(BT * 4);
  int* dstl = (int*)alloc(BT * 4);
  int* cnts = (int*)alloc(64 * 4);
  int* offs = (int*)alloc(64 * 4);
  int* curs = (int*)alloc(64 * 4);

  if ((size_t)(w - (char*)d_ws) > ws_size) {
    k_dbg<<<1, 1, 0, stream>>>(dout, (float)ws_size);
    return;
  }

  hipMemsetAsync(cnts, 0, NBUCK * 4, stream);
  hipMemsetAsync(HS + (size_t)(BT + 32) * HID, 0, HID * 2, stream);

  // converts (f32 -> bf16)
  k_cvt<<<(BT * HID / 8 + 255) / 256, 256, 0, stream>>>(emb, E, BT * HID / 8);
  k_cvt<<<1024, 256, 0, stream>>>(Uh, Uhb, 2 * HID * HID / 8);
  k_cvt<<<512, 256, 0, stream>>>(Wh,             Wh0b,  HID * HID / 8);
  k_cvt<<<512, 256, 0, stream>>>(Wh + HID * HID, Wh1b,  HID * HID / 8);
  k_cvt<<<512, 256, 0, stream>>>(Wff,             Wff0b, HID * HID / 8);
  k_cvt<<<512, 256, 0, stream>>>(Wff + HID * HID, Wff1b, HID * HID / 8);
  k_cvt<<<512, 256, 0, stream>>>(Wout, Woutb, HID * HID / 8);
  k_cvt<<<16, 256, 0, stream>>>(h0, HS + (size_t)BT * HID, 2 * BATCH * HID / 8);

  dim3 tb(32, 8), tg(32, 32);
  k_tr<<<tg, tb, 0, stream>>>(Win, WinT);
  k_tr<<<tg, tb, 0, stream>>>(Wy,             Wy0T);
  k_tr<<<tg, tb, 0, stream>>>(Wy + HID * HID, Wy1T);

  // folded biases
  k_matvec<<<HID, 256, 0, stream>>>(Wh, b_in, nullptr, bias0);
  k_matvec<<<HID, 256, 0, stream>>>(Wff, bWy, bff, bc0);
  k_matvec<<<HID, 256, 0, stream>>>(Wff + HID * HID, bWy + HID, bff + HID, bc1);

  // depth lists
  k_depths<<<BATCH, 256, 0, stream>>>(start, pArr, cnts);
  k_offsets<<<1, 64, 0, stream>>>(cnts, offs, curs);
  k_build<<<BT / 256, 256, 0, stream>>>(pArr, curs, src0, src1, dstl);

  // combined weights: W0 = Wh0@Win, Wc_l = Wff_l@Wy_l
  k_deep8<0, false><<<dim3(8, 8), 512, 0, stream>>>(Wh0b, WinT, W0b, nullptr, HID,
      nullptr, nullptr, 0, nullptr, nullptr, nullptr, nullptr, nullptr, nullptr);
  k_deep8<0, false><<<dim3(8, 8), 512, 0, stream>>>(Wff0b, Wy0T, Wc0b, nullptr, HID,
      nullptr, nullptr, 0, nullptr, nullptr, nullptr, nullptr, nullptr, nullptr);
  k_deep8<0, false><<<dim3(8, 8), 512, 0, stream>>>(Wff1b, Wy1T, Wc1b, nullptr, HID,
      nullptr, nullptr, 0, nullptr, nullptr, nullptr, nullptr, nullptr, nullptr);

  // xp0 = emb @ W0^T + bias0
  k_deep8<0, false><<<dim3(8, 256), 512, 0, stream>>>(E, W0b, X1, bias0, BT,
      nullptr, nullptr, 0, nullptr, nullptr, nullptr, nullptr, nullptr, nullptr);

  // scan rounds (grid-stride covers overflow)
  static const int gyd[DTAIL] = {132, 66, 42, 22, 12, 6, 4, 2, 2, 2, 1, 1, 1, 1, 1, 1, 1, 1};

  // layer 0 scan + exact tail
  for (int d = 0; d < DTAIL; ++d)
    k_deep8<3, true><<<dim3(8, gyd[d]), 512, 0, stream>>>(HS, Uhb, nullptr, nullptr, 0,
        cnts, offs, d, src0, dstl, X1, bUh, dout, HS);
  k_tail<<<1, 1024, 0, stream>>>(cnts, offs, dstl, Uhb, bUh, X1, HS, dout);

  // layer_in1 = leaky_relu(hs0 @ Wc0^T + bc0)
  k_deep8<1, false><<<dim3(8, 256), 512, 0, stream>>>(HS, Wc0b, E, bc0, BT,
      nullptr, nullptr, 0, nullptr, nullptr, nullptr, nullptr, nullptr, nullptr);
  // xp1 = layer_in1 @ Wh1^T
  k_deep8<0, false><<<dim3(8, 256), 512, 0, stream>>>(E, Wh1b, X1, nullptr, BT,
      nullptr, nullptr, 0, nullptr, nullptr, nullptr, nullptr, nullptr, nullptr);

  // layer 1 scan + tail
  for (int d = 0; d < DTAIL; ++d)
    k_deep8<3, true><<<dim3(8, gyd[d]), 512, 0, stream>>>(HS, Uhb + HID * HID, nullptr, nullptr, 0,
        cnts, offs, d, src1, dstl, X1, bUh + HID, dout + BATCH * HID, HS);
  k_tail<<<1, 1024, 0, stream>>>(cnts, offs, dstl, Uhb + HID * HID, bUh + HID, X1, HS,
                                 dout + BATCH * HID);

  // layer_in2 = leaky_relu(hs1 @ Wc1^T + bc1)
  k_deep8<1, false><<<dim3(8, 256), 512, 0, stream>>>(HS, Wc1b, E, bc1, BT,
      nullptr, nullptr, 0, nullptr, nullptr, nullptr, nullptr, nullptr, nullptr);
  // out = layer_in2 @ Wout^T + b_out
  k_deep8<2, false><<<dim3(8, 256), 512, 0, stream>>>(E, Woutb, dout + 2 * BATCH * HID, b_out, BT,
      nullptr, nullptr, 0, nullptr, nullptr, nullptr, nullptr, nullptr, nullptr);
}

// Round 15
// 1671.662 us; speedup vs baseline: 1.5017x; 1.0031x over previous
//
#include <hip/hip_runtime.h>
#include <stdint.h>

#define T_LEN 2048
#define BATCH 16
#define HID   1024
#define BT    (BATCH * T_LEN)   // 32768
#define DTAIL 18                 // depths >= DTAIL go to the serial tail bucket
#define NBUCK (DTAIL + 1)

typedef short short8 __attribute__((ext_vector_type(8)));
typedef float f32x4  __attribute__((ext_vector_type(4)));
typedef unsigned int u32;
typedef unsigned short u16;

__device__ __forceinline__ u16 f2bf(float f) {          // RNE f32->bf16
  u32 u = __builtin_bit_cast(u32, f);
  u = (u + 0x7fffu + ((u >> 16) & 1u)) >> 16;
  return (u16)u;
}
__device__ __forceinline__ float bf2f(u16 h) {
  u32 u = ((u32)h) << 16;
  return __builtin_bit_cast(float, u);
}

// ---------- small utility kernels ----------
__global__ void k_dbg(float* o, float v) { o[0] = v; }

__global__ void k_cvt(const float* __restrict__ s, u16* __restrict__ d, int n8) {
  int i = blockIdx.x * blockDim.x + threadIdx.x;
  if (i >= n8) return;
  const float4* sp = (const float4*)s;
  float4 a = sp[i * 2], b = sp[i * 2 + 1];
  union { u16 h[8]; uint4 v; } o;
  o.h[0] = f2bf(a.x); o.h[1] = f2bf(a.y); o.h[2] = f2bf(a.z); o.h[3] = f2bf(a.w);
  o.h[4] = f2bf(b.x); o.h[5] = f2bf(b.y); o.h[6] = f2bf(b.z); o.h[7] = f2bf(b.w);
  ((uint4*)d)[i] = o.v;
}

// dst[i][h] = src[h][i], f32 -> bf16, 1024x1024
__global__ void k_tr(const float* __restrict__ src, u16* __restrict__ dst) {
  __shared__ float tile[32][33];
  int bx = blockIdx.x * 32, by = blockIdx.y * 32;
  int tx = threadIdx.x, ty = threadIdx.y;   // 32 x 8
#pragma unroll
  for (int j = 0; j < 4; ++j)
    tile[ty + j * 8][tx] = src[(size_t)(by + ty + j * 8) * HID + bx + tx];
  __syncthreads();
#pragma unroll
  for (int j = 0; j < 4; ++j)
    dst[(size_t)(bx + ty + j * 8) * HID + by + tx] = f2bf(tile[tx][ty + j * 8]);
}

// out[r] = sum_h W[r,h]*v[h] (+ add[r])
__global__ void k_matvec(const float* __restrict__ W, const float* __restrict__ v,
                         const float* __restrict__ add, float* __restrict__ out) {
  int r = blockIdx.x;
  float s = 0.f;
  for (int h = threadIdx.x; h < HID; h += 256)
    s += W[(size_t)r * HID + h] * v[h];
  for (int o = 32; o; o >>= 1) s += __shfl_down(s, o);
  __shared__ float ws_[4];
  if ((threadIdx.x & 63) == 0) ws_[threadIdx.x >> 6] = s;
  __syncthreads();
  if (threadIdx.x == 0) {
    s = ws_[0] + ws_[1] + ws_[2] + ws_[3];
    out[r] = s + (add ? add[r] : 0.f);
  }
}

// depth per (b,t) via parallel prefix-max of last-reset position.
__global__ __launch_bounds__(256) void k_depths(const void* startp, int* __restrict__ p,
                                                int* __restrict__ cnt) {
  __shared__ int tmax[256];
  __shared__ int lc[NBUCK];
  __shared__ int isIntSh;
  const int b = blockIdx.x;
  const int tid = threadIdx.x;
  if (tid < NBUCK) lc[tid] = 0;
  if (tid == 0) {
    const unsigned char* q = (const unsigned char*)startp;
    int nz = 0;
    for (int i = 0; i < 256; ++i) if ((i & 3) && q[i]) nz++;
    isIntSh = (nz == 0);
  }
  __syncthreads();
  const int isInt = isIntSh;
  int st[8], lastk[8];
  const int t0 = tid * 8;
  int last = -1;
#pragma unroll
  for (int k = 0; k < 8; ++k) {
    const int t = t0 + k;
    int s;
    if (isInt) s = ((const int*)startp)[b * T_LEN + t] != 0;
    else       s = ((const unsigned char*)startp)[b * T_LEN + t] != 0;
    st[k] = s;
    if (s || t == 0) last = t;
    lastk[k] = last;
  }
  tmax[tid] = last;
  __syncthreads();
  for (int off = 1; off < 256; off <<= 1) {
    int v = tmax[tid];
    int u = (tid >= off) ? tmax[tid - off] : -1;
    __syncthreads();
    tmax[tid] = v > u ? v : u;
    __syncthreads();
  }
  const int pre = (tid > 0) ? tmax[tid - 1] : -1;
#pragma unroll
  for (int k = 0; k < 8; ++k) {
    const int t = t0 + k;
    const int R = lastk[k] > pre ? lastk[k] : pre;
    int d = t - R;
    if (d > DTAIL) d = DTAIL;
    atomicAdd(&lc[d], 1);
    p[b * T_LEN + t] = st[k] ? ~d : d;
  }
  __syncthreads();
  if (tid < NBUCK && lc[tid]) atomicAdd(&cnt[tid], lc[tid]);
}

__global__ void k_offsets(const int* cnt, int* offs, int* cursors) {
  if (threadIdx.x == 0 && blockIdx.x == 0) {
    int s = 0;
    for (int d = 0; d < NBUCK; ++d) { offs[d] = s; cursors[d] = s; s += cnt[d]; }
  }
}

// build per-depth gather lists (wave-aggregated atomics)
__global__ void k_build(const int* __restrict__ p, int* cursors,
                        int* __restrict__ s0, int* __restrict__ s1, int* __restrict__ dl) {
  const int i = blockIdx.x * 256 + threadIdx.x;
  const int pv = p[i];
  const int d = pv < 0 ? ~pv : pv;
  const int isStart = pv < 0;
  const int lane = threadIdx.x & 63;
  int slot = -1;
  while (__ballot(slot < 0)) {
    unsigned long long m = __ballot(slot < 0);
    int leader = __ffsll((unsigned long long)m) - 1;
    int dle = __shfl(d, leader);
    unsigned long long grp = __ballot(slot < 0 && d == dle);
    if (slot < 0 && d == dle) {
      int base = 0;
      if (lane == leader) base = atomicAdd(&cursors[dle], (int)__popcll(grp));
      base = __shfl(base, leader);
      slot = base + (int)__popcll(grp & ((1ull << lane) - 1ull));
    }
  }
  const int b = i >> 11;
  int s;
  if (d == 0) s = isStart ? (BT + 32) : (BT + b);
  else        s = i - 1;
  s0[slot] = s;
  if (d == 0) s = isStart ? (BT + 32) : (BT + 16 + b);
  s1[slot] = s;
  dl[slot] = i;
}

// serial tail: items with depth >= DTAIL, ascending t order (exact).
__global__ __launch_bounds__(1024) void k_tail(
    const int* __restrict__ cnt, const int* __restrict__ offs, const int* __restrict__ dstl,
    const u16* __restrict__ Uw, const float* __restrict__ bu,
    const u16* __restrict__ xp, u16* hs, float* __restrict__ hfin) {
  const int n = cnt[DTAIL];
  if (n <= 0) return;
  const int lo = offs[DTAIL];
  __shared__ int idx[4096];
  const int tid = threadIdx.x;
  const int m = n > 4096 ? 4096 : n;
  if (tid == 0) {
    for (int i = 0; i < m; ++i) {
      int v = dstl[lo + i];
      int j = i;
      while (j > 0 && idx[j - 1] > v) { idx[j] = idx[j - 1]; --j; }
      idx[j] = v;
    }
  }
  __syncthreads();
  const int col = tid;
  for (int e = 0; e < m; ++e) {
    const int i = idx[e];
    const u16* hp = hs + (size_t)(i - 1) * HID;
    const u16* ur = Uw + (size_t)col * HID;
    float acc = 0.f;
    for (int r = 0; r < HID; ++r) acc += bf2f(ur[r]) * bf2f(hp[r]);
    const float v = acc + bu[col] + bf2f(xp[(size_t)i * HID + col]);
    const float hval = tanhf(v);
    hs[(size_t)i * HID + col] = f2bf(hval);
    if ((i & (T_LEN - 1)) == T_LEN - 1) hfin[(i >> 11) * HID + col] = hval;
    __threadfence_block();
    __syncthreads();
  }
}

// ---------- 128^2 GEMM, BK=128, 8 waves (k_deep8): low-VGPR for occupancy ----------
// Each wave computes 64x32 (acc[4][2] = 32 VGPR vs 64 in the 4-wave version).
// __launch_bounds__(512,4) forces <=128 regs/wave -> 4 waves/SIMD = 2 blocks x 8 waves
// resident (2x the TLP of round 12/13) to hide the per-step vmcnt(0) drain.
// LDS: [128 rows][16 slots of 8 u16]; logical chunk g at physical slot g^(row&15).
// Store side: gload_lds lane l of instr i covers row w*16+i*4+(l>>4), phys slot l&15,
// so source column = ((l&15) ^ ((i*4+(l>>4))&15))*8 (involution verified vs round-12
// refchecked layout). Read side: slot = ((s*4+(l>>4)) ^ (l&15))*8 -> conflict-free.
template <int EPI, bool GATHER>
__global__ __launch_bounds__(512, 4) void k_deep8(
    const u16* __restrict__ A, const u16* __restrict__ B, void* __restrict__ C,
    const float* __restrict__ bias, int M,
    const int* __restrict__ cnt, const int* __restrict__ offs, int d,
    const int* __restrict__ srcl, const int* __restrict__ dstl,
    const u16* __restrict__ xp, const float* __restrict__ bu,
    float* __restrict__ hfin, u16* hs) {
  __shared__ u16 As[128 * 128];   // 32 KiB
  __shared__ u16 Bs[128 * 128];   // 32 KiB
  const int tid = threadIdx.x;
  const int l = tid & 63;
  const int w = tid >> 6;          // wave 0..7
  int Mt = M, lo = 0;
  if (GATHER) { Mt = cnt[d]; lo = offs[d]; if (Mt <= 0) return; }
  const int n0 = blockIdx.x * 128;
  const int wr = w & 1;            // M half (64 rows)
  const int wc = w >> 1;           // N quarter (32 cols)
  const int fr = l & 15;
  const int p  = l >> 4;           // 0..3

  for (int mb = blockIdx.y; mb * 128 < Mt; mb += gridDim.y) {
    const int m0 = mb * 128;
    // staging instr i (i=0..3): rows w*16 + i*4 + p, phys slot l&15,
    // carrying logical chunk g = (l&15) ^ ((i*4 + p)&15) -> global u16 col g*8
    const u16* aptr[4];
    const u16* bptr[4];
#pragma unroll
    for (int i = 0; i < 4; ++i) {
      const int g = ((l & 15) ^ ((i * 4 + p) & 15)) * 8;
      int gr = m0 + w * 16 + i * 4 + p;
      if (gr > Mt - 1) gr = Mt - 1;                    // tail clamp (masked at store)
      if (GATHER) gr = srcl[lo + gr];
      aptr[i] = A + (size_t)gr * HID + g;
      bptr[i] = B + (size_t)(n0 + w * 16 + i * 4 + p) * HID + g;
    }
    f32x4 acc[4][2] = {};
    for (int t = 0; t < 8; ++t) {
      const int k0 = t * 128;
      __syncthreads();
#pragma unroll
      for (int i = 0; i < 4; ++i) {
        __builtin_amdgcn_global_load_lds(
            (const __attribute__((address_space(1))) void*)(aptr[i] + k0),
            (__attribute__((address_space(3))) void*)(As + (w * 16 + i * 4) * 128), 16, 0, 0);
        __builtin_amdgcn_global_load_lds(
            (const __attribute__((address_space(1))) void*)(bptr[i] + k0),
            (__attribute__((address_space(3))) void*)(Bs + (w * 16 + i * 4) * 128), 16, 0, 0);
      }
      __syncthreads();
#pragma unroll
      for (int s = 0; s < 4; ++s) {
        const int slot = ((s * 4 + p) ^ fr) * 8;
        short8 af[4], bf_[2];
#pragma unroll
        for (int f = 0; f < 4; ++f)
          af[f] = *(const short8*)(As + (wr * 64 + f * 16 + fr) * 128 + slot);
#pragma unroll
        for (int f = 0; f < 2; ++f)
          bf_[f] = *(const short8*)(Bs + (wc * 32 + f * 16 + fr) * 128 + slot);
#pragma unroll
        for (int mi = 0; mi < 4; ++mi)
#pragma unroll
          for (int ni = 0; ni < 2; ++ni)
            acc[mi][ni] = __builtin_amdgcn_mfma_f32_16x16x32_bf16(af[mi], bf_[ni], acc[mi][ni], 0, 0, 0);
      }
    }
#pragma unroll
    for (int mi = 0; mi < 4; ++mi) {
      const int r0 = m0 + wr * 64 + mi * 16 + p * 4;
#pragma unroll
      for (int ni = 0; ni < 2; ++ni) {
        const int col = n0 + wc * 32 + ni * 16 + fr;
        float bv;
        if (EPI == 3) bv = bu[col];
        else          bv = bias ? bias[col] : 0.0f;
#pragma unroll
        for (int j = 0; j < 4; ++j) {
          const int row = r0 + j;
          if (row >= Mt) continue;
          float v = acc[mi][ni][j] + bv;
          if (EPI == 0) {
            ((u16*)C)[(size_t)row * HID + col] = f2bf(v);
          } else if (EPI == 1) {
            v = v > 0.0f ? v : 0.01f * v;
            ((u16*)C)[(size_t)row * HID + col] = f2bf(v);
          } else if (EPI == 2) {
            ((float*)C)[(size_t)row * HID + col] = v;
          } else {
            const int dsti = dstl[lo + row];
            v += bf2f(xp[(size_t)dsti * HID + col]);
            const float hval = tanhf(v);
            hs[(size_t)dsti * HID + col] = f2bf(hval);
            if ((dsti & (T_LEN - 1)) == T_LEN - 1)
              hfin[(dsti >> 11) * HID + col] = hval;
          }
        }
      }
    }
  }
}

// ---------- host ----------
extern "C" void kernel_launch(void* const* d_in, const int* in_sizes, int n_in,
                              void* d_out, int out_size, void* d_ws, size_t ws_size,
                              hipStream_t stream) {
  (void)in_sizes; (void)n_in; (void)out_size;
  const float* emb   = (const float*)d_in[0];
  const void*  start = d_in[1];
  const float* h0    = (const float*)d_in[2];
  const float* Win   = (const float*)d_in[3];
  const float* b_in  = (const float*)d_in[4];
  const float* Wout  = (const float*)d_in[5];
  const float* b_out = (const float*)d_in[6];
  const float* Uh    = (const float*)d_in[7];
  const float* bUh   = (const float*)d_in[8];
  const float* Wh    = (const float*)d_in[9];
  const float* Wy    = (const float*)d_in[10];
  const float* bWy   = (const float*)d_in[11];
  const float* Wff   = (const float*)d_in[12];
  const float* bff   = (const float*)d_in[13];
  float* dout = (float*)d_out;

  char* w = (char*)d_ws;
  auto alloc = [&](size_t b) { char* r = w; w += (b + 255) & ~(size_t)255; return r; };
  u16* E     = (u16*)alloc((size_t)BT * HID * 2);
  u16* X1    = (u16*)alloc((size_t)BT * HID * 2);
  u16* HS    = (u16*)alloc((size_t)(BT + 33) * HID * 2);
  u16* W0b   = (u16*)alloc((size_t)HID * HID * 2);
  u16* Wc0b  = (u16*)alloc((size_t)HID * HID * 2);
  u16* Wc1b  = (u16*)alloc((size_t)HID * HID * 2);
  u16* Wh1b  = (u16*)alloc((size_t)HID * HID * 2);
  u16* Woutb = (u16*)alloc((size_t)HID * HID * 2);
  u16* Uhb   = (u16*)alloc((size_t)2 * HID * HID * 2);
  u16* Wh0b  = (u16*)alloc((size_t)HID * HID * 2);
  u16* Wff0b = (u16*)alloc((size_t)HID * HID * 2);
  u16* Wff1b = (u16*)alloc((size_t)HID * HID * 2);
  u16* WinT  = (u16*)alloc((size_t)HID * HID * 2);
  u16* Wy0T  = (u16*)alloc((size_t)HID * HID * 2);
  u16* Wy1T  = (u16*)alloc((size_t)HID * HID * 2);
  float* bias0 = (float*)alloc(HID * 4);
  float* bc0   = (float*)alloc(HID * 4);
  float* bc1   = (float*)alloc(HID * 4);
  int* pArr = (int*)alloc(BT * 4);
  int* src0 = (int*)alloc(BT * 4);
  int* src1 = (int*)alloc(BT * 4);
  int* dstl = (int*)alloc(BT * 4);
  int* cnts = (int*)alloc(64 * 4);
  int* offs = (int*)alloc(64 * 4);
  int* curs = (int*)alloc(64 * 4);

  if ((size_t)(w - (char*)d_ws) > ws_size) {
    k_dbg<<<1, 1, 0, stream>>>(dout, (float)ws_size);
    return;
  }

  hipMemsetAsync(cnts, 0, NBUCK * 4, stream);
  hipMemsetAsync(HS + (size_t)(BT + 32) * HID, 0, HID * 2, stream);

  // converts (f32 -> bf16)
  k_cvt<<<(BT * HID / 8 + 255) / 256, 256, 0, stream>>>(emb, E, BT * HID / 8);
  k_cvt<<<1024, 256, 0, stream>>>(Uh, Uhb, 2 * HID * HID / 8);
  k_cvt<<<512, 256, 0, stream>>>(Wh,             Wh0b,  HID * HID / 8);
  k_cvt<<<512, 256, 0, stream>>>(Wh + HID * HID, Wh1b,  HID * HID / 8);
  k_cvt<<<512, 256, 0, stream>>>(Wff,             Wff0b, HID * HID / 8);
  k_cvt<<<512, 256, 0, stream>>>(Wff + HID * HID, Wff1b, HID * HID / 8);
  k_cvt<<<512, 256, 0, stream>>>(Wout, Woutb, HID * HID / 8);
  k_cvt<<<16, 256, 0, stream>>>(h0, HS + (size_t)BT * HID, 2 * BATCH * HID / 8);

  dim3 tb(32, 8), tg(32, 32);
  k_tr<<<tg, tb, 0, stream>>>(Win, WinT);
  k_tr<<<tg, tb, 0, stream>>>(Wy,             Wy0T);
  k_tr<<<tg, tb, 0, stream>>>(Wy + HID * HID, Wy1T);

  // folded biases
  k_matvec<<<HID, 256, 0, stream>>>(Wh, b_in, nullptr, bias0);
  k_matvec<<<HID, 256, 0, stream>>>(Wff, bWy, bff, bc0);
  k_matvec<<<HID, 256, 0, stream>>>(Wff + HID * HID, bWy + HID, bff + HID, bc1);

  // depth lists
  k_depths<<<BATCH, 256, 0, stream>>>(start, pArr, cnts);
  k_offsets<<<1, 64, 0, stream>>>(cnts, offs, curs);
  k_build<<<BT / 256, 256, 0, stream>>>(pArr, curs, src0, src1, dstl);

  // combined weights: W0 = Wh0@Win, Wc_l = Wff_l@Wy_l
  k_deep8<0, false><<<dim3(8, 8), 512, 0, stream>>>(Wh0b, WinT, W0b, nullptr, HID,
      nullptr, nullptr, 0, nullptr, nullptr, nullptr, nullptr, nullptr, nullptr);
  k_deep8<0, false><<<dim3(8, 8), 512, 0, stream>>>(Wff0b, Wy0T, Wc0b, nullptr, HID,
      nullptr, nullptr, 0, nullptr, nullptr, nullptr, nullptr, nullptr, nullptr);
  k_deep8<0, false><<<dim3(8, 8), 512, 0, stream>>>(Wff1b, Wy1T, Wc1b, nullptr, HID,
      nullptr, nullptr, 0, nullptr, nullptr, nullptr, nullptr, nullptr, nullptr);

  // xp0 = emb @ W0^T + bias0
  k_deep8<0, false><<<dim3(8, 256), 512, 0, stream>>>(E, W0b, X1, bias0, BT,
      nullptr, nullptr, 0, nullptr, nullptr, nullptr, nullptr, nullptr, nullptr);

  // scan rounds (grid-stride covers overflow)
  static const int gyd[DTAIL] = {132, 66, 42, 22, 12, 6, 4, 2, 2, 2, 1, 1, 1, 1, 1, 1, 1, 1};

  // layer 0 scan + exact tail
  for (int d = 0; d < DTAIL; ++d)
    k_deep8<3, true><<<dim3(8, gyd[d]), 512, 0, stream>>>(HS, Uhb, nullptr, nullptr, 0,
        cnts, offs, d, src0, dstl, X1, bUh, dout, HS);
  k_tail<<<1, 1024, 0, stream>>>(cnts, offs, dstl, Uhb, bUh, X1, HS, dout);

  // layer_in1 = leaky_relu(hs0 @ Wc0^T + bc0)
  k_deep8<1, false><<<dim3(8, 256), 512, 0, stream>>>(HS, Wc0b, E, bc0, BT,
      nullptr, nullptr, 0, nullptr, nullptr, nullptr, nullptr, nullptr, nullptr);
  // xp1 = layer_in1 @ Wh1^T
  k_deep8<0, false><<<dim3(8, 256), 512, 0, stream>>>(E, Wh1b, X1, nullptr, BT,
      nullptr, nullptr, 0, nullptr, nullptr, nullptr, nullptr, nullptr, nullptr);

  // layer 1 scan + tail
  for (int d = 0; d < DTAIL; ++d)
    k_deep8<3, true><<<dim3(8, gyd[d]), 512, 0, stream>>>(HS, Uhb + HID * HID, nullptr, nullptr, 0,
        cnts, offs, d, src1, dstl, X1, bUh + HID, dout + BATCH * HID, HS);
  k_tail<<<1, 1024, 0, stream>>>(cnts, offs, dstl, Uhb + HID * HID, bUh + HID, X1, HS,
                                 dout + BATCH * HID);

  // layer_in2 = leaky_relu(hs1 @ Wc1^T + bc1)
  k_deep8<1, false><<<dim3(8, 256), 512, 0, stream>>>(HS, Wc1b, E, bc1, BT,
      nullptr, nullptr, 0, nullptr, nullptr, nullptr, nullptr, nullptr, nullptr);
  // out = layer_in2 @ Wout^T + b_out
  k_deep8<2, false><<<dim3(8, 256), 512, 0, stream>>>(E, Woutb, dout + 2 * BATCH * HID, b_out, BT,
      nullptr, nullptr, 0, nullptr, nullptr, nullptr, nullptr, nullptr, nullptr);
}

// Round 16
// 1527.628 us; speedup vs baseline: 1.6433x; 1.0943x over previous
//
#include <hip/hip_runtime.h>
#include <stdint.h>

#define T_LEN 2048
#define BATCH 16
#define HID   1024
#define BT    (BATCH * T_LEN)   // 32768
#define DTAIL 18                 // depths >= DTAIL go to the serial tail bucket
#define NBUCK (DTAIL + 1)

typedef short short8 __attribute__((ext_vector_type(8)));
typedef float f32x4  __attribute__((ext_vector_type(4)));
typedef unsigned int u32;
typedef unsigned short u16;

__device__ __forceinline__ u16 f2bf(float f) {          // RNE f32->bf16
  u32 u = __builtin_bit_cast(u32, f);
  u = (u + 0x7fffu + ((u >> 16) & 1u)) >> 16;
  return (u16)u;
}
__device__ __forceinline__ float bf2f(u16 h) {
  u32 u = ((u32)h) << 16;
  return __builtin_bit_cast(float, u);
}

// ---------- small utility kernels ----------
__global__ void k_dbg(float* o, float v) { o[0] = v; }

__global__ void k_cvt(const float* __restrict__ s, u16* __restrict__ d, int n8) {
  int i = blockIdx.x * blockDim.x + threadIdx.x;
  if (i >= n8) return;
  const float4* sp = (const float4*)s;
  float4 a = sp[i * 2], b = sp[i * 2 + 1];
  union { u16 h[8]; uint4 v; } o;
  o.h[0] = f2bf(a.x); o.h[1] = f2bf(a.y); o.h[2] = f2bf(a.z); o.h[3] = f2bf(a.w);
  o.h[4] = f2bf(b.x); o.h[5] = f2bf(b.y); o.h[6] = f2bf(b.z); o.h[7] = f2bf(b.w);
  ((uint4*)d)[i] = o.v;
}

// dst[i][h] = src[h][i], f32 -> bf16, 1024x1024
__global__ void k_tr(const float* __restrict__ src, u16* __restrict__ dst) {
  __shared__ float tile[32][33];
  int bx = blockIdx.x * 32, by = blockIdx.y * 32;
  int tx = threadIdx.x, ty = threadIdx.y;   // 32 x 8
#pragma unroll
  for (int j = 0; j < 4; ++j)
    tile[ty + j * 8][tx] = src[(size_t)(by + ty + j * 8) * HID + bx + tx];
  __syncthreads();
#pragma unroll
  for (int j = 0; j < 4; ++j)
    dst[(size_t)(bx + ty + j * 8) * HID + by + tx] = f2bf(tile[tx][ty + j * 8]);
}

// out[r] = sum_h W[r,h]*v[h] (+ add[r])
__global__ void k_matvec(const float* __restrict__ W, const float* __restrict__ v,
                         const float* __restrict__ add, float* __restrict__ out) {
  int r = blockIdx.x;
  float s = 0.f;
  for (int h = threadIdx.x; h < HID; h += 256)
    s += W[(size_t)r * HID + h] * v[h];
  for (int o = 32; o; o >>= 1) s += __shfl_down(s, o);
  __shared__ float ws_[4];
  if ((threadIdx.x & 63) == 0) ws_[threadIdx.x >> 6] = s;
  __syncthreads();
  if (threadIdx.x == 0) {
    s = ws_[0] + ws_[1] + ws_[2] + ws_[3];
    out[r] = s + (add ? add[r] : 0.f);
  }
}

// depth per (b,t) via parallel prefix-max of last-reset position.
__global__ __launch_bounds__(256) void k_depths(const void* startp, int* __restrict__ p,
                                                int* __restrict__ cnt) {
  __shared__ int tmax[256];
  __shared__ int lc[NBUCK];
  __shared__ int isIntSh;
  const int b = blockIdx.x;
  const int tid = threadIdx.x;
  if (tid < NBUCK) lc[tid] = 0;
  if (tid == 0) {
    const unsigned char* q = (const unsigned char*)startp;
    int nz = 0;
    for (int i = 0; i < 256; ++i) if ((i & 3) && q[i]) nz++;
    isIntSh = (nz == 0);
  }
  __syncthreads();
  const int isInt = isIntSh;
  int st[8], lastk[8];
  const int t0 = tid * 8;
  int last = -1;
#pragma unroll
  for (int k = 0; k < 8; ++k) {
    const int t = t0 + k;
    int s;
    if (isInt) s = ((const int*)startp)[b * T_LEN + t] != 0;
    else       s = ((const unsigned char*)startp)[b * T_LEN + t] != 0;
    st[k] = s;
    if (s || t == 0) last = t;
    lastk[k] = last;
  }
  tmax[tid] = last;
  __syncthreads();
  for (int off = 1; off < 256; off <<= 1) {
    int v = tmax[tid];
    int u = (tid >= off) ? tmax[tid - off] : -1;
    __syncthreads();
    tmax[tid] = v > u ? v : u;
    __syncthreads();
  }
  const int pre = (tid > 0) ? tmax[tid - 1] : -1;
#pragma unroll
  for (int k = 0; k < 8; ++k) {
    const int t = t0 + k;
    const int R = lastk[k] > pre ? lastk[k] : pre;
    int d = t - R;
    if (d > DTAIL) d = DTAIL;
    atomicAdd(&lc[d], 1);
    p[b * T_LEN + t] = st[k] ? ~d : d;
  }
  __syncthreads();
  if (tid < NBUCK && lc[tid]) atomicAdd(&cnt[tid], lc[tid]);
}

__global__ void k_offsets(const int* cnt, int* offs, int* cursors) {
  if (threadIdx.x == 0 && blockIdx.x == 0) {
    int s = 0;
    for (int d = 0; d < NBUCK; ++d) { offs[d] = s; cursors[d] = s; s += cnt[d]; }
  }
}

// build per-depth gather lists (wave-aggregated atomics)
__global__ void k_build(const int* __restrict__ p, int* cursors,
                        int* __restrict__ s0, int* __restrict__ s1, int* __restrict__ dl) {
  const int i = blockIdx.x * 256 + threadIdx.x;
  const int pv = p[i];
  const int d = pv < 0 ? ~pv : pv;
  const int isStart = pv < 0;
  const int lane = threadIdx.x & 63;
  int slot = -1;
  while (__ballot(slot < 0)) {
    unsigned long long m = __ballot(slot < 0);
    int leader = __ffsll((unsigned long long)m) - 1;
    int dle = __shfl(d, leader);
    unsigned long long grp = __ballot(slot < 0 && d == dle);
    if (slot < 0 && d == dle) {
      int base = 0;
      if (lane == leader) base = atomicAdd(&cursors[dle], (int)__popcll(grp));
      base = __shfl(base, leader);
      slot = base + (int)__popcll(grp & ((1ull << lane) - 1ull));
    }
  }
  const int b = i >> 11;
  int s;
  if (d == 0) s = isStart ? (BT + 32) : (BT + b);
  else        s = i - 1;
  s0[slot] = s;
  if (d == 0) s = isStart ? (BT + 32) : (BT + 16 + b);
  s1[slot] = s;
  dl[slot] = i;
}

// serial tail: items with depth >= DTAIL, ascending t order (exact).
__global__ __launch_bounds__(1024) void k_tail(
    const int* __restrict__ cnt, const int* __restrict__ offs, const int* __restrict__ dstl,
    const u16* __restrict__ Uw, const float* __restrict__ bu,
    const u16* __restrict__ xp, u16* hs, float* __restrict__ hfin) {
  const int n = cnt[DTAIL];
  if (n <= 0) return;
  const int lo = offs[DTAIL];
  __shared__ int idx[4096];
  const int tid = threadIdx.x;
  const int m = n > 4096 ? 4096 : n;
  if (tid == 0) {
    for (int i = 0; i < m; ++i) {
      int v = dstl[lo + i];
      int j = i;
      while (j > 0 && idx[j - 1] > v) { idx[j] = idx[j - 1]; --j; }
      idx[j] = v;
    }
  }
  __syncthreads();
  const int col = tid;
  for (int e = 0; e < m; ++e) {
    const int i = idx[e];
    const u16* hp = hs + (size_t)(i - 1) * HID;
    const u16* ur = Uw + (size_t)col * HID;
    float acc = 0.f;
    for (int r = 0; r < HID; ++r) acc += bf2f(ur[r]) * bf2f(hp[r]);
    const float v = acc + bu[col] + bf2f(xp[(size_t)i * HID + col]);
    const float hval = tanhf(v);
    hs[(size_t)i * HID + col] = f2bf(hval);
    if ((i & (T_LEN - 1)) == T_LEN - 1) hfin[(i >> 11) * HID + col] = hval;
    __threadfence_block();
    __syncthreads();
  }
}

// ---------- 128^2 GEMM, BK=128, 8 waves, XCD panel co-location (k_deep8) ----------
// Low-VGPR (acc[4][2]=32/wave, VGPR_Count 52) -> 2 blocks x 8 waves resident (37% occ,
// round-15 verified). NEW this round: XCD co-location swizzle (round-13 mapping,
// refchecked there): dispatch id D, xcd=D&7 -> XCD c computes only m-panels m%8==c,
// all 8 n-blocks consecutively. Per-XCD concurrent set = 8 A-panels (2MB) + B (2MB)
// = 4MB = L2; A crosses fabric/HBM once (round 15: every XCD streamed all of A ->
// 266MB HBM fetch, 2.7TB/s, the measured limiter). gridDim.y MUST be multiple of 8.
// LDS: [128 rows][16 slots of 8 u16]; chunk g at slot g^(row&15); store via
// pre-swizzled source column, read slot=((s*4+p)^fr)*8 -> conflict-free (verified 0).
template <int EPI, bool GATHER>
__global__ __launch_bounds__(512, 4) void k_deep8(
    const u16* __restrict__ A, const u16* __restrict__ B, void* __restrict__ C,
    const float* __restrict__ bias, int M,
    const int* __restrict__ cnt, const int* __restrict__ offs, int d,
    const int* __restrict__ srcl, const int* __restrict__ dstl,
    const u16* __restrict__ xp, const float* __restrict__ bu,
    float* __restrict__ hfin, u16* hs) {
  __shared__ u16 As[128 * 128];   // 32 KiB
  __shared__ u16 Bs[128 * 128];   // 32 KiB
  const int tid = threadIdx.x;
  const int l = tid & 63;
  const int w = tid >> 6;          // wave 0..7
  int Mt = M, lo = 0;
  if (GATHER) { Mt = cnt[d]; lo = offs[d]; if (Mt <= 0) return; }

  // XCD panel co-location swizzle (bijective for gridDim.y % 8 == 0)
  const int D = blockIdx.y * gridDim.x + blockIdx.x;   // dispatch order, x fastest
  const int xcd = D & 7;
  const int q = D >> 3;
  const int n0 = (q & 7) * 128;
  const int by0 = ((q >> 3) << 3) + xcd;

  const int wr = w & 1;            // M half (64 rows)
  const int wc = w >> 1;           // N quarter (32 cols)
  const int fr = l & 15;
  const int p  = l >> 4;           // 0..3

  for (int mb = by0; mb * 128 < Mt; mb += gridDim.y) {
    const int m0 = mb * 128;
    // staging instr i (i=0..3): rows w*16 + i*4 + p, phys slot l&15,
    // carrying logical chunk g = (l&15) ^ ((i*4 + p)&15) -> global u16 col g*8
    const u16* aptr[4];
    const u16* bptr[4];
#pragma unroll
    for (int i = 0; i < 4; ++i) {
      const int g = ((l & 15) ^ ((i * 4 + p) & 15)) * 8;
      int gr = m0 + w * 16 + i * 4 + p;
      if (gr > Mt - 1) gr = Mt - 1;                    // tail clamp (masked at store)
      if (GATHER) gr = srcl[lo + gr];
      aptr[i] = A + (size_t)gr * HID + g;
      bptr[i] = B + (size_t)(n0 + w * 16 + i * 4 + p) * HID + g;
    }
    f32x4 acc[4][2] = {};
    for (int t = 0; t < 8; ++t) {
      const int k0 = t * 128;
      __syncthreads();
#pragma unroll
      for (int i = 0; i < 4; ++i) {
        __builtin_amdgcn_global_load_lds(
            (const __attribute__((address_space(1))) void*)(aptr[i] + k0),
            (__attribute__((address_space(3))) void*)(As + (w * 16 + i * 4) * 128), 16, 0, 0);
        __builtin_amdgcn_global_load_lds(
            (const __attribute__((address_space(1))) void*)(bptr[i] + k0),
            (__attribute__((address_space(3))) void*)(Bs + (w * 16 + i * 4) * 128), 16, 0, 0);
      }
      __syncthreads();
#pragma unroll
      for (int s = 0; s < 4; ++s) {
        const int slot = ((s * 4 + p) ^ fr) * 8;
        short8 af[4], bf_[2];
#pragma unroll
        for (int f = 0; f < 4; ++f)
          af[f] = *(const short8*)(As + (wr * 64 + f * 16 + fr) * 128 + slot);
#pragma unroll
        for (int f = 0; f < 2; ++f)
          bf_[f] = *(const short8*)(Bs + (wc * 32 + f * 16 + fr) * 128 + slot);
#pragma unroll
        for (int mi = 0; mi < 4; ++mi)
#pragma unroll
          for (int ni = 0; ni < 2; ++ni)
            acc[mi][ni] = __builtin_amdgcn_mfma_f32_16x16x32_bf16(af[mi], bf_[ni], acc[mi][ni], 0, 0, 0);
      }
    }
#pragma unroll
    for (int mi = 0; mi < 4; ++mi) {
      const int r0 = m0 + wr * 64 + mi * 16 + p * 4;
#pragma unroll
      for (int ni = 0; ni < 2; ++ni) {
        const int col = n0 + wc * 32 + ni * 16 + fr;
        float bv;
        if (EPI == 3) bv = bu[col];
        else          bv = bias ? bias[col] : 0.0f;
#pragma unroll
        for (int j = 0; j < 4; ++j) {
          const int row = r0 + j;
          if (row >= Mt) continue;
          float v = acc[mi][ni][j] + bv;
          if (EPI == 0) {
            ((u16*)C)[(size_t)row * HID + col] = f2bf(v);
          } else if (EPI == 1) {
            v = v > 0.0f ? v : 0.01f * v;
            ((u16*)C)[(size_t)row * HID + col] = f2bf(v);
          } else if (EPI == 2) {
            ((float*)C)[(size_t)row * HID + col] = v;
          } else {
            const int dsti = dstl[lo + row];
            v += bf2f(xp[(size_t)dsti * HID + col]);
            const float hval = tanhf(v);
            hs[(size_t)dsti * HID + col] = f2bf(hval);
            if ((dsti & (T_LEN - 1)) == T_LEN - 1)
              hfin[(dsti >> 11) * HID + col] = hval;
          }
        }
      }
    }
  }
}

// ---------- host ----------
extern "C" void kernel_launch(void* const* d_in, const int* in_sizes, int n_in,
                              void* d_out, int out_size, void* d_ws, size_t ws_size,
                              hipStream_t stream) {
  (void)in_sizes; (void)n_in; (void)out_size;
  const float* emb   = (const float*)d_in[0];
  const void*  start = d_in[1];
  const float* h0    = (const float*)d_in[2];
  const float* Win   = (const float*)d_in[3];
  const float* b_in  = (const float*)d_in[4];
  const float* Wout  = (const float*)d_in[5];
  const float* b_out = (const float*)d_in[6];
  const float* Uh    = (const float*)d_in[7];
  const float* bUh   = (const float*)d_in[8];
  const float* Wh    = (const float*)d_in[9];
  const float* Wy    = (const float*)d_in[10];
  const float* bWy   = (const float*)d_in[11];
  const float* Wff   = (const float*)d_in[12];
  const float* bff   = (const float*)d_in[13];
  float* dout = (float*)d_out;

  char* w = (char*)d_ws;
  auto alloc = [&](size_t b) { char* r = w; w += (b + 255) & ~(size_t)255; return r; };
  u16* E     = (u16*)alloc((size_t)BT * HID * 2);
  u16* X1    = (u16*)alloc((size_t)BT * HID * 2);
  u16* HS    = (u16*)alloc((size_t)(BT + 33) * HID * 2);
  u16* W0b   = (u16*)alloc((size_t)HID * HID * 2);
  u16* Wc0b  = (u16*)alloc((size_t)HID * HID * 2);
  u16* Wc1b  = (u16*)alloc((size_t)HID * HID * 2);
  u16* Wh1b  = (u16*)alloc((size_t)HID * HID * 2);
  u16* Woutb = (u16*)alloc((size_t)HID * HID * 2);
  u16* Uhb   = (u16*)alloc((size_t)2 * HID * HID * 2);
  u16* Wh0b  = (u16*)alloc((size_t)HID * HID * 2);
  u16* Wff0b = (u16*)alloc((size_t)HID * HID * 2);
  u16* Wff1b = (u16*)alloc((size_t)HID * HID * 2);
  u16* WinT  = (u16*)alloc((size_t)HID * HID * 2);
  u16* Wy0T  = (u16*)alloc((size_t)HID * HID * 2);
  u16* Wy1T  = (u16*)alloc((size_t)HID * HID * 2);
  float* bias0 = (float*)alloc(HID * 4);
  float* bc0   = (float*)alloc(HID * 4);
  float* bc1   = (float*)alloc(HID * 4);
  int* pArr = (int*)alloc(BT * 4);
  int* src0 = (int*)alloc(BT * 4);
  int* src1 = (int*)alloc(BT * 4);
  int* dstl = (int*)alloc(BT * 4);
  int* cnts = (int*)alloc(64 * 4);
  int* offs = (int*)alloc(64 * 4);
  int* curs = (int*)alloc(64 * 4);

  if ((size_t)(w - (char*)d_ws) > ws_size) {
    k_dbg<<<1, 1, 0, stream>>>(dout, (float)ws_size);
    return;
  }

  hipMemsetAsync(cnts, 0, NBUCK * 4, stream);
  hipMemsetAsync(HS + (size_t)(BT + 32) * HID, 0, HID * 2, stream);

  // converts (f32 -> bf16)
  k_cvt<<<(BT * HID / 8 + 255) / 256, 256, 0, stream>>>(emb, E, BT * HID / 8);
  k_cvt<<<1024, 256, 0, stream>>>(Uh, Uhb, 2 * HID * HID / 8);
  k_cvt<<<512, 256, 0, stream>>>(Wh,             Wh0b,  HID * HID / 8);
  k_cvt<<<512, 256, 0, stream>>>(Wh + HID * HID, Wh1b,  HID * HID / 8);
  k_cvt<<<512, 256, 0, stream>>>(Wff,             Wff0b, HID * HID / 8);
  k_cvt<<<512, 256, 0, stream>>>(Wff + HID * HID, Wff1b, HID * HID / 8);
  k_cvt<<<512, 256, 0, stream>>>(Wout, Woutb, HID * HID / 8);
  k_cvt<<<16, 256, 0, stream>>>(h0, HS + (size_t)BT * HID, 2 * BATCH * HID / 8);

  dim3 tb(32, 8), tg(32, 32);
  k_tr<<<tg, tb, 0, stream>>>(Win, WinT);
  k_tr<<<tg, tb, 0, stream>>>(Wy,             Wy0T);
  k_tr<<<tg, tb, 0, stream>>>(Wy + HID * HID, Wy1T);

  // folded biases
  k_matvec<<<HID, 256, 0, stream>>>(Wh, b_in, nullptr, bias0);
  k_matvec<<<HID, 256, 0, stream>>>(Wff, bWy, bff, bc0);
  k_matvec<<<HID, 256, 0, stream>>>(Wff + HID * HID, bWy + HID, bff + HID, bc1);

  // depth lists
  k_depths<<<BATCH, 256, 0, stream>>>(start, pArr, cnts);
  k_offsets<<<1, 64, 0, stream>>>(cnts, offs, curs);
  k_build<<<BT / 256, 256, 0, stream>>>(pArr, curs, src0, src1, dstl);

  // combined weights: W0 = Wh0@Win, Wc_l = Wff_l@Wy_l
  k_deep8<0, false><<<dim3(8, 8), 512, 0, stream>>>(Wh0b, WinT, W0b, nullptr, HID,
      nullptr, nullptr, 0, nullptr, nullptr, nullptr, nullptr, nullptr, nullptr);
  k_deep8<0, false><<<dim3(8, 8), 512, 0, stream>>>(Wff0b, Wy0T, Wc0b, nullptr, HID,
      nullptr, nullptr, 0, nullptr, nullptr, nullptr, nullptr, nullptr, nullptr);
  k_deep8<0, false><<<dim3(8, 8), 512, 0, stream>>>(Wff1b, Wy1T, Wc1b, nullptr, HID,
      nullptr, nullptr, 0, nullptr, nullptr, nullptr, nullptr, nullptr, nullptr);

  // xp0 = emb @ W0^T + bias0
  k_deep8<0, false><<<dim3(8, 256), 512, 0, stream>>>(E, W0b, X1, bias0, BT,
      nullptr, nullptr, 0, nullptr, nullptr, nullptr, nullptr, nullptr, nullptr);

  // scan rounds (y-dims multiples of 8 for the swizzle; grid-stride covers overflow)
  static const int gyd[DTAIL] = {128, 64, 40, 24, 16, 8, 8, 8, 8, 8, 8, 8, 8, 8, 8, 8, 8, 8};

  // layer 0 scan + exact tail
  for (int d = 0; d < DTAIL; ++d)
    k_deep8<3, true><<<dim3(8, gyd[d]), 512, 0, stream>>>(HS, Uhb, nullptr, nullptr, 0,
        cnts, offs, d, src0, dstl, X1, bUh, dout, HS);
  k_tail<<<1, 1024, 0, stream>>>(cnts, offs, dstl, Uhb, bUh, X1, HS, dout);

  // layer_in1 = leaky_relu(hs0 @ Wc0^T + bc0)
  k_deep8<1, false><<<dim3(8, 256), 512, 0, stream>>>(HS, Wc0b, E, bc0, BT,
      nullptr, nullptr, 0, nullptr, nullptr, nullptr, nullptr, nullptr, nullptr);
  // xp1 = layer_in1 @ Wh1^T
  k_deep8<0, false><<<dim3(8, 256), 512, 0, stream>>>(E, Wh1b, X1, nullptr, BT,
      nullptr, nullptr, 0, nullptr, nullptr, nullptr, nullptr, nullptr, nullptr);

  // layer 1 scan + tail
  for (int d = 0; d < DTAIL; ++d)
    k_deep8<3, true><<<dim3(8, gyd[d]), 512, 0, stream>>>(HS, Uhb + HID * HID, nullptr, nullptr, 0,
        cnts, offs, d, src1, dstl, X1, bUh + HID, dout + BATCH * HID, HS);
  k_tail<<<1, 1024, 0, stream>>>(cnts, offs, dstl, Uhb + HID * HID, bUh + HID, X1, HS,
                                 dout + BATCH * HID);

  // layer_in2 = leaky_relu(hs1 @ Wc1^T + bc1)
  k_deep8<1, false><<<dim3(8, 256), 512, 0, stream>>>(HS, Wc1b, E, bc1, BT,
      nullptr, nullptr, 0, nullptr, nullptr, nullptr, nullptr, nullptr, nullptr);
  // out = layer_in2 @ Wout^T + b_out
  k_deep8<2, false><<<dim3(8, 256), 512, 0, stream>>>(E, Woutb, dout + 2 * BATCH * HID, b_out, BT,
      nullptr, nullptr, 0, nullptr, nullptr, nullptr, nullptr, nullptr, nullptr);
}